// Round 1
// baseline (298.136 us; speedup 1.0000x reference)
//
#include <hip/hip_runtime.h>
#include <hip/hip_bf16.h>

using bf16 = __hip_bfloat16;
typedef __attribute__((ext_vector_type(8))) short short8;   // 8 bf16 (4 VGPRs)
typedef __attribute__((ext_vector_type(4))) float floatx4;  // MFMA C/D frag

#define NPn 4096
#define NCn 1024
#define Dn  512
#define Bn  4

__device__ __forceinline__ float b2f(short s) {
    union { unsigned u; float f; } cv;
    cv.u = ((unsigned)(unsigned short)s) << 16;
    return cv.f;
}

// ---------------------------------------------------------------------------
// async global->LDS, 16B per lane. LDS dest = (wave-uniform base) + lane*16B.
// ---------------------------------------------------------------------------
__device__ __forceinline__ void async_copy16(const bf16* g, bf16* l) {
    __builtin_amdgcn_global_load_lds(
        (const __attribute__((address_space(1))) unsigned int*)g,
        (__attribute__((address_space(3))) unsigned int*)l,
        16, 0, 0);
}

// ---------------------------------------------------------------------------
// C[M x N] = scale * A[M x K] * Bt[N x K]^T  (both row-major bf16)
// 128x128 tile, BK=32, 4 waves 2x2, 4x4 mfma_f32_16x16x32_bf16 per wave.
// m97-pattern global_load_lds staging, unpadded [128][32] LDS.
// RS: multiply output row rr by 1/rsc[b*M+rr] (folded softmax normalization).
// Split-K: z = s*nbat + b; partial slot s at C + z*strideC.
// ---------------------------------------------------------------------------
template <typename OutT, bool RS>
__global__ __launch_bounds__(256) void gemm_bt(
    const bf16* __restrict__ A, const bf16* __restrict__ B, OutT* __restrict__ C,
    int M, int N, int K, long strideA, long strideB, long strideC,
    float scale, int nbat, int splits, const float* __restrict__ rsc)
{
    const int z = blockIdx.z;
    const int b = z % nbat;
    const int s = z / nbat;
    const int klen = K / splits;
    const int k0 = s * klen;

    A += (long)b * strideA;
    B += (long)b * strideB;
    C += (long)z * strideC;

    const int bm = blockIdx.y * 128;
    const int bn = blockIdx.x * 128;
    const int tid = threadIdx.x;
    const int lane = tid & 63;
    const int wave = tid >> 6;
    const int wm = (wave >> 1) * 64;
    const int wn = (wave & 1) * 64;

    __shared__ bf16 As[128][32];
    __shared__ bf16 Bs[128][32];

    floatx4 acc[4][4];
#pragma unroll
    for (int i = 0; i < 4; i++)
#pragma unroll
        for (int j = 0; j < 4; j++) acc[i][j] = (floatx4)(0.0f);

    const int srow = lane >> 2;
    const int scol = (lane & 3) * 8;
    const int mrow = lane & 15;
    const int krow = (lane >> 4) * 8;

    for (int kb = k0; kb < k0 + klen; kb += 32) {
        const bf16* Ag = A + (long)(bm + wave * 32 + srow) * K + kb + scol;
        const bf16* Bg = B + (long)(bn + wave * 32 + srow) * K + kb + scol;
        async_copy16(Ag,           &As[wave * 32][0]);
        async_copy16(Ag + 16L * K, &As[wave * 32 + 16][0]);
        async_copy16(Bg,           &Bs[wave * 32][0]);
        async_copy16(Bg + 16L * K, &Bs[wave * 32 + 16][0]);
        __syncthreads();

        short8 af[4], bf[4];
#pragma unroll
        for (int i = 0; i < 4; i++)
            af[i] = *(const short8*)(&As[wm + i * 16 + mrow][krow]);
#pragma unroll
        for (int j = 0; j < 4; j++)
            bf[j] = *(const short8*)(&Bs[wn + j * 16 + mrow][krow]);

#pragma unroll
        for (int i = 0; i < 4; i++)
#pragma unroll
            for (int j = 0; j < 4; j++)
                acc[i][j] = __builtin_amdgcn_mfma_f32_16x16x32_bf16(
                    af[i], bf[j], acc[i][j], 0, 0, 0);
        __syncthreads();
    }

    const int crow = (lane >> 4) * 4;
    const int ccol = lane & 15;
    float inv_[4][4];
#pragma unroll
    for (int i = 0; i < 4; i++)
#pragma unroll
        for (int r = 0; r < 4; r++) {
            if constexpr (RS)
                inv_[i][r] = 1.0f / rsc[(long)b * M + bm + wm + i * 16 + crow + r];
            else
                inv_[i][r] = 1.0f;
        }
#pragma unroll
    for (int i = 0; i < 4; i++) {
#pragma unroll
        for (int j = 0; j < 4; j++) {
#pragma unroll
            for (int r = 0; r < 4; r++) {
                long rr = bm + wm + i * 16 + crow + r;
                long cc = bn + wn + j * 16 + ccol;
                float v = acc[i][j][r] * scale * inv_[i][r];
                if constexpr (__is_same(OutT, float))
                    C[rr * (long)N + cc] = v;
                else
                    C[rr * (long)N + cc] = __float2bfloat16(v);
            }
        }
    }
}

// ---------------------------------------------------------------------------
// One pass over S (bf16) producing BOTH row and col stat partials.
// Tile 256 rows x 64 cols, grid (NC/64, NP/256, B). Per-block unique slots:
//   rp[(b*16+bx)*NP + row] = (sum,sq,max) over this block's 64 cols
//   cp[(b*16+by)*NC + col] = (sum,sq,max) over this block's 256 rows
// ---------------------------------------------------------------------------
__global__ __launch_bounds__(256) void stats_both(
    const bf16* __restrict__ S, float4* __restrict__ rp, float4* __restrict__ cp)
{
    const int b = blockIdx.z, c0 = blockIdx.x * 64, p0 = blockIdx.y * 256;
    const int tid = threadIdx.x;
    const int rt = tid >> 3;          // 0..31 rows per pass
    const int ct = (tid & 7) * 8;     // 8 cols per thread

    float cs[8], cq[8], cm[8];
#pragma unroll
    for (int t = 0; t < 8; t++) { cs[t] = 0.f; cq[t] = 0.f; cm[t] = -3.4e38f; }

#pragma unroll
    for (int pass = 0; pass < 8; pass++) {
        const int p = p0 + pass * 32 + rt;
        const long sidx = ((long)(b * NPn + p)) * NCn + c0 + ct;
        short8 sv = *(const short8*)(S + sidx);
        float rs = 0.f, rq = 0.f, rm = -3.4e38f;
#pragma unroll
        for (int t = 0; t < 8; t++) {
            float x = b2f(sv[t]);
            rs += x; rq += x * x; rm = fmaxf(rm, x);
            cs[t] += x; cq[t] += x * x; cm[t] = fmaxf(cm[t], x);
        }
        // reduce over the 8 lanes covering this row
#pragma unroll
        for (int m = 1; m < 8; m <<= 1) {
            rs += __shfl_xor(rs, m);
            rq += __shfl_xor(rq, m);
            rm = fmaxf(rm, __shfl_xor(rm, m));
        }
        if ((tid & 7) == 0)
            rp[((long)(b * 16 + blockIdx.x)) * NPn + p] = make_float4(rs, rq, rm, 0.f);
    }

    // col partials: reduce across rt within wave (xor 8,16,32), then LDS across waves
#pragma unroll
    for (int m = 8; m < 64; m <<= 1)
#pragma unroll
        for (int t = 0; t < 8; t++) {
            cs[t] += __shfl_xor(cs[t], m);
            cq[t] += __shfl_xor(cq[t], m);
            cm[t] = fmaxf(cm[t], __shfl_xor(cm[t], m));
        }
    __shared__ float LS[4][64], LQ[4][64], LM[4][64];
    const int lane = tid & 63, wave = tid >> 6;
    if (lane < 8)
#pragma unroll
        for (int t = 0; t < 8; t++) {
            LS[wave][lane * 8 + t] = cs[t];
            LQ[wave][lane * 8 + t] = cq[t];
            LM[wave][lane * 8 + t] = cm[t];
        }
    __syncthreads();
    if (tid < 64) {
        float s0 = LS[0][tid] + LS[1][tid] + LS[2][tid] + LS[3][tid];
        float q0 = LQ[0][tid] + LQ[1][tid] + LQ[2][tid] + LQ[3][tid];
        float m0 = fmaxf(fmaxf(LM[0][tid], LM[1][tid]), fmaxf(LM[2][tid], LM[3][tid]));
        cp[((long)(b * 16 + blockIdx.y)) * NCn + c0 + tid] = make_float4(s0, q0, m0, 0.f);
    }
}

// ---------------------------------------------------------------------------
// Finalize stats: rows (B*NP entries, reduce 16 partials, N=NC) then cols
// (B*NC entries, reduce 16 partials, N=NP). thr = mean + std(ddof=1)/8.
// Also zeros d1/d2 (denominator accumulators).
// ---------------------------------------------------------------------------
__global__ __launch_bounds__(256) void stats_final(
    const float4* __restrict__ rp, const float4* __restrict__ cp,
    float2* __restrict__ row_tm, float2* __restrict__ col_tm,
    float* __restrict__ d1, float* __restrict__ d2)
{
    int idx = blockIdx.x * 256 + threadIdx.x;   // 0 .. B*NP + B*NC - 1
    if (idx < Bn * NPn) {
        int b = idx >> 12, p = idx & (NPn - 1);
        float s = 0.f, q = 0.f, m = -3.4e38f;
#pragma unroll
        for (int i = 0; i < 16; i++) {
            float4 v = rp[((long)(b * 16 + i)) * NPn + p];
            s += v.x; q += v.y; m = fmaxf(m, v.z);
        }
        float mean = s * (1.0f / NCn);
        float var = fmaxf((q - (float)NCn * mean * mean) * (1.0f / (NCn - 1)), 0.0f);
        row_tm[idx] = make_float2(mean + sqrtf(var) * 0.125f, m);
        d1[idx] = 0.f;
    } else {
        int cidx = idx - Bn * NPn;
        int b = cidx >> 10, c = cidx & (NCn - 1);
        float s = 0.f, q = 0.f, m = -3.4e38f;
#pragma unroll
        for (int i = 0; i < 16; i++) {
            float4 v = cp[((long)(b * 16 + i)) * NCn + c];
            s += v.x; q += v.y; m = fmaxf(m, v.z);
        }
        float mean = s * (1.0f / NPn);
        float var = fmaxf((q - (float)NPn * mean * mean) * (1.0f / (NPn - 1)), 0.0f);
        col_tm[cidx] = make_float2(mean + sqrtf(var) * 0.125f, m);
        d2[cidx] = 0.f;
    }
}

// ---------------------------------------------------------------------------
// Merged masked softmax: one read of S (bf16) produces
//   A1u[p][c] = (s>=thr_r[p]) ? exp(s-mx_r[p]) : 0    (row-major, unnormalized)
//   A2u[c][p] = (s>=thr_c[c]) ? exp(s-mx_c[c]) : 0    (transposed via LDS)
// d1[p], d2[c] accumulated via device atomics; normalization folded downstream.
// Tile: 256 rows x 64 cols. 256 threads.
// ---------------------------------------------------------------------------
__global__ __launch_bounds__(256) void softmax_merged(
    const bf16* __restrict__ S, const float2* __restrict__ row_tm,
    const float2* __restrict__ col_tm, float* __restrict__ d1,
    float* __restrict__ d2, bf16* __restrict__ A1u, bf16* __restrict__ A2u)
{
    const int b = blockIdx.z, c0 = blockIdx.x * 64, p0 = blockIdx.y * 256;
    const int tid = threadIdx.x;
    const int rt = tid >> 3;          // 0..31 row within pass
    const int ct = (tid & 7) * 8;     // col offset, 8 cols per thread

    __shared__ float T[64][265];      // transposed e2 staging
    __shared__ float dw2[4][64];      // per-wave col-denom partials

    float2 ctm[8];
#pragma unroll
    for (int t = 0; t < 8; t++) ctm[t] = col_tm[b * NCn + c0 + ct + t];

    float d2acc[8];
#pragma unroll
    for (int t = 0; t < 8; t++) d2acc[t] = 0.f;

#pragma unroll
    for (int pass = 0; pass < 8; pass++) {
        const int p = p0 + pass * 32 + rt;
        const float2 rtm = row_tm[b * NPn + p];
        const long sidx = ((long)(b * NPn + p)) * NCn + c0 + ct;
        short8 sv = *(const short8*)(S + sidx);
        bf16 o1[8] __attribute__((aligned(16)));
        float e1s = 0.f;
#pragma unroll
        for (int t = 0; t < 8; t++) {
            float x = b2f(sv[t]);
            float e1 = (x >= rtm.x) ? __expf(x - rtm.y) : 0.0f;
            o1[t] = __float2bfloat16(e1);
            e1s += e1;
            float e2 = (x >= ctm[t].x) ? __expf(x - ctm[t].y) : 0.0f;
            d2acc[t] += e2;
            T[ct + t][pass * 32 + rt] = e2;
        }
        *(short8*)(A1u + sidx) = *(const short8*)o1;
        e1s += __shfl_xor(e1s, 1);
        e1s += __shfl_xor(e1s, 2);
        e1s += __shfl_xor(e1s, 4);
        if ((tid & 7) == 0) atomicAdd(&d1[b * NPn + p], e1s);
    }

    // col denominators: reduce d2acc across rt within wave, then LDS
#pragma unroll
    for (int m = 8; m < 64; m <<= 1)
#pragma unroll
        for (int t = 0; t < 8; t++) d2acc[t] += __shfl_xor(d2acc[t], m);
    const int lane = tid & 63, wave = tid >> 6;
    if (lane < 8)
#pragma unroll
        for (int t = 0; t < 8; t++) dw2[wave][lane * 8 + t] = d2acc[t];
    __syncthreads();
    if (tid < 64)
        atomicAdd(&d2[b * NCn + c0 + tid],
                  dw2[0][tid] + dw2[1][tid] + dw2[2][tid] + dw2[3][tid]);

    // write A2u (transposed tile) from LDS
    const int c = tid >> 2, pb = (tid & 3) * 64;
    bf16* dst = A2u + ((long)(b * NCn + c0 + c)) * NPn + p0 + pb;
#pragma unroll
    for (int u = 0; u < 8; u++) {
        bf16 tmp[8] __attribute__((aligned(16)));
#pragma unroll
        for (int w = 0; w < 8; w++)
            tmp[w] = __float2bfloat16(T[c][pb + u * 8 + w]);
        *(short8*)(dst + u * 8) = *(const short8*)tmp;
    }
}

// ---------------------------------------------------------------------------
// Sum 4 split-K fp32 partials, scale row (b*NC+c) by 1/d2 -> bf16
// ---------------------------------------------------------------------------
__global__ __launch_bounds__(256) void reduce_scale_bf16(
    const float* __restrict__ Pp, const float* __restrict__ d2,
    bf16* __restrict__ out, long n4, long stride)
{
    long i = (long)blockIdx.x * 256 + threadIdx.x;
    if (i < n4) {
        float4 a = ((const float4*)Pp)[i];
#pragma unroll
        for (int s = 1; s < 4; s++) {
            float4 v = ((const float4*)(Pp + (long)s * stride))[i];
            a.x += v.x; a.y += v.y; a.z += v.z; a.w += v.w;
        }
        float inv = 1.0f / d2[i / (Dn / 4)];
        out[i * 4 + 0] = __float2bfloat16(a.x * inv);
        out[i * 4 + 1] = __float2bfloat16(a.y * inv);
        out[i * 4 + 2] = __float2bfloat16(a.z * inv);
        out[i * 4 + 3] = __float2bfloat16(a.w * inv);
    }
}

// ---------------------------------------------------------------------------
// fp32 [R x C] -> bf16 row-major copy AND bf16 [C x R] transpose, batched z.
// ---------------------------------------------------------------------------
__global__ __launch_bounds__(256) void cvt_both(
    const float* __restrict__ in, bf16* __restrict__ out_rm,
    bf16* __restrict__ out_t, int R, int C)
{
    __shared__ float tile[32][33];
    const long boff = (long)blockIdx.z * (long)R * C;
    in += boff; out_rm += boff; out_t += boff;
    const int c0 = blockIdx.x * 32, r0 = blockIdx.y * 32;
    const int tx = threadIdx.x, ty = threadIdx.y;
#pragma unroll
    for (int i = ty; i < 32; i += 8) {
        float x = in[(long)(r0 + i) * C + c0 + tx];
        tile[i][tx] = x;
        out_rm[(long)(r0 + i) * C + c0 + tx] = __float2bfloat16(x);
    }
    __syncthreads();
#pragma unroll
    for (int i = ty; i < 32; i += 8)
        out_t[(long)(c0 + i) * R + r0 + tx] = __float2bfloat16(tile[tx][i]);
}

// ---------------------------------------------------------------------------
extern "C" void kernel_launch(void* const* d_in, const int* in_sizes, int n_in,
                              void* d_out, int out_size, void* d_ws, size_t ws_size,
                              hipStream_t stream)
{
    const float* Xp = (const float*)d_in[0];  // [4,4096,512]
    const float* Xc = (const float*)d_in[1];  // [4,1024,512]
    float* out = (float*)d_out;               // [4,4096,1024]

    constexpr int B = Bn, NP = NPn, NC = NCn, D = Dn;
    constexpr float SCALE = 0.044194173824159216f;  // 1/sqrt(512)

    // workspace layout (bytes), ~164 MB
    char* ws = (char*)d_ws;
    bf16*   Qp     = (bf16*)(ws);                   // 16.78 MB [B,NP,D]
    bf16*   Kc     = (bf16*)(ws + 16777216);        //  4.19 MB [B,NC,D]
    bf16*   KcT    = (bf16*)(ws + 20971520);        //  4.19 MB [B,D,NC]
    bf16*   XpT    = (bf16*)(ws + 25165824);        // 16.78 MB [B,D,NP]
    bf16*   S      = (bf16*)(ws + 41943040);        // 33.55 MB [B,NP,NC]; later Hp overlays
    bf16*   A1u    = (bf16*)(ws + 75497472);        // 33.55 MB [B,NP,NC]
    bf16*   A2u    = (bf16*)(ws + 109051904);       // 33.55 MB [B,NC,NP]; rp/cp overlay pre-softmax
    bf16*   H1u    = (bf16*)(ws + 142606336);       // 16.78 MB [B,NP,D]
    bf16*   H2     = (bf16*)(ws + 159383552);       //  4.19 MB [B,NC,D]
    float2* row_tm = (float2*)(ws + 163577856);     // 128 KB  [B*NP]
    float2* col_tm = (float2*)(ws + 163708928);     //  32 KB  [B*NC]
    float*  d1     = (float*)(ws + 163741696);      //  64 KB  [B*NP]
    float*  d2     = (float*)(ws + 163807232);      //  16 KB  [B*NC]
    // stat partials overlay A2u (dead until softmax_merged; consumed by stats_final)
    float4* rp     = (float4*)A2u;                  //  4.19 MB [B*16,NP]
    float4* cp     = (float4*)(ws + 109051904 + 4194304);  // 1.05 MB [B*16,NC]
    float*  Hp     = (float*)S;                     // split-K partials [4][B,NC,D] fp32 (S dead)

    // 1-2: convert + transpose inputs (one read of fp32 each)
    cvt_both<<<dim3(D / 32, NP / 32, B), dim3(32, 8), 0, stream>>>(Xp, Qp, XpT, NP, D);
    cvt_both<<<dim3(D / 32, NC / 32, B), dim3(32, 8), 0, stream>>>(Xc, Kc, KcT, NC, D);

    // 3: S = Qp*Kc^T*scale (bf16)
    gemm_bt<bf16, false><<<dim3(NC / 128, NP / 128, B), dim3(256), 0, stream>>>(
        Qp, Kc, S, NP, NC, D, (long)NP * D, (long)NC * D, (long)NP * NC,
        SCALE, B, 1, nullptr);
    // 4: one-pass row+col stat partials from S
    stats_both<<<dim3(NC / 64, NP / 256, B), dim3(256), 0, stream>>>(S, rp, cp);
    // 5: finalize thr/max; zero denoms
    stats_final<<<dim3((B * NP + B * NC) / 256), dim3(256), 0, stream>>>(
        rp, cp, row_tm, col_tm, d1, d2);
    // 6: merged softmax -> A1u (row-major) + A2u (transposed), denoms via atomics
    softmax_merged<<<dim3(NC / 64, NP / 256, B), dim3(256), 0, stream>>>(
        S, row_tm, col_tm, d1, d2, A1u, A2u);
    // 7: H1u = A1u * Kc            [B,NP,D] bf16 (unnormalized; 1/d1 folded into step 10)
    gemm_bt<bf16, false><<<dim3(D / 128, NP / 128, B), dim3(256), 0, stream>>>(
        A1u, KcT, H1u, NP, D, NC, (long)NP * NC, (long)D * NC, (long)NP * D,
        1.0f, B, 1, nullptr);
    // 8: Hp = A2u * Xp partials    [4][B,NC,D] fp32, 4-way split-K
    gemm_bt<float, false><<<dim3(D / 128, NC / 128, 4 * B), dim3(256), 0, stream>>>(
        A2u, XpT, Hp, NC, D, NP, (long)NC * NP, (long)D * NP, (long)NC * D,
        1.0f, B, 4, nullptr);
    // 9: H2 = sum(Hp) / d2 -> bf16
    {
        long n = (long)B * NC * D;
        reduce_scale_bf16<<<dim3((n / 4 + 255) / 256), dim3(256), 0, stream>>>(
            Hp, d2, H2, n / 4, n);
    }
    // 10: out = diag(1/d1) * H1u * H2^T   [B,NP,NC] fp32
    gemm_bt<float, true><<<dim3(NC / 128, NP / 128, B), dim3(256), 0, stream>>>(
        H1u, H2, out, NP, NC, D, (long)NP * D, (long)NC * D, (long)NP * NC,
        1.0f, B, 1, d1);
}

// Round 2
// 283.197 us; speedup vs baseline: 1.0528x; 1.0528x over previous
//
#include <hip/hip_runtime.h>
#include <hip/hip_bf16.h>

using bf16 = __hip_bfloat16;
typedef __attribute__((ext_vector_type(8))) short short8;   // 8 bf16 (4 VGPRs)
typedef __attribute__((ext_vector_type(4))) float floatx4;  // MFMA C/D frag

#define NPn 4096
#define NCn 1024
#define Dn  512
#define Bn  4

__device__ __forceinline__ float b2f(short s) {
    union { unsigned u; float f; } cv;
    cv.u = ((unsigned)(unsigned short)s) << 16;
    return cv.f;
}

// ---------------------------------------------------------------------------
// async global->LDS, 16B per lane. LDS dest = (wave-uniform base) + lane*16B.
// ---------------------------------------------------------------------------
__device__ __forceinline__ void async_copy16(const bf16* g, bf16* l) {
    __builtin_amdgcn_global_load_lds(
        (const __attribute__((address_space(1))) unsigned int*)g,
        (__attribute__((address_space(3))) unsigned int*)l,
        16, 0, 0);
}

// ---------------------------------------------------------------------------
// C[M x N] = scale * A[M x K] * Bt[N x K]^T  (both row-major bf16)
// 128x128 tile, BK=32, 4 waves 2x2, 4x4 mfma_f32_16x16x32_bf16 per wave.
// Round-2 changes vs m97 structure:
//   * double-buffered LDS: prefetch tile t+1 via global_load_lds while
//     computing tile t -> the end-of-iter barrier's vmcnt(0) drain waits
//     (latency - compute) instead of a full L2/HBM round trip.
//   * bijective XCD-aware (bx,by) swizzle (m204): consecutive blocks on one
//     XCD share A-panels -> L2 hits instead of HBM re-fetch.
// RS: multiply output row rr by 1/rsc[b*M+rr] (folded softmax normalization).
// Split-K: z = s*nbat + b; partial slot s at C + z*strideC.
// ---------------------------------------------------------------------------
template <typename OutT, bool RS>
__global__ __launch_bounds__(256) void gemm_bt(
    const bf16* __restrict__ A, const bf16* __restrict__ B, OutT* __restrict__ C,
    int M, int N, int K, long strideA, long strideB, long strideC,
    float scale, int nbat, int splits, const float* __restrict__ rsc)
{
    const int z = blockIdx.z;
    const int b = z % nbat;
    const int s = z / nbat;
    const int klen = K / splits;
    const int k0 = s * klen;

    A += (long)b * strideA;
    B += (long)b * strideB;
    C += (long)z * strideC;

    // XCD-aware bijective swizzle of the (bx,by) plane (m204).
    const int nwg = gridDim.x * gridDim.y;
    const int orig = blockIdx.y * gridDim.x + blockIdx.x;
    const int q = nwg >> 3, r = nwg & 7;
    const int xcd = orig & 7, pos = orig >> 3;
    const int nid = (xcd < r ? xcd * (q + 1) : r * (q + 1) + (xcd - r) * q) + pos;
    const int bxs = nid % gridDim.x;
    const int bys = nid / gridDim.x;

    const int bm = bys * 128;
    const int bn = bxs * 128;
    const int tid = threadIdx.x;
    const int lane = tid & 63;
    const int wave = tid >> 6;
    const int wm = (wave >> 1) * 64;
    const int wn = (wave & 1) * 64;

    __shared__ bf16 As[2][128][32];
    __shared__ bf16 Bs[2][128][32];

    floatx4 acc[4][4];
#pragma unroll
    for (int i = 0; i < 4; i++)
#pragma unroll
        for (int j = 0; j < 4; j++) acc[i][j] = (floatx4)(0.0f);

    const int srow = lane >> 2;
    const int scol = (lane & 3) * 8;
    const int mrow = lane & 15;
    const int krow = (lane >> 4) * 8;

    const bf16* Arow = A + (long)(bm + wave * 32 + srow) * K + scol;
    const bf16* Brow = B + (long)(bn + wave * 32 + srow) * K + scol;

    // prologue: stage first K-tile into buffer 0
    {
        const bf16* Ag = Arow + k0;
        const bf16* Bg = Brow + k0;
        async_copy16(Ag,           &As[0][wave * 32][0]);
        async_copy16(Ag + 16L * K, &As[0][wave * 32 + 16][0]);
        async_copy16(Bg,           &Bs[0][wave * 32][0]);
        async_copy16(Bg + 16L * K, &Bs[0][wave * 32 + 16][0]);
    }
    __syncthreads();

    const int kend = k0 + klen;
    int cur = 0;
    for (int kb = k0; kb < kend; kb += 32) {
        // issue prefetch of next tile into the other buffer (in flight
        // across the ds_read + MFMA below)
        if (kb + 32 < kend) {
            const bf16* Ag = Arow + kb + 32;
            const bf16* Bg = Brow + kb + 32;
            async_copy16(Ag,           &As[cur ^ 1][wave * 32][0]);
            async_copy16(Ag + 16L * K, &As[cur ^ 1][wave * 32 + 16][0]);
            async_copy16(Bg,           &Bs[cur ^ 1][wave * 32][0]);
            async_copy16(Bg + 16L * K, &Bs[cur ^ 1][wave * 32 + 16][0]);
        }

        short8 af[4], bf[4];
#pragma unroll
        for (int i = 0; i < 4; i++)
            af[i] = *(const short8*)(&As[cur][wm + i * 16 + mrow][krow]);
#pragma unroll
        for (int j = 0; j < 4; j++)
            bf[j] = *(const short8*)(&Bs[cur][wn + j * 16 + mrow][krow]);

#pragma unroll
        for (int i = 0; i < 4; i++)
#pragma unroll
            for (int j = 0; j < 4; j++)
                acc[i][j] = __builtin_amdgcn_mfma_f32_16x16x32_bf16(
                    af[i], bf[j], acc[i][j], 0, 0, 0);

        // drains vmcnt(0) (prefetch landed) + lgkmcnt, then barrier:
        // next iter may read buf cur^1 and overwrite buf cur.
        __syncthreads();
        cur ^= 1;
    }

    const int crow = (lane >> 4) * 4;
    const int ccol = lane & 15;
    float inv_[4][4];
#pragma unroll
    for (int i = 0; i < 4; i++)
#pragma unroll
        for (int r2 = 0; r2 < 4; r2++) {
            if constexpr (RS)
                inv_[i][r2] = 1.0f / rsc[(long)b * M + bm + wm + i * 16 + crow + r2];
            else
                inv_[i][r2] = 1.0f;
        }
#pragma unroll
    for (int i = 0; i < 4; i++) {
#pragma unroll
        for (int j = 0; j < 4; j++) {
#pragma unroll
            for (int r2 = 0; r2 < 4; r2++) {
                long rr = bm + wm + i * 16 + crow + r2;
                long cc = bn + wn + j * 16 + ccol;
                float v = acc[i][j][r2] * scale * inv_[i][r2];
                if constexpr (__is_same(OutT, float))
                    C[rr * (long)N + cc] = v;
                else
                    C[rr * (long)N + cc] = __float2bfloat16(v);
            }
        }
    }
}

// ---------------------------------------------------------------------------
// One pass over S (bf16) producing BOTH row and col stat partials.
// Tile 256 rows x 64 cols, grid (NC/64, NP/256, B). Per-block unique slots:
//   rp[(b*16+bx)*NP + row] = (sum,sq,max) over this block's 64 cols
//   cp[(b*16+by)*NC + col] = (sum,sq,max) over this block's 256 rows
// ---------------------------------------------------------------------------
__global__ __launch_bounds__(256) void stats_both(
    const bf16* __restrict__ S, float4* __restrict__ rp, float4* __restrict__ cp)
{
    const int b = blockIdx.z, c0 = blockIdx.x * 64, p0 = blockIdx.y * 256;
    const int tid = threadIdx.x;
    const int rt = tid >> 3;          // 0..31 rows per pass
    const int ct = (tid & 7) * 8;     // 8 cols per thread

    float cs[8], cq[8], cm[8];
#pragma unroll
    for (int t = 0; t < 8; t++) { cs[t] = 0.f; cq[t] = 0.f; cm[t] = -3.4e38f; }

#pragma unroll
    for (int pass = 0; pass < 8; pass++) {
        const int p = p0 + pass * 32 + rt;
        const long sidx = ((long)(b * NPn + p)) * NCn + c0 + ct;
        short8 sv = *(const short8*)(S + sidx);
        float rs = 0.f, rq = 0.f, rm = -3.4e38f;
#pragma unroll
        for (int t = 0; t < 8; t++) {
            float x = b2f(sv[t]);
            rs += x; rq += x * x; rm = fmaxf(rm, x);
            cs[t] += x; cq[t] += x * x; cm[t] = fmaxf(cm[t], x);
        }
        // reduce over the 8 lanes covering this row
#pragma unroll
        for (int m = 1; m < 8; m <<= 1) {
            rs += __shfl_xor(rs, m);
            rq += __shfl_xor(rq, m);
            rm = fmaxf(rm, __shfl_xor(rm, m));
        }
        if ((tid & 7) == 0)
            rp[((long)(b * 16 + blockIdx.x)) * NPn + p] = make_float4(rs, rq, rm, 0.f);
    }

    // col partials: reduce across rt within wave (xor 8,16,32), then LDS across waves
#pragma unroll
    for (int m = 8; m < 64; m <<= 1)
#pragma unroll
        for (int t = 0; t < 8; t++) {
            cs[t] += __shfl_xor(cs[t], m);
            cq[t] += __shfl_xor(cq[t], m);
            cm[t] = fmaxf(cm[t], __shfl_xor(cm[t], m));
        }
    __shared__ float LS[4][64], LQ[4][64], LM[4][64];
    const int lane = tid & 63, wave = tid >> 6;
    if (lane < 8)
#pragma unroll
        for (int t = 0; t < 8; t++) {
            LS[wave][lane * 8 + t] = cs[t];
            LQ[wave][lane * 8 + t] = cq[t];
            LM[wave][lane * 8 + t] = cm[t];
        }
    __syncthreads();
    if (tid < 64) {
        float s0 = LS[0][tid] + LS[1][tid] + LS[2][tid] + LS[3][tid];
        float q0 = LQ[0][tid] + LQ[1][tid] + LQ[2][tid] + LQ[3][tid];
        float m0 = fmaxf(fmaxf(LM[0][tid], LM[1][tid]), fmaxf(LM[2][tid], LM[3][tid]));
        cp[((long)(b * 16 + blockIdx.y)) * NCn + c0 + tid] = make_float4(s0, q0, m0, 0.f);
    }
}

// ---------------------------------------------------------------------------
// Finalize stats: rows (B*NP entries, reduce 16 partials, N=NC) then cols
// (B*NC entries, reduce 16 partials, N=NP). thr = mean + std(ddof=1)/8.
// Also zeros d1/d2 (denominator accumulators).
// ---------------------------------------------------------------------------
__global__ __launch_bounds__(256) void stats_final(
    const float4* __restrict__ rp, const float4* __restrict__ cp,
    float2* __restrict__ row_tm, float2* __restrict__ col_tm,
    float* __restrict__ d1, float* __restrict__ d2)
{
    int idx = blockIdx.x * 256 + threadIdx.x;   // 0 .. B*NP + B*NC - 1
    if (idx < Bn * NPn) {
        int b = idx >> 12, p = idx & (NPn - 1);
        float s = 0.f, q = 0.f, m = -3.4e38f;
#pragma unroll
        for (int i = 0; i < 16; i++) {
            float4 v = rp[((long)(b * 16 + i)) * NPn + p];
            s += v.x; q += v.y; m = fmaxf(m, v.z);
        }
        float mean = s * (1.0f / NCn);
        float var = fmaxf((q - (float)NCn * mean * mean) * (1.0f / (NCn - 1)), 0.0f);
        row_tm[idx] = make_float2(mean + sqrtf(var) * 0.125f, m);
        d1[idx] = 0.f;
    } else {
        int cidx = idx - Bn * NPn;
        int b = cidx >> 10, c = cidx & (NCn - 1);
        float s = 0.f, q = 0.f, m = -3.4e38f;
#pragma unroll
        for (int i = 0; i < 16; i++) {
            float4 v = cp[((long)(b * 16 + i)) * NCn + c];
            s += v.x; q += v.y; m = fmaxf(m, v.z);
        }
        float mean = s * (1.0f / NPn);
        float var = fmaxf((q - (float)NPn * mean * mean) * (1.0f / (NPn - 1)), 0.0f);
        col_tm[cidx] = make_float2(mean + sqrtf(var) * 0.125f, m);
        d2[cidx] = 0.f;
    }
}

// ---------------------------------------------------------------------------
// Merged masked softmax: one read of S (bf16) produces
//   A1u[p][c] = (s>=thr_r[p]) ? exp(s-mx_r[p]) : 0    (row-major, unnormalized)
//   A2u[c][p] = (s>=thr_c[c]) ? exp(s-mx_c[c]) : 0    (transposed via LDS)
// d1[p], d2[c] accumulated via device atomics; normalization folded downstream.
// Tile: 256 rows x 64 cols. 256 threads.
// ---------------------------------------------------------------------------
__global__ __launch_bounds__(256) void softmax_merged(
    const bf16* __restrict__ S, const float2* __restrict__ row_tm,
    const float2* __restrict__ col_tm, float* __restrict__ d1,
    float* __restrict__ d2, bf16* __restrict__ A1u, bf16* __restrict__ A2u)
{
    const int b = blockIdx.z, c0 = blockIdx.x * 64, p0 = blockIdx.y * 256;
    const int tid = threadIdx.x;
    const int rt = tid >> 3;          // 0..31 row within pass
    const int ct = (tid & 7) * 8;     // col offset, 8 cols per thread

    __shared__ float T[64][265];      // transposed e2 staging
    __shared__ float dw2[4][64];      // per-wave col-denom partials

    float2 ctm[8];
#pragma unroll
    for (int t = 0; t < 8; t++) ctm[t] = col_tm[b * NCn + c0 + ct + t];

    float d2acc[8];
#pragma unroll
    for (int t = 0; t < 8; t++) d2acc[t] = 0.f;

#pragma unroll
    for (int pass = 0; pass < 8; pass++) {
        const int p = p0 + pass * 32 + rt;
        const float2 rtm = row_tm[b * NPn + p];
        const long sidx = ((long)(b * NPn + p)) * NCn + c0 + ct;
        short8 sv = *(const short8*)(S + sidx);
        bf16 o1[8] __attribute__((aligned(16)));
        float e1s = 0.f;
#pragma unroll
        for (int t = 0; t < 8; t++) {
            float x = b2f(sv[t]);
            float e1 = (x >= rtm.x) ? __expf(x - rtm.y) : 0.0f;
            o1[t] = __float2bfloat16(e1);
            e1s += e1;
            float e2 = (x >= ctm[t].x) ? __expf(x - ctm[t].y) : 0.0f;
            d2acc[t] += e2;
            T[ct + t][pass * 32 + rt] = e2;
        }
        *(short8*)(A1u + sidx) = *(const short8*)o1;
        e1s += __shfl_xor(e1s, 1);
        e1s += __shfl_xor(e1s, 2);
        e1s += __shfl_xor(e1s, 4);
        if ((tid & 7) == 0) atomicAdd(&d1[b * NPn + p], e1s);
    }

    // col denominators: reduce d2acc across rt within wave, then LDS
#pragma unroll
    for (int m = 8; m < 64; m <<= 1)
#pragma unroll
        for (int t = 0; t < 8; t++) d2acc[t] += __shfl_xor(d2acc[t], m);
    const int lane = tid & 63, wave = tid >> 6;
    if (lane < 8)
#pragma unroll
        for (int t = 0; t < 8; t++) dw2[wave][lane * 8 + t] = d2acc[t];
    __syncthreads();
    if (tid < 64)
        atomicAdd(&d2[b * NCn + c0 + tid],
                  dw2[0][tid] + dw2[1][tid] + dw2[2][tid] + dw2[3][tid]);

    // write A2u (transposed tile) from LDS
    const int c = tid >> 2, pb = (tid & 3) * 64;
    bf16* dst = A2u + ((long)(b * NCn + c0 + c)) * NPn + p0 + pb;
#pragma unroll
    for (int u = 0; u < 8; u++) {
        bf16 tmp[8] __attribute__((aligned(16)));
#pragma unroll
        for (int w = 0; w < 8; w++)
            tmp[w] = __float2bfloat16(T[c][pb + u * 8 + w]);
        *(short8*)(dst + u * 8) = *(const short8*)tmp;
    }
}

// ---------------------------------------------------------------------------
// Sum 4 split-K fp32 partials, scale row (b*NC+c) by 1/d2 -> bf16
// ---------------------------------------------------------------------------
__global__ __launch_bounds__(256) void reduce_scale_bf16(
    const float* __restrict__ Pp, const float* __restrict__ d2,
    bf16* __restrict__ out, long n4, long stride)
{
    long i = (long)blockIdx.x * 256 + threadIdx.x;
    if (i < n4) {
        float4 a = ((const float4*)Pp)[i];
#pragma unroll
        for (int s = 1; s < 4; s++) {
            float4 v = ((const float4*)(Pp + (long)s * stride))[i];
            a.x += v.x; a.y += v.y; a.z += v.z; a.w += v.w;
        }
        float inv = 1.0f / d2[i / (Dn / 4)];
        out[i * 4 + 0] = __float2bfloat16(a.x * inv);
        out[i * 4 + 1] = __float2bfloat16(a.y * inv);
        out[i * 4 + 2] = __float2bfloat16(a.z * inv);
        out[i * 4 + 3] = __float2bfloat16(a.w * inv);
    }
}

// ---------------------------------------------------------------------------
// fp32 [R x C] -> bf16 row-major copy AND bf16 [C x R] transpose, batched z.
// ---------------------------------------------------------------------------
__global__ __launch_bounds__(256) void cvt_both(
    const float* __restrict__ in, bf16* __restrict__ out_rm,
    bf16* __restrict__ out_t, int R, int C)
{
    __shared__ float tile[32][33];
    const long boff = (long)blockIdx.z * (long)R * C;
    in += boff; out_rm += boff; out_t += boff;
    const int c0 = blockIdx.x * 32, r0 = blockIdx.y * 32;
    const int tx = threadIdx.x, ty = threadIdx.y;
#pragma unroll
    for (int i = ty; i < 32; i += 8) {
        float x = in[(long)(r0 + i) * C + c0 + tx];
        tile[i][tx] = x;
        out_rm[(long)(r0 + i) * C + c0 + tx] = __float2bfloat16(x);
    }
    __syncthreads();
#pragma unroll
    for (int i = ty; i < 32; i += 8)
        out_t[(long)(c0 + i) * R + r0 + tx] = __float2bfloat16(tile[tx][i]);
}

// ---------------------------------------------------------------------------
extern "C" void kernel_launch(void* const* d_in, const int* in_sizes, int n_in,
                              void* d_out, int out_size, void* d_ws, size_t ws_size,
                              hipStream_t stream)
{
    const float* Xp = (const float*)d_in[0];  // [4,4096,512]
    const float* Xc = (const float*)d_in[1];  // [4,1024,512]
    float* out = (float*)d_out;               // [4,4096,1024]

    constexpr int B = Bn, NP = NPn, NC = NCn, D = Dn;
    constexpr float SCALE = 0.044194173824159216f;  // 1/sqrt(512)

    // workspace layout (bytes), ~164 MB
    char* ws = (char*)d_ws;
    bf16*   Qp     = (bf16*)(ws);                   // 16.78 MB [B,NP,D]
    bf16*   Kc     = (bf16*)(ws + 16777216);        //  4.19 MB [B,NC,D]
    bf16*   KcT    = (bf16*)(ws + 20971520);        //  4.19 MB [B,D,NC]
    bf16*   XpT    = (bf16*)(ws + 25165824);        // 16.78 MB [B,D,NP]
    bf16*   S      = (bf16*)(ws + 41943040);        // 33.55 MB [B,NP,NC]; later Hp overlays
    bf16*   A1u    = (bf16*)(ws + 75497472);        // 33.55 MB [B,NP,NC]
    bf16*   A2u    = (bf16*)(ws + 109051904);       // 33.55 MB [B,NC,NP]; rp/cp overlay pre-softmax
    bf16*   H1u    = (bf16*)(ws + 142606336);       // 16.78 MB [B,NP,D]
    bf16*   H2     = (bf16*)(ws + 159383552);       //  4.19 MB [B,NC,D]
    float2* row_tm = (float2*)(ws + 163577856);     // 128 KB  [B*NP]
    float2* col_tm = (float2*)(ws + 163708928);     //  32 KB  [B*NC]
    float*  d1     = (float*)(ws + 163741696);      //  64 KB  [B*NP]
    float*  d2     = (float*)(ws + 163807232);      //  16 KB  [B*NC]
    // stat partials overlay A2u (dead until softmax_merged; consumed by stats_final)
    float4* rp     = (float4*)A2u;                  //  4.19 MB [B*16,NP]
    float4* cp     = (float4*)(ws + 109051904 + 4194304);  // 1.05 MB [B*16,NC]
    float*  Hp     = (float*)S;                     // split-K partials [4][B,NC,D] fp32 (S dead)

    // 1-2: convert + transpose inputs (one read of fp32 each)
    cvt_both<<<dim3(D / 32, NP / 32, B), dim3(32, 8), 0, stream>>>(Xp, Qp, XpT, NP, D);
    cvt_both<<<dim3(D / 32, NC / 32, B), dim3(32, 8), 0, stream>>>(Xc, Kc, KcT, NC, D);

    // 3: S = Qp*Kc^T*scale (bf16)
    gemm_bt<bf16, false><<<dim3(NC / 128, NP / 128, B), dim3(256), 0, stream>>>(
        Qp, Kc, S, NP, NC, D, (long)NP * D, (long)NC * D, (long)NP * NC,
        SCALE, B, 1, nullptr);
    // 4: one-pass row+col stat partials from S
    stats_both<<<dim3(NC / 64, NP / 256, B), dim3(256), 0, stream>>>(S, rp, cp);
    // 5: finalize thr/max; zero denoms
    stats_final<<<dim3((B * NP + B * NC) / 256), dim3(256), 0, stream>>>(
        rp, cp, row_tm, col_tm, d1, d2);
    // 6: merged softmax -> A1u (row-major) + A2u (transposed), denoms via atomics
    softmax_merged<<<dim3(NC / 64, NP / 256, B), dim3(256), 0, stream>>>(
        S, row_tm, col_tm, d1, d2, A1u, A2u);
    // 7: H1u = A1u * Kc            [B,NP,D] bf16 (unnormalized; 1/d1 folded into step 10)
    gemm_bt<bf16, false><<<dim3(D / 128, NP / 128, B), dim3(256), 0, stream>>>(
        A1u, KcT, H1u, NP, D, NC, (long)NP * NC, (long)D * NC, (long)NP * D,
        1.0f, B, 1, nullptr);
    // 8: Hp = A2u * Xp partials    [4][B,NC,D] fp32, 4-way split-K
    gemm_bt<float, false><<<dim3(D / 128, NC / 128, 4 * B), dim3(256), 0, stream>>>(
        A2u, XpT, Hp, NC, D, NP, (long)NC * NP, (long)D * NP, (long)NC * D,
        1.0f, B, 4, nullptr);
    // 9: H2 = sum(Hp) / d2 -> bf16
    {
        long n = (long)B * NC * D;
        reduce_scale_bf16<<<dim3((n / 4 + 255) / 256), dim3(256), 0, stream>>>(
            Hp, d2, H2, n / 4, n);
    }
    // 10: out = diag(1/d1) * H1u * H2^T   [B,NP,NC] fp32
    gemm_bt<float, true><<<dim3(NC / 128, NP / 128, B), dim3(256), 0, stream>>>(
        H1u, H2, out, NP, NC, D, (long)NP * D, (long)NC * D, (long)NP * NC,
        1.0f, B, 1, d1);
}

// Round 3
// 280.588 us; speedup vs baseline: 1.0625x; 1.0093x over previous
//
#include <hip/hip_runtime.h>
#include <hip/hip_bf16.h>

using bf16 = __hip_bfloat16;
typedef __attribute__((ext_vector_type(8))) short short8;   // 8 bf16 (4 VGPRs)
typedef __attribute__((ext_vector_type(4))) float floatx4;  // MFMA C/D frag

#define NPn 4096
#define NCn 1024
#define Dn  512
#define Bn  4

__device__ __forceinline__ float b2f(short s) {
    union { unsigned u; float f; } cv;
    cv.u = ((unsigned)(unsigned short)s) << 16;
    return cv.f;
}

// ---------------------------------------------------------------------------
// async global->LDS, 16B per lane. LDS dest = (wave-uniform base) + lane*16B.
// ---------------------------------------------------------------------------
__device__ __forceinline__ void async_copy16(const bf16* g, bf16* l) {
    __builtin_amdgcn_global_load_lds(
        (const __attribute__((address_space(1))) unsigned int*)g,
        (__attribute__((address_space(3))) unsigned int*)l,
        16, 0, 0);
}

// ---------------------------------------------------------------------------
// C[M x N] = scale * A[M x K] * Bt[N x K]^T  (both row-major bf16)
// 128x128 tile, BK=32, 4 waves 2x2, 4x4 mfma_f32_16x16x32_bf16 per wave.
// Round-3: T4 counted-vmcnt pipeline. 3 LDS buffers, stage 2 tiles ahead,
// raw s_barrier + asm s_waitcnt vmcnt(8) in steady state (4/0 only in the
// two tail iters) -> prefetch stays in flight across barriers, no per-iter
// vmcnt(0) drain. Barrier edges:
//   B2(t-1) guarantees all reads of buf[(t+2)%3] (tile t-1) done before
//   iter t's stage(t+2) overwrites it; vmcnt(K)+B1 guarantees every wave's
//   stage(t) loads landed before any wave ds_reads buf[t%3].
// RS: multiply output row rr by 1/rsc[b*M+rr] (folded softmax normalization).
// Split-K: z = s*nbat + b; partial slot s at C + z*strideC.
// ---------------------------------------------------------------------------
template <typename OutT, bool RS>
__global__ __launch_bounds__(256) void gemm_bt(
    const bf16* __restrict__ A, const bf16* __restrict__ B, OutT* __restrict__ C,
    int M, int N, int K, long strideA, long strideB, long strideC,
    float scale, int nbat, int splits, const float* __restrict__ rsc)
{
    const int z = blockIdx.z;
    const int b = z % nbat;
    const int s = z / nbat;
    const int klen = K / splits;
    const int k0 = s * klen;

    A += (long)b * strideA;
    B += (long)b * strideB;
    C += (long)z * strideC;

    // XCD-aware bijective swizzle of the (bx,by) plane (m204).
    const int nwg = gridDim.x * gridDim.y;
    const int orig = blockIdx.y * gridDim.x + blockIdx.x;
    const int q = nwg >> 3, r = nwg & 7;
    const int xcd = orig & 7, pos = orig >> 3;
    const int nid = (xcd < r ? xcd * (q + 1) : r * (q + 1) + (xcd - r) * q) + pos;
    const int bxs = nid % gridDim.x;
    const int bys = nid / gridDim.x;

    const int bm = bys * 128;
    const int bn = bxs * 128;
    const int tid = threadIdx.x;
    const int lane = tid & 63;
    const int wave = tid >> 6;
    const int wm = (wave >> 1) * 64;
    const int wn = (wave & 1) * 64;

    __shared__ bf16 As[3][128][32];
    __shared__ bf16 Bs[3][128][32];

    floatx4 acc[4][4];
#pragma unroll
    for (int i = 0; i < 4; i++)
#pragma unroll
        for (int j = 0; j < 4; j++) acc[i][j] = (floatx4)(0.0f);

    const int srow = lane >> 2;
    const int scol = (lane & 3) * 8;
    const int mrow = lane & 15;
    const int krow = (lane >> 4) * 8;

    const bf16* Arow = A + (long)(bm + wave * 32 + srow) * K + scol;
    const bf16* Brow = B + (long)(bn + wave * 32 + srow) * K + scol;

    // per-wave stage of one BK=32 tile pair into LDS buffer `buf`
    auto stage = [&](int kb, int buf) {
        const bf16* Ag = Arow + kb;
        const bf16* Bg = Brow + kb;
        async_copy16(Ag,           &As[buf][wave * 32][0]);
        async_copy16(Ag + 16L * K, &As[buf][wave * 32 + 16][0]);
        async_copy16(Bg,           &Bs[buf][wave * 32][0]);
        async_copy16(Bg + 16L * K, &Bs[buf][wave * 32 + 16][0]);
    };

    auto compute = [&](int buf) {
        short8 af[4], bfr[4];
#pragma unroll
        for (int i = 0; i < 4; i++)
            af[i] = *(const short8*)(&As[buf][wm + i * 16 + mrow][krow]);
#pragma unroll
        for (int j = 0; j < 4; j++)
            bfr[j] = *(const short8*)(&Bs[buf][wn + j * 16 + mrow][krow]);
#pragma unroll
        for (int i = 0; i < 4; i++)
#pragma unroll
            for (int j = 0; j < 4; j++)
                acc[i][j] = __builtin_amdgcn_mfma_f32_16x16x32_bf16(
                    af[i], bfr[j], acc[i][j], 0, 0, 0);
    };

    const int nt = klen / 32;
    // prologue: stage tiles 0 and 1
    stage(k0, 0);
    if (nt > 1) stage(k0 + 32, 1);

    int cur = 0;
    for (int t = 0; t < nt; ++t) {
        if (t + 2 < nt) {
            // overwrites buf[(cur+2)%3], whose tile-(t-1) reads completed
            // before B2 of iter t-1.
            int nb = cur + 2; if (nb >= 3) nb -= 3;
            stage(k0 + (t + 2) * 32, nb);
            // wave's outstanding vm ops: stages t,t+1,t+2 = 12; <=8 left
            // means stage(t)'s 4 loads retired (vmcnt retires in order).
            asm volatile("s_waitcnt vmcnt(8)" ::: "memory");
        } else if (t + 1 < nt) {
            asm volatile("s_waitcnt vmcnt(4)" ::: "memory");
        } else {
            asm volatile("s_waitcnt vmcnt(0)" ::: "memory");
        }
        __builtin_amdgcn_s_barrier();   // everyone's stage(t) landed
        compute(cur);
        asm volatile("s_waitcnt lgkmcnt(0)" ::: "memory");
        __builtin_amdgcn_s_barrier();   // all reads of buf[t%3] done
        cur = cur == 2 ? 0 : cur + 1;
    }

    const int crow = (lane >> 4) * 4;
    const int ccol = lane & 15;
    float inv_[4][4];
#pragma unroll
    for (int i = 0; i < 4; i++)
#pragma unroll
        for (int r2 = 0; r2 < 4; r2++) {
            if constexpr (RS)
                inv_[i][r2] = 1.0f / rsc[(long)b * M + bm + wm + i * 16 + crow + r2];
            else
                inv_[i][r2] = 1.0f;
        }
#pragma unroll
    for (int i = 0; i < 4; i++) {
#pragma unroll
        for (int j = 0; j < 4; j++) {
#pragma unroll
            for (int r2 = 0; r2 < 4; r2++) {
                long rr = bm + wm + i * 16 + crow + r2;
                long cc = bn + wn + j * 16 + ccol;
                float v = acc[i][j][r2] * scale * inv_[i][r2];
                if constexpr (__is_same(OutT, float))
                    C[rr * (long)N + cc] = v;
                else
                    C[rr * (long)N + cc] = __float2bfloat16(v);
            }
        }
    }
}

// ---------------------------------------------------------------------------
// One pass over S (bf16) producing BOTH row and col stat partials.
// Tile 256 rows x 64 cols, grid (NC/64, NP/256, B). Per-block unique slots:
//   rp[(b*16+bx)*NP + row] = (sum,sq,max) over this block's 64 cols
//   cp[(b*16+by)*NC + col] = (sum,sq,max) over this block's 256 rows
// ---------------------------------------------------------------------------
__global__ __launch_bounds__(256) void stats_both(
    const bf16* __restrict__ S, float4* __restrict__ rp, float4* __restrict__ cp)
{
    const int b = blockIdx.z, c0 = blockIdx.x * 64, p0 = blockIdx.y * 256;
    const int tid = threadIdx.x;
    const int rt = tid >> 3;          // 0..31 rows per pass
    const int ct = (tid & 7) * 8;     // 8 cols per thread

    float cs[8], cq[8], cm[8];
#pragma unroll
    for (int t = 0; t < 8; t++) { cs[t] = 0.f; cq[t] = 0.f; cm[t] = -3.4e38f; }

#pragma unroll
    for (int pass = 0; pass < 8; pass++) {
        const int p = p0 + pass * 32 + rt;
        const long sidx = ((long)(b * NPn + p)) * NCn + c0 + ct;
        short8 sv = *(const short8*)(S + sidx);
        float rs = 0.f, rq = 0.f, rm = -3.4e38f;
#pragma unroll
        for (int t = 0; t < 8; t++) {
            float x = b2f(sv[t]);
            rs += x; rq += x * x; rm = fmaxf(rm, x);
            cs[t] += x; cq[t] += x * x; cm[t] = fmaxf(cm[t], x);
        }
        // reduce over the 8 lanes covering this row
#pragma unroll
        for (int m = 1; m < 8; m <<= 1) {
            rs += __shfl_xor(rs, m);
            rq += __shfl_xor(rq, m);
            rm = fmaxf(rm, __shfl_xor(rm, m));
        }
        if ((tid & 7) == 0)
            rp[((long)(b * 16 + blockIdx.x)) * NPn + p] = make_float4(rs, rq, rm, 0.f);
    }

    // col partials: reduce across rt within wave (xor 8,16,32), then LDS across waves
#pragma unroll
    for (int m = 8; m < 64; m <<= 1)
#pragma unroll
        for (int t = 0; t < 8; t++) {
            cs[t] += __shfl_xor(cs[t], m);
            cq[t] += __shfl_xor(cq[t], m);
            cm[t] = fmaxf(cm[t], __shfl_xor(cm[t], m));
        }
    __shared__ float LS[4][64], LQ[4][64], LM[4][64];
    const int lane = tid & 63, wave = tid >> 6;
    if (lane < 8)
#pragma unroll
        for (int t = 0; t < 8; t++) {
            LS[wave][lane * 8 + t] = cs[t];
            LQ[wave][lane * 8 + t] = cq[t];
            LM[wave][lane * 8 + t] = cm[t];
        }
    __syncthreads();
    if (tid < 64) {
        float s0 = LS[0][tid] + LS[1][tid] + LS[2][tid] + LS[3][tid];
        float q0 = LQ[0][tid] + LQ[1][tid] + LQ[2][tid] + LQ[3][tid];
        float m0 = fmaxf(fmaxf(LM[0][tid], LM[1][tid]), fmaxf(LM[2][tid], LM[3][tid]));
        cp[((long)(b * 16 + blockIdx.y)) * NCn + c0 + tid] = make_float4(s0, q0, m0, 0.f);
    }
}

// ---------------------------------------------------------------------------
// Finalize stats: rows (B*NP entries, reduce 16 partials, N=NC) then cols
// (B*NC entries, reduce 16 partials, N=NP). thr = mean + std(ddof=1)/8.
// Also zeros d1/d2 (denominator accumulators).
// ---------------------------------------------------------------------------
__global__ __launch_bounds__(256) void stats_final(
    const float4* __restrict__ rp, const float4* __restrict__ cp,
    float2* __restrict__ row_tm, float2* __restrict__ col_tm,
    float* __restrict__ d1, float* __restrict__ d2)
{
    int idx = blockIdx.x * 256 + threadIdx.x;   // 0 .. B*NP + B*NC - 1
    if (idx < Bn * NPn) {
        int b = idx >> 12, p = idx & (NPn - 1);
        float s = 0.f, q = 0.f, m = -3.4e38f;
#pragma unroll
        for (int i = 0; i < 16; i++) {
            float4 v = rp[((long)(b * 16 + i)) * NPn + p];
            s += v.x; q += v.y; m = fmaxf(m, v.z);
        }
        float mean = s * (1.0f / NCn);
        float var = fmaxf((q - (float)NCn * mean * mean) * (1.0f / (NCn - 1)), 0.0f);
        row_tm[idx] = make_float2(mean + sqrtf(var) * 0.125f, m);
        d1[idx] = 0.f;
    } else {
        int cidx = idx - Bn * NPn;
        int b = cidx >> 10, c = cidx & (NCn - 1);
        float s = 0.f, q = 0.f, m = -3.4e38f;
#pragma unroll
        for (int i = 0; i < 16; i++) {
            float4 v = cp[((long)(b * 16 + i)) * NCn + c];
            s += v.x; q += v.y; m = fmaxf(m, v.z);
        }
        float mean = s * (1.0f / NPn);
        float var = fmaxf((q - (float)NPn * mean * mean) * (1.0f / (NPn - 1)), 0.0f);
        col_tm[cidx] = make_float2(mean + sqrtf(var) * 0.125f, m);
        d2[cidx] = 0.f;
    }
}

// ---------------------------------------------------------------------------
// Merged masked softmax: one read of S (bf16) produces
//   A1u[p][c] = (s>=thr_r[p]) ? exp(s-mx_r[p]) : 0    (row-major, unnormalized)
//   A2u[c][p] = (s>=thr_c[c]) ? exp(s-mx_c[c]) : 0    (transposed via LDS)
// d1[p], d2[c] accumulated via device atomics; normalization folded downstream.
// Tile: 256 rows x 64 cols. 256 threads.
// ---------------------------------------------------------------------------
__global__ __launch_bounds__(256) void softmax_merged(
    const bf16* __restrict__ S, const float2* __restrict__ row_tm,
    const float2* __restrict__ col_tm, float* __restrict__ d1,
    float* __restrict__ d2, bf16* __restrict__ A1u, bf16* __restrict__ A2u)
{
    const int b = blockIdx.z, c0 = blockIdx.x * 64, p0 = blockIdx.y * 256;
    const int tid = threadIdx.x;
    const int rt = tid >> 3;          // 0..31 row within pass
    const int ct = (tid & 7) * 8;     // col offset, 8 cols per thread

    __shared__ float T[64][265];      // transposed e2 staging
    __shared__ float dw2[4][64];      // per-wave col-denom partials

    float2 ctm[8];
#pragma unroll
    for (int t = 0; t < 8; t++) ctm[t] = col_tm[b * NCn + c0 + ct + t];

    float d2acc[8];
#pragma unroll
    for (int t = 0; t < 8; t++) d2acc[t] = 0.f;

#pragma unroll
    for (int pass = 0; pass < 8; pass++) {
        const int p = p0 + pass * 32 + rt;
        const float2 rtm = row_tm[b * NPn + p];
        const long sidx = ((long)(b * NPn + p)) * NCn + c0 + ct;
        short8 sv = *(const short8*)(S + sidx);
        bf16 o1[8] __attribute__((aligned(16)));
        float e1s = 0.f;
#pragma unroll
        for (int t = 0; t < 8; t++) {
            float x = b2f(sv[t]);
            float e1 = (x >= rtm.x) ? __expf(x - rtm.y) : 0.0f;
            o1[t] = __float2bfloat16(e1);
            e1s += e1;
            float e2 = (x >= ctm[t].x) ? __expf(x - ctm[t].y) : 0.0f;
            d2acc[t] += e2;
            T[ct + t][pass * 32 + rt] = e2;
        }
        *(short8*)(A1u + sidx) = *(const short8*)o1;
        e1s += __shfl_xor(e1s, 1);
        e1s += __shfl_xor(e1s, 2);
        e1s += __shfl_xor(e1s, 4);
        if ((tid & 7) == 0) atomicAdd(&d1[b * NPn + p], e1s);
    }

    // col denominators: reduce d2acc across rt within wave, then LDS
#pragma unroll
    for (int m = 8; m < 64; m <<= 1)
#pragma unroll
        for (int t = 0; t < 8; t++) d2acc[t] += __shfl_xor(d2acc[t], m);
    const int lane = tid & 63, wave = tid >> 6;
    if (lane < 8)
#pragma unroll
        for (int t = 0; t < 8; t++) dw2[wave][lane * 8 + t] = d2acc[t];
    __syncthreads();
    if (tid < 64)
        atomicAdd(&d2[b * NCn + c0 + tid],
                  dw2[0][tid] + dw2[1][tid] + dw2[2][tid] + dw2[3][tid]);

    // write A2u (transposed tile) from LDS
    const int c = tid >> 2, pb = (tid & 3) * 64;
    bf16* dst = A2u + ((long)(b * NCn + c0 + c)) * NPn + p0 + pb;
#pragma unroll
    for (int u = 0; u < 8; u++) {
        bf16 tmp[8] __attribute__((aligned(16)));
#pragma unroll
        for (int w = 0; w < 8; w++)
            tmp[w] = __float2bfloat16(T[c][pb + u * 8 + w]);
        *(short8*)(dst + u * 8) = *(const short8*)tmp;
    }
}

// ---------------------------------------------------------------------------
// Sum 4 split-K fp32 partials, scale row (b*NC+c) by 1/d2 -> bf16
// ---------------------------------------------------------------------------
__global__ __launch_bounds__(256) void reduce_scale_bf16(
    const float* __restrict__ Pp, const float* __restrict__ d2,
    bf16* __restrict__ out, long n4, long stride)
{
    long i = (long)blockIdx.x * 256 + threadIdx.x;
    if (i < n4) {
        float4 a = ((const float4*)Pp)[i];
#pragma unroll
        for (int s = 1; s < 4; s++) {
            float4 v = ((const float4*)(Pp + (long)s * stride))[i];
            a.x += v.x; a.y += v.y; a.z += v.z; a.w += v.w;
        }
        float inv = 1.0f / d2[i / (Dn / 4)];
        out[i * 4 + 0] = __float2bfloat16(a.x * inv);
        out[i * 4 + 1] = __float2bfloat16(a.y * inv);
        out[i * 4 + 2] = __float2bfloat16(a.z * inv);
        out[i * 4 + 3] = __float2bfloat16(a.w * inv);
    }
}

// ---------------------------------------------------------------------------
// fp32 [R x C] -> bf16 row-major copy AND bf16 [C x R] transpose, batched z.
// ---------------------------------------------------------------------------
__global__ __launch_bounds__(256) void cvt_both(
    const float* __restrict__ in, bf16* __restrict__ out_rm,
    bf16* __restrict__ out_t, int R, int C)
{
    __shared__ float tile[32][33];
    const long boff = (long)blockIdx.z * (long)R * C;
    in += boff; out_rm += boff; out_t += boff;
    const int c0 = blockIdx.x * 32, r0 = blockIdx.y * 32;
    const int tx = threadIdx.x, ty = threadIdx.y;
#pragma unroll
    for (int i = ty; i < 32; i += 8) {
        float x = in[(long)(r0 + i) * C + c0 + tx];
        tile[i][tx] = x;
        out_rm[(long)(r0 + i) * C + c0 + tx] = __float2bfloat16(x);
    }
    __syncthreads();
#pragma unroll
    for (int i = ty; i < 32; i += 8)
        out_t[(long)(c0 + i) * R + r0 + tx] = __float2bfloat16(tile[tx][i]);
}

// ---------------------------------------------------------------------------
extern "C" void kernel_launch(void* const* d_in, const int* in_sizes, int n_in,
                              void* d_out, int out_size, void* d_ws, size_t ws_size,
                              hipStream_t stream)
{
    const float* Xp = (const float*)d_in[0];  // [4,4096,512]
    const float* Xc = (const float*)d_in[1];  // [4,1024,512]
    float* out = (float*)d_out;               // [4,4096,1024]

    constexpr int B = Bn, NP = NPn, NC = NCn, D = Dn;
    constexpr float SCALE = 0.044194173824159216f;  // 1/sqrt(512)

    // workspace layout (bytes), ~164 MB
    char* ws = (char*)d_ws;
    bf16*   Qp     = (bf16*)(ws);                   // 16.78 MB [B,NP,D]
    bf16*   Kc     = (bf16*)(ws + 16777216);        //  4.19 MB [B,NC,D]
    bf16*   KcT    = (bf16*)(ws + 20971520);        //  4.19 MB [B,D,NC]
    bf16*   XpT    = (bf16*)(ws + 25165824);        // 16.78 MB [B,D,NP]
    bf16*   S      = (bf16*)(ws + 41943040);        // 33.55 MB [B,NP,NC]; later Hp overlays
    bf16*   A1u    = (bf16*)(ws + 75497472);        // 33.55 MB [B,NP,NC]
    bf16*   A2u    = (bf16*)(ws + 109051904);       // 33.55 MB [B,NC,NP]; rp/cp overlay pre-softmax
    bf16*   H1u    = (bf16*)(ws + 142606336);       // 16.78 MB [B,NP,D]
    bf16*   H2     = (bf16*)(ws + 159383552);       //  4.19 MB [B,NC,D]
    float2* row_tm = (float2*)(ws + 163577856);     // 128 KB  [B*NP]
    float2* col_tm = (float2*)(ws + 163708928);     //  32 KB  [B*NC]
    float*  d1     = (float*)(ws + 163741696);      //  64 KB  [B*NP]
    float*  d2     = (float*)(ws + 163807232);      //  16 KB  [B*NC]
    // stat partials overlay A2u (dead until softmax_merged; consumed by stats_final)
    float4* rp     = (float4*)A2u;                  //  4.19 MB [B*16,NP]
    float4* cp     = (float4*)(ws + 109051904 + 4194304);  // 1.05 MB [B*16,NC]
    float*  Hp     = (float*)S;                     // split-K partials [4][B,NC,D] fp32 (S dead)

    // 1-2: convert + transpose inputs (one read of fp32 each)
    cvt_both<<<dim3(D / 32, NP / 32, B), dim3(32, 8), 0, stream>>>(Xp, Qp, XpT, NP, D);
    cvt_both<<<dim3(D / 32, NC / 32, B), dim3(32, 8), 0, stream>>>(Xc, Kc, KcT, NC, D);

    // 3: S = Qp*Kc^T*scale (bf16)
    gemm_bt<bf16, false><<<dim3(NC / 128, NP / 128, B), dim3(256), 0, stream>>>(
        Qp, Kc, S, NP, NC, D, (long)NP * D, (long)NC * D, (long)NP * NC,
        SCALE, B, 1, nullptr);
    // 4: one-pass row+col stat partials from S
    stats_both<<<dim3(NC / 64, NP / 256, B), dim3(256), 0, stream>>>(S, rp, cp);
    // 5: finalize thr/max; zero denoms
    stats_final<<<dim3((B * NP + B * NC) / 256), dim3(256), 0, stream>>>(
        rp, cp, row_tm, col_tm, d1, d2);
    // 6: merged softmax -> A1u (row-major) + A2u (transposed), denoms via atomics
    softmax_merged<<<dim3(NC / 64, NP / 256, B), dim3(256), 0, stream>>>(
        S, row_tm, col_tm, d1, d2, A1u, A2u);
    // 7: H1u = A1u * Kc            [B,NP,D] bf16 (unnormalized; 1/d1 folded into step 10)
    gemm_bt<bf16, false><<<dim3(D / 128, NP / 128, B), dim3(256), 0, stream>>>(
        A1u, KcT, H1u, NP, D, NC, (long)NP * NC, (long)D * NC, (long)NP * D,
        1.0f, B, 1, nullptr);
    // 8: Hp = A2u * Xp partials    [4][B,NC,D] fp32, 4-way split-K
    gemm_bt<float, false><<<dim3(D / 128, NC / 128, 4 * B), dim3(256), 0, stream>>>(
        A2u, XpT, Hp, NC, D, NP, (long)NC * NP, (long)D * NP, (long)NC * D,
        1.0f, B, 4, nullptr);
    // 9: H2 = sum(Hp) / d2 -> bf16
    {
        long n = (long)B * NC * D;
        reduce_scale_bf16<<<dim3((n / 4 + 255) / 256), dim3(256), 0, stream>>>(
            Hp, d2, H2, n / 4, n);
    }
    // 10: out = diag(1/d1) * H1u * H2^T   [B,NP,NC] fp32
    gemm_bt<float, true><<<dim3(NC / 128, NP / 128, B), dim3(256), 0, stream>>>(
        H1u, H2, out, NP, NC, D, (long)NP * D, (long)NC * D, (long)NP * NC,
        1.0f, B, 1, d1);
}

// Round 4
// 267.754 us; speedup vs baseline: 1.1135x; 1.0479x over previous
//
#include <hip/hip_runtime.h>
#include <hip/hip_bf16.h>

using bf16 = __hip_bfloat16;
typedef __attribute__((ext_vector_type(8))) short short8;   // 8 bf16 (4 VGPRs)
typedef __attribute__((ext_vector_type(4))) float floatx4;  // MFMA C/D frag

#define NPn 4096
#define NCn 1024
#define Dn  512
#define Bn  4

__device__ __forceinline__ float b2f(short s) {
    union { unsigned u; float f; } cv;
    cv.u = ((unsigned)(unsigned short)s) << 16;
    return cv.f;
}

// ---------------------------------------------------------------------------
// async global->LDS, 16B per lane. LDS dest = (wave-uniform base) + lane*16B.
// ---------------------------------------------------------------------------
__device__ __forceinline__ void async_copy16(const bf16* g, bf16* l) {
    __builtin_amdgcn_global_load_lds(
        (const __attribute__((address_space(1))) unsigned int*)g,
        (__attribute__((address_space(3))) unsigned int*)l,
        16, 0, 0);
}

#define SBAR()  __builtin_amdgcn_s_barrier()
#define SCHED0() __builtin_amdgcn_sched_barrier(0)

// ---------------------------------------------------------------------------
// 256x256-tile 8-phase GEMM (T2+T3+T4+T5 port of the m201 template).
// C[M x N] = scale * A[M x K] * Bt[N x K]^T, row-major bf16 in, OutT out.
// 512 threads = 8 waves as 2(M) x 4(N); per-wave output 128x64 = acc[8][4].
// K consumed in BK=64 tiles, each as two k-32 halves (ks=0,1).
// LDS [buf][ks][256][32] bf16, 128 KB total, double buffered.
//
// Swizzle (T2, both-sides): within each 64B half-row, 16B-chunk index is
// XORed with (row&3). Staging pre-swizzles the GLOBAL source chunk
// (global_load_lds dest stays linear); ds_read applies the same XOR.
// 8-way -> 4-way bank conflict on the b128 fragment reads.
//
// Phase schedule per K-tile t (cur=t&1, nxt=cur^1), per-thread load ledger
// (each stage op = 2 global_load_lds per thread, vm ops retire in order):
//  P0: ds_read A(k0,m0..3)+B(k0,n0..3)[8]; stage A-klo(t+1)->nxt;
//      barrier; lgkm0; MFMA m0..3 k0; barrier
//  P1: ds_read A(k0,m4..7)[4]; stage B-klo(t+1);
//      vmcnt(4)  [in flight: A-khi(t),B-khi(t),A-klo(t+1),B-klo(t+1) = 8;
//                 retires t's khi -> safe for P2's ds_reads]
//      barrier; lgkm0; MFMA m4..7 k0; barrier
//  P2: ds_read A(k1,m0..3)+B(k1)[8]; stage A-khi(t+1);
//      barrier; lgkm0; MFMA m0..3 k1; barrier
//  P3: ds_read A(k1,m4..7)[4]; stage B-khi(t+1);
//      vmcnt(4)  [in flight: klo(t+1) 4 + khi(t+1) 4; retires t+1's klo]
//      barrier; lgkm0; MFMA m4..7 k1; barrier
// vmcnt never drains to 0 in the main loop (T4). Last tile peeled: no
// staging, vmcnt(0) at its P1 (only its khi can be outstanding).
// ---------------------------------------------------------------------------
template <typename OutT, bool RS>
__global__ __launch_bounds__(512) void gemm256(
    const bf16* __restrict__ A, const bf16* __restrict__ B, OutT* __restrict__ C,
    int M, int N, int K, long strideA, long strideB, long strideC,
    float scale, int nbat, const float* __restrict__ rsc)
{
    const int z = blockIdx.z;
    const int b = z % nbat;
    A += (long)b * strideA;
    B += (long)b * strideB;
    C += (long)z * strideC;

    // XCD-aware bijective swizzle of the (bx,by) plane (m204).
    const int nwg = gridDim.x * gridDim.y;
    const int orig = blockIdx.y * gridDim.x + blockIdx.x;
    const int q = nwg >> 3, r = nwg & 7;
    const int xcd = orig & 7, pos = orig >> 3;
    const int nid = (xcd < r ? xcd * (q + 1) : r * (q + 1) + (xcd - r) * q) + pos;
    const int bm = (nid / gridDim.x) * 256;
    const int bn = (nid % gridDim.x) * 256;

    const int tid = threadIdx.x;
    const int lane = tid & 63;
    const int wave = tid >> 6;                 // 0..7
    const int wm2 = (wave >> 2) * 128;         // wave's M offset (0/128)
    const int wn2 = (wave & 3) * 64;           // wave's N offset (0/64/128/192)
    const int mrow = lane & 15;
    const int g = lane >> 4;                   // k-chunk group 0..3

    __shared__ bf16 Asl[2][2][256][32];        // [buf][ks][row][col] 64 KB
    __shared__ bf16 Bsl[2][2][256][32];        // 64 KB

    floatx4 acc[8][4];
#pragma unroll
    for (int i = 0; i < 8; i++)
#pragma unroll
        for (int j = 0; j < 4; j++) acc[i][j] = (floatx4)(0.0f);

    // stage one [256 x 32] half (ks) of A or B tile (k base kb) into buf.
    // slot s in 0..1023: row = s>>2 (two batches of 128), chunk c = s&3.
    // LDS linear: byte = s*16  ->  global source chunk = c ^ (row&3).
    const int s0 = wave * 64 + lane;
    const int sr = s0 >> 2, sc = s0 & 3;
    auto stageA = [&](int kb, int ks, int buf) {
        const int cg = (sc ^ (sr & 3)) * 8;
        const bf16* src0 = A + (long)(bm + sr) * K + kb + ks * 32 + cg;
        const bf16* src1 = A + (long)(bm + sr + 128) * K + kb + ks * 32 + cg;
        bf16* base = &Asl[buf][ks][0][0];
        async_copy16(src0, base + wave * 512);
        async_copy16(src1, base + 4096 + wave * 512);
    };
    auto stageB = [&](int kb, int ks, int buf) {
        const int cg = (sc ^ (sr & 3)) * 8;
        const bf16* src0 = B + (long)(bn + sr) * K + kb + ks * 32 + cg;
        const bf16* src1 = B + (long)(bn + sr + 128) * K + kb + ks * 32 + cg;
        bf16* base = &Bsl[buf][ks][0][0];
        async_copy16(src0, base + wave * 512);
        async_copy16(src1, base + 4096 + wave * 512);
    };
    auto ldA = [&](int buf, int ks, int mi) -> short8 {
        const int row = wm2 + mi * 16 + mrow;
        const int cc = (g ^ (row & 3)) * 8;
        return *(const short8*)(&Asl[buf][ks][row][cc]);
    };
    auto ldB = [&](int buf, int ks, int ni) -> short8 {
        const int row = wn2 + ni * 16 + mrow;
        const int cc = (g ^ (row & 3)) * 8;
        return *(const short8*)(&Bsl[buf][ks][row][cc]);
    };

#define MFMA_GRP(MS)                                                          \
    do {                                                                      \
        _Pragma("unroll") for (int i = 0; i < 4; i++)                         \
            _Pragma("unroll") for (int j = 0; j < 4; j++)                     \
                acc[(MS) + i][j] = __builtin_amdgcn_mfma_f32_16x16x32_bf16(   \
                    a[i], bb[j], acc[(MS) + i][j], 0, 0, 0);                  \
    } while (0)

    const int nt = K / 64;
    // prologue: stage tile 0 (klo first, then khi), wait only for klo.
    stageA(0, 0, 0); stageB(0, 0, 0);
    stageA(0, 1, 0); stageB(0, 1, 0);
    asm volatile("s_waitcnt vmcnt(4)" ::: "memory");
    SBAR(); SCHED0();

    int cur = 0;
    for (int t = 0; t < nt - 1; ++t) {
        const int nxt = cur ^ 1;
        const int kb1 = (t + 1) * 64;
        short8 a[4], bb[4];
        // ---- P0 ----
#pragma unroll
        for (int i = 0; i < 4; i++) a[i] = ldA(cur, 0, i);
#pragma unroll
        for (int j = 0; j < 4; j++) bb[j] = ldB(cur, 0, j);
        stageA(kb1, 0, nxt);
        SBAR();
        asm volatile("s_waitcnt lgkmcnt(0)" ::: "memory");
        SCHED0();
        __builtin_amdgcn_s_setprio(1);
        MFMA_GRP(0);
        __builtin_amdgcn_s_setprio(0);
        SCHED0(); SBAR(); SCHED0();
        // ---- P1 ----
#pragma unroll
        for (int i = 0; i < 4; i++) a[i] = ldA(cur, 0, 4 + i);
        stageB(kb1, 0, nxt);
        asm volatile("s_waitcnt vmcnt(4)" ::: "memory");   // t's khi landed
        SBAR();
        asm volatile("s_waitcnt lgkmcnt(0)" ::: "memory");
        SCHED0();
        __builtin_amdgcn_s_setprio(1);
        MFMA_GRP(4);
        __builtin_amdgcn_s_setprio(0);
        SCHED0(); SBAR(); SCHED0();
        // ---- P2 ----
#pragma unroll
        for (int i = 0; i < 4; i++) a[i] = ldA(cur, 1, i);
#pragma unroll
        for (int j = 0; j < 4; j++) bb[j] = ldB(cur, 1, j);
        stageA(kb1, 1, nxt);
        SBAR();
        asm volatile("s_waitcnt lgkmcnt(0)" ::: "memory");
        SCHED0();
        __builtin_amdgcn_s_setprio(1);
        MFMA_GRP(0);
        __builtin_amdgcn_s_setprio(0);
        SCHED0(); SBAR(); SCHED0();
        // ---- P3 ----
#pragma unroll
        for (int i = 0; i < 4; i++) a[i] = ldA(cur, 1, 4 + i);
        stageB(kb1, 1, nxt);
        asm volatile("s_waitcnt vmcnt(4)" ::: "memory");   // t+1's klo landed
        SBAR();
        asm volatile("s_waitcnt lgkmcnt(0)" ::: "memory");
        SCHED0();
        __builtin_amdgcn_s_setprio(1);
        MFMA_GRP(4);
        __builtin_amdgcn_s_setprio(0);
        SCHED0(); SBAR(); SCHED0();
        cur = nxt;
    }
    // ---- last tile (no staging) ----
    {
        short8 a[4], bb[4];
        // P0
#pragma unroll
        for (int i = 0; i < 4; i++) a[i] = ldA(cur, 0, i);
#pragma unroll
        for (int j = 0; j < 4; j++) bb[j] = ldB(cur, 0, j);
        SBAR();
        asm volatile("s_waitcnt lgkmcnt(0)" ::: "memory");
        SCHED0();
        MFMA_GRP(0);
        SCHED0(); SBAR(); SCHED0();
        // P1
#pragma unroll
        for (int i = 0; i < 4; i++) a[i] = ldA(cur, 0, 4 + i);
        asm volatile("s_waitcnt vmcnt(0)" ::: "memory");   // its khi landed
        SBAR();
        asm volatile("s_waitcnt lgkmcnt(0)" ::: "memory");
        SCHED0();
        MFMA_GRP(4);
        SCHED0(); SBAR(); SCHED0();
        // P2
#pragma unroll
        for (int i = 0; i < 4; i++) a[i] = ldA(cur, 1, i);
#pragma unroll
        for (int j = 0; j < 4; j++) bb[j] = ldB(cur, 1, j);
        asm volatile("s_waitcnt lgkmcnt(0)" ::: "memory");
        SCHED0();
        MFMA_GRP(0);
        // P3
#pragma unroll
        for (int i = 0; i < 4; i++) a[i] = ldA(cur, 1, 4 + i);
        asm volatile("s_waitcnt lgkmcnt(0)" ::: "memory");
        SCHED0();
        MFMA_GRP(4);
    }
#undef MFMA_GRP

    // epilogue
    const int crow = (lane >> 4) * 4;
    const int ccol = lane & 15;
    float inv_[8][4];
#pragma unroll
    for (int i = 0; i < 8; i++)
#pragma unroll
        for (int r2 = 0; r2 < 4; r2++) {
            if constexpr (RS)
                inv_[i][r2] = 1.0f / rsc[(long)b * M + bm + wm2 + i * 16 + crow + r2];
            else
                inv_[i][r2] = 1.0f;
        }
#pragma unroll
    for (int i = 0; i < 8; i++) {
#pragma unroll
        for (int j = 0; j < 4; j++) {
#pragma unroll
            for (int r2 = 0; r2 < 4; r2++) {
                long rr = bm + wm2 + i * 16 + crow + r2;
                long cc = bn + wn2 + j * 16 + ccol;
                float v = acc[i][j][r2] * scale * inv_[i][r2];
                if constexpr (__is_same(OutT, float))
                    C[rr * (long)N + cc] = v;
                else
                    C[rr * (long)N + cc] = __float2bfloat16(v);
            }
        }
    }
}

// ---------------------------------------------------------------------------
// C[M x N] = scale * A[M x K] * Bt[N x K]^T  (both row-major bf16)
// 128x128 tile, BK=32, 4 waves 2x2, 4x4 mfma_f32_16x16x32_bf16 per wave.
// 3-buffer counted-vmcnt pipeline (Round 3, verified). Used for the two
// skinny GEMMs (N=512) where the 256-tile grid would underfill the chip.
// ---------------------------------------------------------------------------
template <typename OutT, bool RS>
__global__ __launch_bounds__(256) void gemm_bt(
    const bf16* __restrict__ A, const bf16* __restrict__ B, OutT* __restrict__ C,
    int M, int N, int K, long strideA, long strideB, long strideC,
    float scale, int nbat, int splits, const float* __restrict__ rsc)
{
    const int z = blockIdx.z;
    const int b = z % nbat;
    const int s = z / nbat;
    const int klen = K / splits;
    const int k0 = s * klen;

    A += (long)b * strideA;
    B += (long)b * strideB;
    C += (long)z * strideC;

    const int nwg = gridDim.x * gridDim.y;
    const int orig = blockIdx.y * gridDim.x + blockIdx.x;
    const int q = nwg >> 3, r = nwg & 7;
    const int xcd = orig & 7, pos = orig >> 3;
    const int nid = (xcd < r ? xcd * (q + 1) : r * (q + 1) + (xcd - r) * q) + pos;
    const int bxs = nid % gridDim.x;
    const int bys = nid / gridDim.x;

    const int bm = bys * 128;
    const int bn = bxs * 128;
    const int tid = threadIdx.x;
    const int lane = tid & 63;
    const int wave = tid >> 6;
    const int wm = (wave >> 1) * 64;
    const int wn = (wave & 1) * 64;

    __shared__ bf16 As[3][128][32];
    __shared__ bf16 Bs[3][128][32];

    floatx4 acc[4][4];
#pragma unroll
    for (int i = 0; i < 4; i++)
#pragma unroll
        for (int j = 0; j < 4; j++) acc[i][j] = (floatx4)(0.0f);

    const int srow = lane >> 2;
    const int scol = (lane & 3) * 8;
    const int mrow = lane & 15;
    const int krow = (lane >> 4) * 8;

    const bf16* Arow = A + (long)(bm + wave * 32 + srow) * K + scol;
    const bf16* Brow = B + (long)(bn + wave * 32 + srow) * K + scol;

    auto stage = [&](int kb, int buf) {
        const bf16* Ag = Arow + kb;
        const bf16* Bg = Brow + kb;
        async_copy16(Ag,           &As[buf][wave * 32][0]);
        async_copy16(Ag + 16L * K, &As[buf][wave * 32 + 16][0]);
        async_copy16(Bg,           &Bs[buf][wave * 32][0]);
        async_copy16(Bg + 16L * K, &Bs[buf][wave * 32 + 16][0]);
    };

    auto compute = [&](int buf) {
        short8 af[4], bfr[4];
#pragma unroll
        for (int i = 0; i < 4; i++)
            af[i] = *(const short8*)(&As[buf][wm + i * 16 + mrow][krow]);
#pragma unroll
        for (int j = 0; j < 4; j++)
            bfr[j] = *(const short8*)(&Bs[buf][wn + j * 16 + mrow][krow]);
#pragma unroll
        for (int i = 0; i < 4; i++)
#pragma unroll
            for (int j = 0; j < 4; j++)
                acc[i][j] = __builtin_amdgcn_mfma_f32_16x16x32_bf16(
                    af[i], bfr[j], acc[i][j], 0, 0, 0);
    };

    const int nt = klen / 32;
    stage(k0, 0);
    if (nt > 1) stage(k0 + 32, 1);

    int cur = 0;
    for (int t = 0; t < nt; ++t) {
        if (t + 2 < nt) {
            int nb = cur + 2; if (nb >= 3) nb -= 3;
            stage(k0 + (t + 2) * 32, nb);
            asm volatile("s_waitcnt vmcnt(8)" ::: "memory");
        } else if (t + 1 < nt) {
            asm volatile("s_waitcnt vmcnt(4)" ::: "memory");
        } else {
            asm volatile("s_waitcnt vmcnt(0)" ::: "memory");
        }
        __builtin_amdgcn_s_barrier();
        compute(cur);
        asm volatile("s_waitcnt lgkmcnt(0)" ::: "memory");
        __builtin_amdgcn_s_barrier();
        cur = cur == 2 ? 0 : cur + 1;
    }

    const int crow = (lane >> 4) * 4;
    const int ccol = lane & 15;
    float inv_[4][4];
#pragma unroll
    for (int i = 0; i < 4; i++)
#pragma unroll
        for (int r2 = 0; r2 < 4; r2++) {
            if constexpr (RS)
                inv_[i][r2] = 1.0f / rsc[(long)b * M + bm + wm + i * 16 + crow + r2];
            else
                inv_[i][r2] = 1.0f;
        }
#pragma unroll
    for (int i = 0; i < 4; i++) {
#pragma unroll
        for (int j = 0; j < 4; j++) {
#pragma unroll
            for (int r2 = 0; r2 < 4; r2++) {
                long rr = bm + wm + i * 16 + crow + r2;
                long cc = bn + wn + j * 16 + ccol;
                float v = acc[i][j][r2] * scale * inv_[i][r2];
                if constexpr (__is_same(OutT, float))
                    C[rr * (long)N + cc] = v;
                else
                    C[rr * (long)N + cc] = __float2bfloat16(v);
            }
        }
    }
}

// ---------------------------------------------------------------------------
// One pass over S (bf16) producing BOTH row and col stat partials.
// ---------------------------------------------------------------------------
__global__ __launch_bounds__(256) void stats_both(
    const bf16* __restrict__ S, float4* __restrict__ rp, float4* __restrict__ cp)
{
    const int b = blockIdx.z, c0 = blockIdx.x * 64, p0 = blockIdx.y * 256;
    const int tid = threadIdx.x;
    const int rt = tid >> 3;          // 0..31 rows per pass
    const int ct = (tid & 7) * 8;     // 8 cols per thread

    float cs[8], cq[8], cm[8];
#pragma unroll
    for (int t = 0; t < 8; t++) { cs[t] = 0.f; cq[t] = 0.f; cm[t] = -3.4e38f; }

#pragma unroll
    for (int pass = 0; pass < 8; pass++) {
        const int p = p0 + pass * 32 + rt;
        const long sidx = ((long)(b * NPn + p)) * NCn + c0 + ct;
        short8 sv = *(const short8*)(S + sidx);
        float rs = 0.f, rq = 0.f, rm = -3.4e38f;
#pragma unroll
        for (int t = 0; t < 8; t++) {
            float x = b2f(sv[t]);
            rs += x; rq += x * x; rm = fmaxf(rm, x);
            cs[t] += x; cq[t] += x * x; cm[t] = fmaxf(cm[t], x);
        }
#pragma unroll
        for (int m = 1; m < 8; m <<= 1) {
            rs += __shfl_xor(rs, m);
            rq += __shfl_xor(rq, m);
            rm = fmaxf(rm, __shfl_xor(rm, m));
        }
        if ((tid & 7) == 0)
            rp[((long)(b * 16 + blockIdx.x)) * NPn + p] = make_float4(rs, rq, rm, 0.f);
    }

#pragma unroll
    for (int m = 8; m < 64; m <<= 1)
#pragma unroll
        for (int t = 0; t < 8; t++) {
            cs[t] += __shfl_xor(cs[t], m);
            cq[t] += __shfl_xor(cq[t], m);
            cm[t] = fmaxf(cm[t], __shfl_xor(cm[t], m));
        }
    __shared__ float LS[4][64], LQ[4][64], LM[4][64];
    const int lane = tid & 63, wave = tid >> 6;
    if (lane < 8)
#pragma unroll
        for (int t = 0; t < 8; t++) {
            LS[wave][lane * 8 + t] = cs[t];
            LQ[wave][lane * 8 + t] = cq[t];
            LM[wave][lane * 8 + t] = cm[t];
        }
    __syncthreads();
    if (tid < 64) {
        float s0 = LS[0][tid] + LS[1][tid] + LS[2][tid] + LS[3][tid];
        float q0 = LQ[0][tid] + LQ[1][tid] + LQ[2][tid] + LQ[3][tid];
        float m0 = fmaxf(fmaxf(LM[0][tid], LM[1][tid]), fmaxf(LM[2][tid], LM[3][tid]));
        cp[((long)(b * 16 + blockIdx.y)) * NCn + c0 + tid] = make_float4(s0, q0, m0, 0.f);
    }
}

// ---------------------------------------------------------------------------
// Finalize stats; thr = mean + std(ddof=1)/8. Also zeros d1/d2.
// ---------------------------------------------------------------------------
__global__ __launch_bounds__(256) void stats_final(
    const float4* __restrict__ rp, const float4* __restrict__ cp,
    float2* __restrict__ row_tm, float2* __restrict__ col_tm,
    float* __restrict__ d1, float* __restrict__ d2)
{
    int idx = blockIdx.x * 256 + threadIdx.x;
    if (idx < Bn * NPn) {
        int b = idx >> 12, p = idx & (NPn - 1);
        float s = 0.f, q = 0.f, m = -3.4e38f;
#pragma unroll
        for (int i = 0; i < 16; i++) {
            float4 v = rp[((long)(b * 16 + i)) * NPn + p];
            s += v.x; q += v.y; m = fmaxf(m, v.z);
        }
        float mean = s * (1.0f / NCn);
        float var = fmaxf((q - (float)NCn * mean * mean) * (1.0f / (NCn - 1)), 0.0f);
        row_tm[idx] = make_float2(mean + sqrtf(var) * 0.125f, m);
        d1[idx] = 0.f;
    } else {
        int cidx = idx - Bn * NPn;
        int b = cidx >> 10, c = cidx & (NCn - 1);
        float s = 0.f, q = 0.f, m = -3.4e38f;
#pragma unroll
        for (int i = 0; i < 16; i++) {
            float4 v = cp[((long)(b * 16 + i)) * NCn + c];
            s += v.x; q += v.y; m = fmaxf(m, v.z);
        }
        float mean = s * (1.0f / NPn);
        float var = fmaxf((q - (float)NPn * mean * mean) * (1.0f / (NPn - 1)), 0.0f);
        col_tm[cidx] = make_float2(mean + sqrtf(var) * 0.125f, m);
        d2[cidx] = 0.f;
    }
}

// ---------------------------------------------------------------------------
// Merged masked softmax: one read of S produces A1u (row-major) and A2u
// (transposed); d1/d2 denominators via atomics.
// ---------------------------------------------------------------------------
__global__ __launch_bounds__(256) void softmax_merged(
    const bf16* __restrict__ S, const float2* __restrict__ row_tm,
    const float2* __restrict__ col_tm, float* __restrict__ d1,
    float* __restrict__ d2, bf16* __restrict__ A1u, bf16* __restrict__ A2u)
{
    const int b = blockIdx.z, c0 = blockIdx.x * 64, p0 = blockIdx.y * 256;
    const int tid = threadIdx.x;
    const int rt = tid >> 3;
    const int ct = (tid & 7) * 8;

    __shared__ float T[64][265];
    __shared__ float dw2[4][64];

    float2 ctm[8];
#pragma unroll
    for (int t = 0; t < 8; t++) ctm[t] = col_tm[b * NCn + c0 + ct + t];

    float d2acc[8];
#pragma unroll
    for (int t = 0; t < 8; t++) d2acc[t] = 0.f;

#pragma unroll
    for (int pass = 0; pass < 8; pass++) {
        const int p = p0 + pass * 32 + rt;
        const float2 rtm = row_tm[b * NPn + p];
        const long sidx = ((long)(b * NPn + p)) * NCn + c0 + ct;
        short8 sv = *(const short8*)(S + sidx);
        bf16 o1[8] __attribute__((aligned(16)));
        float e1s = 0.f;
#pragma unroll
        for (int t = 0; t < 8; t++) {
            float x = b2f(sv[t]);
            float e1 = (x >= rtm.x) ? __expf(x - rtm.y) : 0.0f;
            o1[t] = __float2bfloat16(e1);
            e1s += e1;
            float e2 = (x >= ctm[t].x) ? __expf(x - ctm[t].y) : 0.0f;
            d2acc[t] += e2;
            T[ct + t][pass * 32 + rt] = e2;
        }
        *(short8*)(A1u + sidx) = *(const short8*)o1;
        e1s += __shfl_xor(e1s, 1);
        e1s += __shfl_xor(e1s, 2);
        e1s += __shfl_xor(e1s, 4);
        if ((tid & 7) == 0) atomicAdd(&d1[b * NPn + p], e1s);
    }

#pragma unroll
    for (int m = 8; m < 64; m <<= 1)
#pragma unroll
        for (int t = 0; t < 8; t++) d2acc[t] += __shfl_xor(d2acc[t], m);
    const int lane = tid & 63, wave = tid >> 6;
    if (lane < 8)
#pragma unroll
        for (int t = 0; t < 8; t++) dw2[wave][lane * 8 + t] = d2acc[t];
    __syncthreads();
    if (tid < 64)
        atomicAdd(&d2[b * NCn + c0 + tid],
                  dw2[0][tid] + dw2[1][tid] + dw2[2][tid] + dw2[3][tid]);

    const int c = tid >> 2, pb = (tid & 3) * 64;
    bf16* dst = A2u + ((long)(b * NCn + c0 + c)) * NPn + p0 + pb;
#pragma unroll
    for (int u = 0; u < 8; u++) {
        bf16 tmp[8] __attribute__((aligned(16)));
#pragma unroll
        for (int w = 0; w < 8; w++)
            tmp[w] = __float2bfloat16(T[c][pb + u * 8 + w]);
        *(short8*)(dst + u * 8) = *(const short8*)tmp;
    }
}

// ---------------------------------------------------------------------------
// Sum 4 split-K fp32 partials, scale row (b*NC+c) by 1/d2 -> bf16
// ---------------------------------------------------------------------------
__global__ __launch_bounds__(256) void reduce_scale_bf16(
    const float* __restrict__ Pp, const float* __restrict__ d2,
    bf16* __restrict__ out, long n4, long stride)
{
    long i = (long)blockIdx.x * 256 + threadIdx.x;
    if (i < n4) {
        float4 a = ((const float4*)Pp)[i];
#pragma unroll
        for (int s = 1; s < 4; s++) {
            float4 v = ((const float4*)(Pp + (long)s * stride))[i];
            a.x += v.x; a.y += v.y; a.z += v.z; a.w += v.w;
        }
        float inv = 1.0f / d2[i / (Dn / 4)];
        out[i * 4 + 0] = __float2bfloat16(a.x * inv);
        out[i * 4 + 1] = __float2bfloat16(a.y * inv);
        out[i * 4 + 2] = __float2bfloat16(a.z * inv);
        out[i * 4 + 3] = __float2bfloat16(a.w * inv);
    }
}

// ---------------------------------------------------------------------------
// fp32 [R x C] -> bf16 row-major copy AND bf16 [C x R] transpose, batched z.
// ---------------------------------------------------------------------------
__global__ __launch_bounds__(256) void cvt_both(
    const float* __restrict__ in, bf16* __restrict__ out_rm,
    bf16* __restrict__ out_t, int R, int C)
{
    __shared__ float tile[32][33];
    const long boff = (long)blockIdx.z * (long)R * C;
    in += boff; out_rm += boff; out_t += boff;
    const int c0 = blockIdx.x * 32, r0 = blockIdx.y * 32;
    const int tx = threadIdx.x, ty = threadIdx.y;
#pragma unroll
    for (int i = ty; i < 32; i += 8) {
        float x = in[(long)(r0 + i) * C + c0 + tx];
        tile[i][tx] = x;
        out_rm[(long)(r0 + i) * C + c0 + tx] = __float2bfloat16(x);
    }
    __syncthreads();
#pragma unroll
    for (int i = ty; i < 32; i += 8)
        out_t[(long)(c0 + i) * R + r0 + tx] = __float2bfloat16(tile[tx][i]);
}

// ---------------------------------------------------------------------------
extern "C" void kernel_launch(void* const* d_in, const int* in_sizes, int n_in,
                              void* d_out, int out_size, void* d_ws, size_t ws_size,
                              hipStream_t stream)
{
    const float* Xp = (const float*)d_in[0];  // [4,4096,512]
    const float* Xc = (const float*)d_in[1];  // [4,1024,512]
    float* out = (float*)d_out;               // [4,4096,1024]

    constexpr int B = Bn, NP = NPn, NC = NCn, D = Dn;
    constexpr float SCALE = 0.044194173824159216f;  // 1/sqrt(512)

    // workspace layout (bytes), ~164 MB
    char* ws = (char*)d_ws;
    bf16*   Qp     = (bf16*)(ws);                   // 16.78 MB [B,NP,D]
    bf16*   Kc     = (bf16*)(ws + 16777216);        //  4.19 MB [B,NC,D]
    bf16*   KcT    = (bf16*)(ws + 20971520);        //  4.19 MB [B,D,NC]
    bf16*   XpT    = (bf16*)(ws + 25165824);        // 16.78 MB [B,D,NP]
    bf16*   S      = (bf16*)(ws + 41943040);        // 33.55 MB [B,NP,NC]; later Hp overlays
    bf16*   A1u    = (bf16*)(ws + 75497472);        // 33.55 MB [B,NP,NC]
    bf16*   A2u    = (bf16*)(ws + 109051904);       // 33.55 MB [B,NC,NP]; rp/cp overlay pre-softmax
    bf16*   H1u    = (bf16*)(ws + 142606336);       // 16.78 MB [B,NP,D]
    bf16*   H2     = (bf16*)(ws + 159383552);       //  4.19 MB [B,NC,D]
    float2* row_tm = (float2*)(ws + 163577856);     // 128 KB  [B*NP]
    float2* col_tm = (float2*)(ws + 163708928);     //  32 KB  [B*NC]
    float*  d1     = (float*)(ws + 163741696);      //  64 KB  [B*NP]
    float*  d2     = (float*)(ws + 163807232);      //  16 KB  [B*NC]
    float4* rp     = (float4*)A2u;                  //  4.19 MB [B*16,NP]
    float4* cp     = (float4*)(ws + 109051904 + 4194304);  // 1.05 MB [B*16,NC]
    float*  Hp     = (float*)S;                     // split-K partials [4][B,NC,D] fp32 (S dead)

    // 1-2: convert + transpose inputs (one read of fp32 each)
    cvt_both<<<dim3(D / 32, NP / 32, B), dim3(32, 8), 0, stream>>>(Xp, Qp, XpT, NP, D);
    cvt_both<<<dim3(D / 32, NC / 32, B), dim3(32, 8), 0, stream>>>(Xc, Kc, KcT, NC, D);

    // 3: S = Qp*Kc^T*scale (bf16) -- 256-tile 8-phase
    gemm256<bf16, false><<<dim3(NC / 256, NP / 256, B), dim3(512), 0, stream>>>(
        Qp, Kc, S, NP, NC, D, (long)NP * D, (long)NC * D, (long)NP * NC,
        SCALE, B, nullptr);
    // 4: one-pass row+col stat partials from S
    stats_both<<<dim3(NC / 64, NP / 256, B), dim3(256), 0, stream>>>(S, rp, cp);
    // 5: finalize thr/max; zero denoms
    stats_final<<<dim3((B * NP + B * NC) / 256), dim3(256), 0, stream>>>(
        rp, cp, row_tm, col_tm, d1, d2);
    // 6: merged softmax -> A1u + A2u (transposed), denoms via atomics
    softmax_merged<<<dim3(NC / 64, NP / 256, B), dim3(256), 0, stream>>>(
        S, row_tm, col_tm, d1, d2, A1u, A2u);
    // 7: H1u = A1u * Kc            [B,NP,D] bf16 (1/d1 folded into step 10)
    gemm_bt<bf16, false><<<dim3(D / 128, NP / 128, B), dim3(256), 0, stream>>>(
        A1u, KcT, H1u, NP, D, NC, (long)NP * NC, (long)D * NC, (long)NP * D,
        1.0f, B, 1, nullptr);
    // 8: Hp = A2u * Xp partials    [4][B,NC,D] fp32, 4-way split-K
    gemm_bt<float, false><<<dim3(D / 128, NC / 128, 4 * B), dim3(256), 0, stream>>>(
        A2u, XpT, Hp, NC, D, NP, (long)NC * NP, (long)D * NP, (long)NC * D,
        1.0f, B, 4, nullptr);
    // 9: H2 = sum(Hp) / d2 -> bf16
    {
        long n = (long)B * NC * D;
        reduce_scale_bf16<<<dim3((n / 4 + 255) / 256), dim3(256), 0, stream>>>(
            Hp, d2, H2, n / 4, n);
    }
    // 10: out = diag(1/d1) * H1u * H2^T   [B,NP,NC] fp32 -- 256-tile 8-phase
    gemm256<float, true><<<dim3(NC / 256, NP / 256, B), dim3(512), 0, stream>>>(
        H1u, H2, out, NP, NC, D, (long)NP * D, (long)NC * D, (long)NP * NC,
        1.0f, B, d1);
}

// Round 5
// 265.076 us; speedup vs baseline: 1.1247x; 1.0101x over previous
//
#include <hip/hip_runtime.h>
#include <hip/hip_bf16.h>

using bf16 = __hip_bfloat16;
typedef __attribute__((ext_vector_type(8))) short short8;   // 8 bf16 (4 VGPRs)
typedef __attribute__((ext_vector_type(4))) float floatx4;  // MFMA C/D frag

#define NPn 4096
#define NCn 1024
#define Dn  512
#define Bn  4

__device__ __forceinline__ float b2f(short s) {
    union { unsigned u; float f; } cv;
    cv.u = ((unsigned)(unsigned short)s) << 16;
    return cv.f;
}

// ---------------------------------------------------------------------------
// async global->LDS, 16B per lane. LDS dest = (wave-uniform base) + lane*16B.
// ---------------------------------------------------------------------------
__device__ __forceinline__ void async_copy16(const bf16* g, bf16* l) {
    __builtin_amdgcn_global_load_lds(
        (const __attribute__((address_space(1))) unsigned int*)g,
        (__attribute__((address_space(3))) unsigned int*)l,
        16, 0, 0);
}

#define SBAR()  __builtin_amdgcn_s_barrier()
#define SCHED0() __builtin_amdgcn_sched_barrier(0)

// ---------------------------------------------------------------------------
// 256x256-tile 8-phase GEMM (T2+T3+T4+T5 port of the m201 template).
// C[M x N] = scale * A[M x K] * Bt[N x K]^T, row-major bf16 in, OutT out.
// 512 threads = 8 waves as 2(M) x 4(N); per-wave output 128x64 = acc[8][4].
// K consumed in BK=64 tiles, each as two k-32 halves (ks=0,1).
// LDS [buf][ks][256][32] bf16, 128 KB total, double buffered.
// Verified in Round 4 (passed, absmax unchanged).
//
// Swizzle (T2, both-sides): within each 64B half-row, 16B-chunk index is
// XORed with (row&3). Staging pre-swizzles the GLOBAL source chunk
// (global_load_lds dest stays linear); ds_read applies the same XOR.
//
// Per-thread vmcnt ledger (stageA/stageB = 2 ops each, retire in order):
//  prologue stages 8 ops, vmcnt(4) -> klo landed, khi(4) in flight.
//  P0 +2 (A-klo t+1) =6; P1 +2 (B-klo t+1) =8, vmcnt(4) retires t's khi.
//  P2 +2 (A-khi t+1) =6; P3 +2 (B-khi t+1) =8, vmcnt(4) retires t+1's klo.
// vmcnt never 0 in the main loop (T4). Last tile peeled: vmcnt(0) at P1.
// ---------------------------------------------------------------------------
template <typename OutT, bool RS>
__global__ __launch_bounds__(512) void gemm256(
    const bf16* __restrict__ A, const bf16* __restrict__ B, OutT* __restrict__ C,
    int M, int N, int K, long strideA, long strideB, long strideC,
    float scale, int nbat, const float* __restrict__ rsc)
{
    const int z = blockIdx.z;
    const int b = z % nbat;
    A += (long)b * strideA;
    B += (long)b * strideB;
    C += (long)z * strideC;

    // XCD-aware bijective swizzle of the (bx,by) plane (m204).
    const int nwg = gridDim.x * gridDim.y;
    const int orig = blockIdx.y * gridDim.x + blockIdx.x;
    const int q = nwg >> 3, r = nwg & 7;
    const int xcd = orig & 7, pos = orig >> 3;
    const int nid = (xcd < r ? xcd * (q + 1) : r * (q + 1) + (xcd - r) * q) + pos;
    const int bm = (nid / gridDim.x) * 256;
    const int bn = (nid % gridDim.x) * 256;

    const int tid = threadIdx.x;
    const int lane = tid & 63;
    const int wave = tid >> 6;                 // 0..7
    const int wm2 = (wave >> 2) * 128;         // wave's M offset (0/128)
    const int wn2 = (wave & 3) * 64;           // wave's N offset (0/64/128/192)
    const int mrow = lane & 15;
    const int g = lane >> 4;                   // k-chunk group 0..3

    __shared__ bf16 Asl[2][2][256][32];        // [buf][ks][row][col] 64 KB
    __shared__ bf16 Bsl[2][2][256][32];        // 64 KB

    floatx4 acc[8][4];
#pragma unroll
    for (int i = 0; i < 8; i++)
#pragma unroll
        for (int j = 0; j < 4; j++) acc[i][j] = (floatx4)(0.0f);

    const int s0 = wave * 64 + lane;
    const int sr = s0 >> 2, sc = s0 & 3;
    auto stageA = [&](int kb, int ks, int buf) {
        const int cg = (sc ^ (sr & 3)) * 8;
        const bf16* src0 = A + (long)(bm + sr) * K + kb + ks * 32 + cg;
        const bf16* src1 = A + (long)(bm + sr + 128) * K + kb + ks * 32 + cg;
        bf16* base = &Asl[buf][ks][0][0];
        async_copy16(src0, base + wave * 512);
        async_copy16(src1, base + 4096 + wave * 512);
    };
    auto stageB = [&](int kb, int ks, int buf) {
        const int cg = (sc ^ (sr & 3)) * 8;
        const bf16* src0 = B + (long)(bn + sr) * K + kb + ks * 32 + cg;
        const bf16* src1 = B + (long)(bn + sr + 128) * K + kb + ks * 32 + cg;
        bf16* base = &Bsl[buf][ks][0][0];
        async_copy16(src0, base + wave * 512);
        async_copy16(src1, base + 4096 + wave * 512);
    };
    auto ldA = [&](int buf, int ks, int mi) -> short8 {
        const int row = wm2 + mi * 16 + mrow;
        const int cc = (g ^ (row & 3)) * 8;
        return *(const short8*)(&Asl[buf][ks][row][cc]);
    };
    auto ldB = [&](int buf, int ks, int ni) -> short8 {
        const int row = wn2 + ni * 16 + mrow;
        const int cc = (g ^ (row & 3)) * 8;
        return *(const short8*)(&Bsl[buf][ks][row][cc]);
    };

#define MFMA_GRP(MS)                                                          \
    do {                                                                      \
        _Pragma("unroll") for (int i = 0; i < 4; i++)                         \
            _Pragma("unroll") for (int j = 0; j < 4; j++)                     \
                acc[(MS) + i][j] = __builtin_amdgcn_mfma_f32_16x16x32_bf16(   \
                    a[i], bb[j], acc[(MS) + i][j], 0, 0, 0);                  \
    } while (0)

    const int nt = K / 64;
    stageA(0, 0, 0); stageB(0, 0, 0);
    stageA(0, 1, 0); stageB(0, 1, 0);
    asm volatile("s_waitcnt vmcnt(4)" ::: "memory");
    SBAR(); SCHED0();

    int cur = 0;
    for (int t = 0; t < nt - 1; ++t) {
        const int nxt = cur ^ 1;
        const int kb1 = (t + 1) * 64;
        short8 a[4], bb[4];
        // ---- P0 ----
#pragma unroll
        for (int i = 0; i < 4; i++) a[i] = ldA(cur, 0, i);
#pragma unroll
        for (int j = 0; j < 4; j++) bb[j] = ldB(cur, 0, j);
        stageA(kb1, 0, nxt);
        SBAR();
        asm volatile("s_waitcnt lgkmcnt(0)" ::: "memory");
        SCHED0();
        __builtin_amdgcn_s_setprio(1);
        MFMA_GRP(0);
        __builtin_amdgcn_s_setprio(0);
        SCHED0(); SBAR(); SCHED0();
        // ---- P1 ----
#pragma unroll
        for (int i = 0; i < 4; i++) a[i] = ldA(cur, 0, 4 + i);
        stageB(kb1, 0, nxt);
        asm volatile("s_waitcnt vmcnt(4)" ::: "memory");   // t's khi landed
        SBAR();
        asm volatile("s_waitcnt lgkmcnt(0)" ::: "memory");
        SCHED0();
        __builtin_amdgcn_s_setprio(1);
        MFMA_GRP(4);
        __builtin_amdgcn_s_setprio(0);
        SCHED0(); SBAR(); SCHED0();
        // ---- P2 ----
#pragma unroll
        for (int i = 0; i < 4; i++) a[i] = ldA(cur, 1, i);
#pragma unroll
        for (int j = 0; j < 4; j++) bb[j] = ldB(cur, 1, j);
        stageA(kb1, 1, nxt);
        SBAR();
        asm volatile("s_waitcnt lgkmcnt(0)" ::: "memory");
        SCHED0();
        __builtin_amdgcn_s_setprio(1);
        MFMA_GRP(0);
        __builtin_amdgcn_s_setprio(0);
        SCHED0(); SBAR(); SCHED0();
        // ---- P3 ----
#pragma unroll
        for (int i = 0; i < 4; i++) a[i] = ldA(cur, 1, 4 + i);
        stageB(kb1, 1, nxt);
        asm volatile("s_waitcnt vmcnt(4)" ::: "memory");   // t+1's klo landed
        SBAR();
        asm volatile("s_waitcnt lgkmcnt(0)" ::: "memory");
        SCHED0();
        __builtin_amdgcn_s_setprio(1);
        MFMA_GRP(4);
        __builtin_amdgcn_s_setprio(0);
        SCHED0(); SBAR(); SCHED0();
        cur = nxt;
    }
    // ---- last tile (no staging) ----
    {
        short8 a[4], bb[4];
#pragma unroll
        for (int i = 0; i < 4; i++) a[i] = ldA(cur, 0, i);
#pragma unroll
        for (int j = 0; j < 4; j++) bb[j] = ldB(cur, 0, j);
        SBAR();
        asm volatile("s_waitcnt lgkmcnt(0)" ::: "memory");
        SCHED0();
        MFMA_GRP(0);
        SCHED0(); SBAR(); SCHED0();
#pragma unroll
        for (int i = 0; i < 4; i++) a[i] = ldA(cur, 0, 4 + i);
        asm volatile("s_waitcnt vmcnt(0)" ::: "memory");   // its khi landed
        SBAR();
        asm volatile("s_waitcnt lgkmcnt(0)" ::: "memory");
        SCHED0();
        MFMA_GRP(4);
        SCHED0(); SBAR(); SCHED0();
#pragma unroll
        for (int i = 0; i < 4; i++) a[i] = ldA(cur, 1, i);
#pragma unroll
        for (int j = 0; j < 4; j++) bb[j] = ldB(cur, 1, j);
        asm volatile("s_waitcnt lgkmcnt(0)" ::: "memory");
        SCHED0();
        MFMA_GRP(0);
#pragma unroll
        for (int i = 0; i < 4; i++) a[i] = ldA(cur, 1, 4 + i);
        asm volatile("s_waitcnt lgkmcnt(0)" ::: "memory");
        SCHED0();
        MFMA_GRP(4);
    }
#undef MFMA_GRP

    // epilogue
    const int crow = (lane >> 4) * 4;
    const int ccol = lane & 15;
    float inv_[8][4];
#pragma unroll
    for (int i = 0; i < 8; i++)
#pragma unroll
        for (int r2 = 0; r2 < 4; r2++) {
            if constexpr (RS)
                inv_[i][r2] = 1.0f / rsc[(long)b * M + bm + wm2 + i * 16 + crow + r2];
            else
                inv_[i][r2] = 1.0f;
        }
#pragma unroll
    for (int i = 0; i < 8; i++) {
#pragma unroll
        for (int j = 0; j < 4; j++) {
#pragma unroll
            for (int r2 = 0; r2 < 4; r2++) {
                long rr = bm + wm2 + i * 16 + crow + r2;
                long cc = bn + wn2 + j * 16 + ccol;
                float v = acc[i][j][r2] * scale * inv_[i][r2];
                if constexpr (__is_same(OutT, float))
                    C[rr * (long)N + cc] = v;
                else
                    C[rr * (long)N + cc] = __float2bfloat16(v);
            }
        }
    }
}

// ---------------------------------------------------------------------------
// 256x128-tile 8-phase GEMM (Round-5; same template family as gemm256, for
// N=512 outputs where a 256-wide tile would underfill the chip).
// 512 threads = 8 waves as 4(M) x 2(N); per-wave output 64x64 = acc[4][4].
// K in BK=64 tiles as two k-32 halves. LDS: A[2][2][256][32] 64 KB +
// B[2][2][128][32] 32 KB = 96 KB -> 1 block/CU.
// Split-K supported: z = s*nbat + b; partial slot s at C + z*strideC.
//
// Per-thread vmcnt ledger (stageA = 2 ops, stageB = 1 op, in-order retire):
//  prologue stages 6 ops (A-klo2, B-klo1, A-khi2, B-khi1), vmcnt(3) ->
//    klo landed; khi(3) in flight.
//  P0 +2 (A-klo t+1) =5; P1 +1 (B-klo t+1) =6, vmcnt(3) retires t's khi.
//  P2 +2 (A-khi t+1) =5; P3 +1 (B-khi t+1) =6, vmcnt(3) retires t+1's klo.
// vmcnt never 0 in the main loop (T4). Last tile peeled: vmcnt(0) at P1.
// Per phase: 8 MFMA (2 m-frags x 4 n-frags), bb[] reused across P0/P1 pair.
// ---------------------------------------------------------------------------
template <typename OutT, bool RS>
__global__ __launch_bounds__(512) void gemm256n128(
    const bf16* __restrict__ A, const bf16* __restrict__ B, OutT* __restrict__ C,
    int M, int N, int K, long strideA, long strideB, long strideC,
    float scale, int nbat, int splits, const float* __restrict__ rsc)
{
    const int z = blockIdx.z;
    const int b = z % nbat;
    const int s = z / nbat;
    const int klen = K / splits;
    const int k0 = s * klen;

    A += (long)b * strideA;
    B += (long)b * strideB;
    C += (long)z * strideC;

    // XCD-aware bijective swizzle of the (bx,by) plane (m204).
    const int nwg = gridDim.x * gridDim.y;
    const int orig = blockIdx.y * gridDim.x + blockIdx.x;
    const int q = nwg >> 3, r = nwg & 7;
    const int xcd = orig & 7, pos = orig >> 3;
    const int nid = (xcd < r ? xcd * (q + 1) : r * (q + 1) + (xcd - r) * q) + pos;
    const int bm = (nid / gridDim.x) * 256;
    const int bn = (nid % gridDim.x) * 128;

    const int tid = threadIdx.x;
    const int lane = tid & 63;
    const int wave = tid >> 6;                 // 0..7
    const int wm2 = (wave >> 1) * 64;          // wave's M offset (0/64/128/192)
    const int wn2 = (wave & 1) * 64;           // wave's N offset (0/64)
    const int mrow = lane & 15;
    const int g = lane >> 4;                   // k-chunk group 0..3

    __shared__ bf16 Asl[2][2][256][32];        // 64 KB
    __shared__ bf16 Bsl[2][2][128][32];        // 32 KB

    floatx4 acc[4][4];
#pragma unroll
    for (int i = 0; i < 4; i++)
#pragma unroll
        for (int j = 0; j < 4; j++) acc[i][j] = (floatx4)(0.0f);

    const int s0 = wave * 64 + lane;           // 0..511
    const int sr = s0 >> 2, sc = s0 & 3;       // row 0..127, chunk 0..3
    auto stageA = [&](int kb, int ks, int buf) {
        const int cg = (sc ^ (sr & 3)) * 8;    // (sr+128)&3 == sr&3
        const bf16* src0 = A + (long)(bm + sr) * K + kb + ks * 32 + cg;
        const bf16* src1 = A + (long)(bm + sr + 128) * K + kb + ks * 32 + cg;
        bf16* base = &Asl[buf][ks][0][0];
        async_copy16(src0, base + wave * 512);
        async_copy16(src1, base + 4096 + wave * 512);
    };
    auto stageB = [&](int kb, int ks, int buf) {
        const int cg = (sc ^ (sr & 3)) * 8;
        const bf16* src0 = B + (long)(bn + sr) * K + kb + ks * 32 + cg;
        bf16* base = &Bsl[buf][ks][0][0];
        async_copy16(src0, base + wave * 512);
    };
    auto ldA = [&](int buf, int ks, int mi) -> short8 {
        const int row = wm2 + mi * 16 + mrow;
        const int cc = (g ^ (row & 3)) * 8;
        return *(const short8*)(&Asl[buf][ks][row][cc]);
    };
    auto ldB = [&](int buf, int ks, int ni) -> short8 {
        const int row = wn2 + ni * 16 + mrow;
        const int cc = (g ^ (row & 3)) * 8;
        return *(const short8*)(&Bsl[buf][ks][row][cc]);
    };

#define MFMA_GRP2(MH)                                                         \
    do {                                                                      \
        _Pragma("unroll") for (int i = 0; i < 2; i++)                         \
            _Pragma("unroll") for (int j = 0; j < 4; j++)                     \
                acc[(MH)*2 + i][j] = __builtin_amdgcn_mfma_f32_16x16x32_bf16( \
                    a[i], bb[j], acc[(MH)*2 + i][j], 0, 0, 0);                \
    } while (0)

    const int nt = klen / 64;
    stageA(k0, 0, 0); stageB(k0, 0, 0);
    stageA(k0, 1, 0); stageB(k0, 1, 0);
    asm volatile("s_waitcnt vmcnt(3)" ::: "memory");
    SBAR(); SCHED0();

    int cur = 0;
    for (int t = 0; t < nt - 1; ++t) {
        const int nxt = cur ^ 1;
        const int kb1 = k0 + (t + 1) * 64;
        short8 a[2], bb[4];
        // ---- P0 ----
#pragma unroll
        for (int i = 0; i < 2; i++) a[i] = ldA(cur, 0, i);
#pragma unroll
        for (int j = 0; j < 4; j++) bb[j] = ldB(cur, 0, j);
        stageA(kb1, 0, nxt);
        SBAR();
        asm volatile("s_waitcnt lgkmcnt(0)" ::: "memory");
        SCHED0();
        __builtin_amdgcn_s_setprio(1);
        MFMA_GRP2(0);
        __builtin_amdgcn_s_setprio(0);
        SCHED0(); SBAR(); SCHED0();
        // ---- P1 ----
#pragma unroll
        for (int i = 0; i < 2; i++) a[i] = ldA(cur, 0, 2 + i);
        stageB(kb1, 0, nxt);
        asm volatile("s_waitcnt vmcnt(3)" ::: "memory");   // t's khi landed
        SBAR();
        asm volatile("s_waitcnt lgkmcnt(0)" ::: "memory");
        SCHED0();
        __builtin_amdgcn_s_setprio(1);
        MFMA_GRP2(1);
        __builtin_amdgcn_s_setprio(0);
        SCHED0(); SBAR(); SCHED0();
        // ---- P2 ----
#pragma unroll
        for (int i = 0; i < 2; i++) a[i] = ldA(cur, 1, i);
#pragma unroll
        for (int j = 0; j < 4; j++) bb[j] = ldB(cur, 1, j);
        stageA(kb1, 1, nxt);
        SBAR();
        asm volatile("s_waitcnt lgkmcnt(0)" ::: "memory");
        SCHED0();
        __builtin_amdgcn_s_setprio(1);
        MFMA_GRP2(0);
        __builtin_amdgcn_s_setprio(0);
        SCHED0(); SBAR(); SCHED0();
        // ---- P3 ----
#pragma unroll
        for (int i = 0; i < 2; i++) a[i] = ldA(cur, 1, 2 + i);
        stageB(kb1, 1, nxt);
        asm volatile("s_waitcnt vmcnt(3)" ::: "memory");   // t+1's klo landed
        SBAR();
        asm volatile("s_waitcnt lgkmcnt(0)" ::: "memory");
        SCHED0();
        __builtin_amdgcn_s_setprio(1);
        MFMA_GRP2(1);
        __builtin_amdgcn_s_setprio(0);
        SCHED0(); SBAR(); SCHED0();
        cur = nxt;
    }
    // ---- last tile (no staging) ----
    {
        short8 a[2], bb[4];
#pragma unroll
        for (int i = 0; i < 2; i++) a[i] = ldA(cur, 0, i);
#pragma unroll
        for (int j = 0; j < 4; j++) bb[j] = ldB(cur, 0, j);
        SBAR();
        asm volatile("s_waitcnt lgkmcnt(0)" ::: "memory");
        SCHED0();
        MFMA_GRP2(0);
        SCHED0(); SBAR(); SCHED0();
#pragma unroll
        for (int i = 0; i < 2; i++) a[i] = ldA(cur, 0, 2 + i);
        asm volatile("s_waitcnt vmcnt(0)" ::: "memory");   // its khi landed
        SBAR();
        asm volatile("s_waitcnt lgkmcnt(0)" ::: "memory");
        SCHED0();
        MFMA_GRP2(1);
        SCHED0(); SBAR(); SCHED0();
#pragma unroll
        for (int i = 0; i < 2; i++) a[i] = ldA(cur, 1, i);
#pragma unroll
        for (int j = 0; j < 4; j++) bb[j] = ldB(cur, 1, j);
        asm volatile("s_waitcnt lgkmcnt(0)" ::: "memory");
        SCHED0();
        MFMA_GRP2(0);
#pragma unroll
        for (int i = 0; i < 2; i++) a[i] = ldA(cur, 1, 2 + i);
        asm volatile("s_waitcnt lgkmcnt(0)" ::: "memory");
        SCHED0();
        MFMA_GRP2(1);
    }
#undef MFMA_GRP2

    // epilogue
    const int crow = (lane >> 4) * 4;
    const int ccol = lane & 15;
    float inv_[4][4];
#pragma unroll
    for (int i = 0; i < 4; i++)
#pragma unroll
        for (int r2 = 0; r2 < 4; r2++) {
            if constexpr (RS)
                inv_[i][r2] = 1.0f / rsc[(long)b * M + bm + wm2 + i * 16 + crow + r2];
            else
                inv_[i][r2] = 1.0f;
        }
#pragma unroll
    for (int i = 0; i < 4; i++) {
#pragma unroll
        for (int j = 0; j < 4; j++) {
#pragma unroll
            for (int r2 = 0; r2 < 4; r2++) {
                long rr = bm + wm2 + i * 16 + crow + r2;
                long cc = bn + wn2 + j * 16 + ccol;
                float v = acc[i][j][r2] * scale * inv_[i][r2];
                if constexpr (__is_same(OutT, float))
                    C[rr * (long)N + cc] = v;
                else
                    C[rr * (long)N + cc] = __float2bfloat16(v);
            }
        }
    }
}

// ---------------------------------------------------------------------------
// One pass over S (bf16) producing BOTH row and col stat partials.
// ---------------------------------------------------------------------------
__global__ __launch_bounds__(256) void stats_both(
    const bf16* __restrict__ S, float4* __restrict__ rp, float4* __restrict__ cp)
{
    const int b = blockIdx.z, c0 = blockIdx.x * 64, p0 = blockIdx.y * 256;
    const int tid = threadIdx.x;
    const int rt = tid >> 3;          // 0..31 rows per pass
    const int ct = (tid & 7) * 8;     // 8 cols per thread

    float cs[8], cq[8], cm[8];
#pragma unroll
    for (int t = 0; t < 8; t++) { cs[t] = 0.f; cq[t] = 0.f; cm[t] = -3.4e38f; }

#pragma unroll
    for (int pass = 0; pass < 8; pass++) {
        const int p = p0 + pass * 32 + rt;
        const long sidx = ((long)(b * NPn + p)) * NCn + c0 + ct;
        short8 sv = *(const short8*)(S + sidx);
        float rs = 0.f, rq = 0.f, rm = -3.4e38f;
#pragma unroll
        for (int t = 0; t < 8; t++) {
            float x = b2f(sv[t]);
            rs += x; rq += x * x; rm = fmaxf(rm, x);
            cs[t] += x; cq[t] += x * x; cm[t] = fmaxf(cm[t], x);
        }
#pragma unroll
        for (int m = 1; m < 8; m <<= 1) {
            rs += __shfl_xor(rs, m);
            rq += __shfl_xor(rq, m);
            rm = fmaxf(rm, __shfl_xor(rm, m));
        }
        if ((tid & 7) == 0)
            rp[((long)(b * 16 + blockIdx.x)) * NPn + p] = make_float4(rs, rq, rm, 0.f);
    }

#pragma unroll
    for (int m = 8; m < 64; m <<= 1)
#pragma unroll
        for (int t = 0; t < 8; t++) {
            cs[t] += __shfl_xor(cs[t], m);
            cq[t] += __shfl_xor(cq[t], m);
            cm[t] = fmaxf(cm[t], __shfl_xor(cm[t], m));
        }
    __shared__ float LS[4][64], LQ[4][64], LM[4][64];
    const int lane = tid & 63, wave = tid >> 6;
    if (lane < 8)
#pragma unroll
        for (int t = 0; t < 8; t++) {
            LS[wave][lane * 8 + t] = cs[t];
            LQ[wave][lane * 8 + t] = cq[t];
            LM[wave][lane * 8 + t] = cm[t];
        }
    __syncthreads();
    if (tid < 64) {
        float s0 = LS[0][tid] + LS[1][tid] + LS[2][tid] + LS[3][tid];
        float q0 = LQ[0][tid] + LQ[1][tid] + LQ[2][tid] + LQ[3][tid];
        float m0 = fmaxf(fmaxf(LM[0][tid], LM[1][tid]), fmaxf(LM[2][tid], LM[3][tid]));
        cp[((long)(b * 16 + blockIdx.y)) * NCn + c0 + tid] = make_float4(s0, q0, m0, 0.f);
    }
}

// ---------------------------------------------------------------------------
// Finalize stats; thr = mean + std(ddof=1)/8. Also zeros d1/d2.
// ---------------------------------------------------------------------------
__global__ __launch_bounds__(256) void stats_final(
    const float4* __restrict__ rp, const float4* __restrict__ cp,
    float2* __restrict__ row_tm, float2* __restrict__ col_tm,
    float* __restrict__ d1, float* __restrict__ d2)
{
    int idx = blockIdx.x * 256 + threadIdx.x;
    if (idx < Bn * NPn) {
        int b = idx >> 12, p = idx & (NPn - 1);
        float s = 0.f, q = 0.f, m = -3.4e38f;
#pragma unroll
        for (int i = 0; i < 16; i++) {
            float4 v = rp[((long)(b * 16 + i)) * NPn + p];
            s += v.x; q += v.y; m = fmaxf(m, v.z);
        }
        float mean = s * (1.0f / NCn);
        float var = fmaxf((q - (float)NCn * mean * mean) * (1.0f / (NCn - 1)), 0.0f);
        row_tm[idx] = make_float2(mean + sqrtf(var) * 0.125f, m);
        d1[idx] = 0.f;
    } else {
        int cidx = idx - Bn * NPn;
        int b = cidx >> 10, c = cidx & (NCn - 1);
        float s = 0.f, q = 0.f, m = -3.4e38f;
#pragma unroll
        for (int i = 0; i < 16; i++) {
            float4 v = cp[((long)(b * 16 + i)) * NCn + c];
            s += v.x; q += v.y; m = fmaxf(m, v.z);
        }
        float mean = s * (1.0f / NPn);
        float var = fmaxf((q - (float)NPn * mean * mean) * (1.0f / (NPn - 1)), 0.0f);
        col_tm[cidx] = make_float2(mean + sqrtf(var) * 0.125f, m);
        d2[cidx] = 0.f;
    }
}

// ---------------------------------------------------------------------------
// Merged masked softmax: one read of S produces A1u (row-major) and A2u
// (transposed); d1/d2 denominators via atomics.
// ---------------------------------------------------------------------------
__global__ __launch_bounds__(256) void softmax_merged(
    const bf16* __restrict__ S, const float2* __restrict__ row_tm,
    const float2* __restrict__ col_tm, float* __restrict__ d1,
    float* __restrict__ d2, bf16* __restrict__ A1u, bf16* __restrict__ A2u)
{
    const int b = blockIdx.z, c0 = blockIdx.x * 64, p0 = blockIdx.y * 256;
    const int tid = threadIdx.x;
    const int rt = tid >> 3;
    const int ct = (tid & 7) * 8;

    __shared__ float T[64][265];
    __shared__ float dw2[4][64];

    float2 ctm[8];
#pragma unroll
    for (int t = 0; t < 8; t++) ctm[t] = col_tm[b * NCn + c0 + ct + t];

    float d2acc[8];
#pragma unroll
    for (int t = 0; t < 8; t++) d2acc[t] = 0.f;

#pragma unroll
    for (int pass = 0; pass < 8; pass++) {
        const int p = p0 + pass * 32 + rt;
        const float2 rtm = row_tm[b * NPn + p];
        const long sidx = ((long)(b * NPn + p)) * NCn + c0 + ct;
        short8 sv = *(const short8*)(S + sidx);
        bf16 o1[8] __attribute__((aligned(16)));
        float e1s = 0.f;
#pragma unroll
        for (int t = 0; t < 8; t++) {
            float x = b2f(sv[t]);
            float e1 = (x >= rtm.x) ? __expf(x - rtm.y) : 0.0f;
            o1[t] = __float2bfloat16(e1);
            e1s += e1;
            float e2 = (x >= ctm[t].x) ? __expf(x - ctm[t].y) : 0.0f;
            d2acc[t] += e2;
            T[ct + t][pass * 32 + rt] = e2;
        }
        *(short8*)(A1u + sidx) = *(const short8*)o1;
        e1s += __shfl_xor(e1s, 1);
        e1s += __shfl_xor(e1s, 2);
        e1s += __shfl_xor(e1s, 4);
        if ((tid & 7) == 0) atomicAdd(&d1[b * NPn + p], e1s);
    }

#pragma unroll
    for (int m = 8; m < 64; m <<= 1)
#pragma unroll
        for (int t = 0; t < 8; t++) d2acc[t] += __shfl_xor(d2acc[t], m);
    const int lane = tid & 63, wave = tid >> 6;
    if (lane < 8)
#pragma unroll
        for (int t = 0; t < 8; t++) dw2[wave][lane * 8 + t] = d2acc[t];
    __syncthreads();
    if (tid < 64)
        atomicAdd(&d2[b * NCn + c0 + tid],
                  dw2[0][tid] + dw2[1][tid] + dw2[2][tid] + dw2[3][tid]);

    const int c = tid >> 2, pb = (tid & 3) * 64;
    bf16* dst = A2u + ((long)(b * NCn + c0 + c)) * NPn + p0 + pb;
#pragma unroll
    for (int u = 0; u < 8; u++) {
        bf16 tmp[8] __attribute__((aligned(16)));
#pragma unroll
        for (int w = 0; w < 8; w++)
            tmp[w] = __float2bfloat16(T[c][pb + u * 8 + w]);
        *(short8*)(dst + u * 8) = *(const short8*)tmp;
    }
}

// ---------------------------------------------------------------------------
// Sum 4 split-K fp32 partials, scale row (b*NC+c) by 1/d2 -> bf16
// ---------------------------------------------------------------------------
__global__ __launch_bounds__(256) void reduce_scale_bf16(
    const float* __restrict__ Pp, const float* __restrict__ d2,
    bf16* __restrict__ out, long n4, long stride)
{
    long i = (long)blockIdx.x * 256 + threadIdx.x;
    if (i < n4) {
        float4 a = ((const float4*)Pp)[i];
#pragma unroll
        for (int s = 1; s < 4; s++) {
            float4 v = ((const float4*)(Pp + (long)s * stride))[i];
            a.x += v.x; a.y += v.y; a.z += v.z; a.w += v.w;
        }
        float inv = 1.0f / d2[i / (Dn / 4)];
        out[i * 4 + 0] = __float2bfloat16(a.x * inv);
        out[i * 4 + 1] = __float2bfloat16(a.y * inv);
        out[i * 4 + 2] = __float2bfloat16(a.z * inv);
        out[i * 4 + 3] = __float2bfloat16(a.w * inv);
    }
}

// ---------------------------------------------------------------------------
// fp32 [R x C] -> bf16 row-major copy AND bf16 [C x R] transpose, batched z.
// ---------------------------------------------------------------------------
__global__ __launch_bounds__(256) void cvt_both(
    const float* __restrict__ in, bf16* __restrict__ out_rm,
    bf16* __restrict__ out_t, int R, int C)
{
    __shared__ float tile[32][33];
    const long boff = (long)blockIdx.z * (long)R * C;
    in += boff; out_rm += boff; out_t += boff;
    const int c0 = blockIdx.x * 32, r0 = blockIdx.y * 32;
    const int tx = threadIdx.x, ty = threadIdx.y;
#pragma unroll
    for (int i = ty; i < 32; i += 8) {
        float x = in[(long)(r0 + i) * C + c0 + tx];
        tile[i][tx] = x;
        out_rm[(long)(r0 + i) * C + c0 + tx] = __float2bfloat16(x);
    }
    __syncthreads();
#pragma unroll
    for (int i = ty; i < 32; i += 8)
        out_t[(long)(c0 + i) * R + r0 + tx] = __float2bfloat16(tile[tx][i]);
}

// ---------------------------------------------------------------------------
extern "C" void kernel_launch(void* const* d_in, const int* in_sizes, int n_in,
                              void* d_out, int out_size, void* d_ws, size_t ws_size,
                              hipStream_t stream)
{
    const float* Xp = (const float*)d_in[0];  // [4,4096,512]
    const float* Xc = (const float*)d_in[1];  // [4,1024,512]
    float* out = (float*)d_out;               // [4,4096,1024]

    constexpr int B = Bn, NP = NPn, NC = NCn, D = Dn;
    constexpr float SCALE = 0.044194173824159216f;  // 1/sqrt(512)

    // workspace layout (bytes), ~164 MB
    char* ws = (char*)d_ws;
    bf16*   Qp     = (bf16*)(ws);                   // 16.78 MB [B,NP,D]
    bf16*   Kc     = (bf16*)(ws + 16777216);        //  4.19 MB [B,NC,D]
    bf16*   KcT    = (bf16*)(ws + 20971520);        //  4.19 MB [B,D,NC]
    bf16*   XpT    = (bf16*)(ws + 25165824);        // 16.78 MB [B,D,NP]
    bf16*   S      = (bf16*)(ws + 41943040);        // 33.55 MB [B,NP,NC]; later Hp overlays
    bf16*   A1u    = (bf16*)(ws + 75497472);        // 33.55 MB [B,NP,NC]
    bf16*   A2u    = (bf16*)(ws + 109051904);       // 33.55 MB [B,NC,NP]; rp/cp overlay pre-softmax
    bf16*   H1u    = (bf16*)(ws + 142606336);       // 16.78 MB [B,NP,D]
    bf16*   H2     = (bf16*)(ws + 159383552);       //  4.19 MB [B,NC,D]
    float2* row_tm = (float2*)(ws + 163577856);     // 128 KB  [B*NP]
    float2* col_tm = (float2*)(ws + 163708928);     //  32 KB  [B*NC]
    float*  d1     = (float*)(ws + 163741696);      //  64 KB  [B*NP]
    float*  d2     = (float*)(ws + 163807232);      //  16 KB  [B*NC]
    float4* rp     = (float4*)A2u;                  //  4.19 MB [B*16,NP]
    float4* cp     = (float4*)(ws + 109051904 + 4194304);  // 1.05 MB [B*16,NC]
    float*  Hp     = (float*)S;                     // split-K partials [4][B,NC,D] fp32 (S dead)

    // 1-2: convert + transpose inputs (one read of fp32 each)
    cvt_both<<<dim3(D / 32, NP / 32, B), dim3(32, 8), 0, stream>>>(Xp, Qp, XpT, NP, D);
    cvt_both<<<dim3(D / 32, NC / 32, B), dim3(32, 8), 0, stream>>>(Xc, Kc, KcT, NC, D);

    // 3: S = Qp*Kc^T*scale (bf16) -- 256x256 8-phase
    gemm256<bf16, false><<<dim3(NC / 256, NP / 256, B), dim3(512), 0, stream>>>(
        Qp, Kc, S, NP, NC, D, (long)NP * D, (long)NC * D, (long)NP * NC,
        SCALE, B, nullptr);
    // 4: one-pass row+col stat partials from S
    stats_both<<<dim3(NC / 64, NP / 256, B), dim3(256), 0, stream>>>(S, rp, cp);
    // 5: finalize thr/max; zero denoms
    stats_final<<<dim3((B * NP + B * NC) / 256), dim3(256), 0, stream>>>(
        rp, cp, row_tm, col_tm, d1, d2);
    // 6: merged softmax -> A1u + A2u (transposed), denoms via atomics
    softmax_merged<<<dim3(NC / 64, NP / 256, B), dim3(256), 0, stream>>>(
        S, row_tm, col_tm, d1, d2, A1u, A2u);
    // 7: H1u = A1u * Kc  [B,NP,D] bf16 -- 256x128 8-phase (grid 4x16x4 = 256)
    gemm256n128<bf16, false><<<dim3(D / 128, NP / 256, B), dim3(512), 0, stream>>>(
        A1u, KcT, H1u, NP, D, NC, (long)NP * NC, (long)D * NC, (long)NP * D,
        1.0f, B, 1, nullptr);
    // 8: Hp = A2u * Xp partials [4][B,NC,D] fp32, 4-way split-K
    //    -- 256x128 8-phase (grid 4x4x16 = 256)
    gemm256n128<float, false><<<dim3(D / 128, NC / 256, 4 * B), dim3(512), 0, stream>>>(
        A2u, XpT, Hp, NC, D, NP, (long)NC * NP, (long)D * NP, (long)NC * D,
        1.0f, B, 4, nullptr);
    // 9: H2 = sum(Hp) / d2 -> bf16
    {
        long n = (long)B * NC * D;
        reduce_scale_bf16<<<dim3((n / 4 + 255) / 256), dim3(256), 0, stream>>>(
            Hp, d2, H2, n / 4, n);
    }
    // 10: out = diag(1/d1) * H1u * H2^T   [B,NP,NC] fp32 -- 256x256 8-phase
    gemm256<float, true><<<dim3(NC / 256, NP / 256, B), dim3(512), 0, stream>>>(
        H1u, H2, out, NP, NC, D, (long)NP * D, (long)NC * D, (long)NP * NC,
        1.0f, B, d1);
}

// Round 6
// 263.827 us; speedup vs baseline: 1.1300x; 1.0047x over previous
//
#include <hip/hip_runtime.h>
#include <hip/hip_bf16.h>

using bf16 = __hip_bfloat16;
typedef __attribute__((ext_vector_type(8))) short short8;   // 8 bf16 (4 VGPRs)
typedef __attribute__((ext_vector_type(4))) float floatx4;  // MFMA C/D frag

#define NPn 4096
#define NCn 1024
#define Dn  512
#define Bn  4

__device__ __forceinline__ float b2f(short s) {
    union { unsigned u; float f; } cv;
    cv.u = ((unsigned)(unsigned short)s) << 16;
    return cv.f;
}

// ---------------------------------------------------------------------------
// async global->LDS, 16B per lane. LDS dest = (wave-uniform base) + lane*16B.
// ---------------------------------------------------------------------------
__device__ __forceinline__ void async_copy16(const bf16* g, bf16* l) {
    __builtin_amdgcn_global_load_lds(
        (const __attribute__((address_space(1))) unsigned int*)g,
        (__attribute__((address_space(3))) unsigned int*)l,
        16, 0, 0);
}

#define SBAR()  __builtin_amdgcn_s_barrier()
#define SCHED0() __builtin_amdgcn_sched_barrier(0)

// ---------------------------------------------------------------------------
// 256x256-tile 8-phase GEMM (T2+T3+T4+T5 port of the m201 template).
// C[M x N] = scale * A[M x K] * Bt[N x K]^T, row-major bf16 in, OutT out.
// 512 threads = 8 waves as 2(M) x 4(N); per-wave output 128x64 = acc[8][4].
// K consumed in BK=64 tiles, each as two k-32 halves (ks=0,1).
// LDS [buf][ks][256][32] bf16, 128 KB total, double buffered.
// Verified in Round 4 (passed, absmax unchanged).
//
// Swizzle (T2, both-sides): within each 64B half-row, 16B-chunk index is
// XORed with (row&3). Staging pre-swizzles the GLOBAL source chunk
// (global_load_lds dest stays linear); ds_read applies the same XOR.
//
// Per-thread vmcnt ledger (stageA/stageB = 2 ops each, retire in order):
//  prologue stages 8 ops, vmcnt(4) -> klo landed, khi(4) in flight.
//  P0 +2 (A-klo t+1) =6; P1 +2 (B-klo t+1) =8, vmcnt(4) retires t's khi.
//  P2 +2 (A-khi t+1) =6; P3 +2 (B-khi t+1) =8, vmcnt(4) retires t+1's klo.
// vmcnt never 0 in the main loop (T4). Last tile peeled: vmcnt(0) at P1.
// ---------------------------------------------------------------------------
template <typename OutT, bool RS>
__global__ __launch_bounds__(512) void gemm256(
    const bf16* __restrict__ A, const bf16* __restrict__ B, OutT* __restrict__ C,
    int M, int N, int K, long strideA, long strideB, long strideC,
    float scale, int nbat, const float* __restrict__ rsc)
{
    const int z = blockIdx.z;
    const int b = z % nbat;
    A += (long)b * strideA;
    B += (long)b * strideB;
    C += (long)z * strideC;

    // XCD-aware bijective swizzle of the (bx,by) plane (m204).
    const int nwg = gridDim.x * gridDim.y;
    const int orig = blockIdx.y * gridDim.x + blockIdx.x;
    const int q = nwg >> 3, r = nwg & 7;
    const int xcd = orig & 7, pos = orig >> 3;
    const int nid = (xcd < r ? xcd * (q + 1) : r * (q + 1) + (xcd - r) * q) + pos;
    const int bm = (nid / gridDim.x) * 256;
    const int bn = (nid % gridDim.x) * 256;

    const int tid = threadIdx.x;
    const int lane = tid & 63;
    const int wave = tid >> 6;                 // 0..7
    const int wm2 = (wave >> 2) * 128;         // wave's M offset (0/128)
    const int wn2 = (wave & 3) * 64;           // wave's N offset (0/64/128/192)
    const int mrow = lane & 15;
    const int g = lane >> 4;                   // k-chunk group 0..3

    __shared__ bf16 Asl[2][2][256][32];        // [buf][ks][row][col] 64 KB
    __shared__ bf16 Bsl[2][2][256][32];        // 64 KB

    floatx4 acc[8][4];
#pragma unroll
    for (int i = 0; i < 8; i++)
#pragma unroll
        for (int j = 0; j < 4; j++) acc[i][j] = (floatx4)(0.0f);

    const int s0 = wave * 64 + lane;
    const int sr = s0 >> 2, sc = s0 & 3;
    auto stageA = [&](int kb, int ks, int buf) {
        const int cg = (sc ^ (sr & 3)) * 8;
        const bf16* src0 = A + (long)(bm + sr) * K + kb + ks * 32 + cg;
        const bf16* src1 = A + (long)(bm + sr + 128) * K + kb + ks * 32 + cg;
        bf16* base = &Asl[buf][ks][0][0];
        async_copy16(src0, base + wave * 512);
        async_copy16(src1, base + 4096 + wave * 512);
    };
    auto stageB = [&](int kb, int ks, int buf) {
        const int cg = (sc ^ (sr & 3)) * 8;
        const bf16* src0 = B + (long)(bn + sr) * K + kb + ks * 32 + cg;
        const bf16* src1 = B + (long)(bn + sr + 128) * K + kb + ks * 32 + cg;
        bf16* base = &Bsl[buf][ks][0][0];
        async_copy16(src0, base + wave * 512);
        async_copy16(src1, base + 4096 + wave * 512);
    };
    auto ldA = [&](int buf, int ks, int mi) -> short8 {
        const int row = wm2 + mi * 16 + mrow;
        const int cc = (g ^ (row & 3)) * 8;
        return *(const short8*)(&Asl[buf][ks][row][cc]);
    };
    auto ldB = [&](int buf, int ks, int ni) -> short8 {
        const int row = wn2 + ni * 16 + mrow;
        const int cc = (g ^ (row & 3)) * 8;
        return *(const short8*)(&Bsl[buf][ks][row][cc]);
    };

#define MFMA_GRP(MS)                                                          \
    do {                                                                      \
        _Pragma("unroll") for (int i = 0; i < 4; i++)                         \
            _Pragma("unroll") for (int j = 0; j < 4; j++)                     \
                acc[(MS) + i][j] = __builtin_amdgcn_mfma_f32_16x16x32_bf16(   \
                    a[i], bb[j], acc[(MS) + i][j], 0, 0, 0);                  \
    } while (0)

    const int nt = K / 64;
    stageA(0, 0, 0); stageB(0, 0, 0);
    stageA(0, 1, 0); stageB(0, 1, 0);
    asm volatile("s_waitcnt vmcnt(4)" ::: "memory");
    SBAR(); SCHED0();

    int cur = 0;
    for (int t = 0; t < nt - 1; ++t) {
        const int nxt = cur ^ 1;
        const int kb1 = (t + 1) * 64;
        short8 a[4], bb[4];
        // ---- P0 ----
#pragma unroll
        for (int i = 0; i < 4; i++) a[i] = ldA(cur, 0, i);
#pragma unroll
        for (int j = 0; j < 4; j++) bb[j] = ldB(cur, 0, j);
        stageA(kb1, 0, nxt);
        SBAR();
        asm volatile("s_waitcnt lgkmcnt(0)" ::: "memory");
        SCHED0();
        __builtin_amdgcn_s_setprio(1);
        MFMA_GRP(0);
        __builtin_amdgcn_s_setprio(0);
        SCHED0(); SBAR(); SCHED0();
        // ---- P1 ----
#pragma unroll
        for (int i = 0; i < 4; i++) a[i] = ldA(cur, 0, 4 + i);
        stageB(kb1, 0, nxt);
        asm volatile("s_waitcnt vmcnt(4)" ::: "memory");   // t's khi landed
        SBAR();
        asm volatile("s_waitcnt lgkmcnt(0)" ::: "memory");
        SCHED0();
        __builtin_amdgcn_s_setprio(1);
        MFMA_GRP(4);
        __builtin_amdgcn_s_setprio(0);
        SCHED0(); SBAR(); SCHED0();
        // ---- P2 ----
#pragma unroll
        for (int i = 0; i < 4; i++) a[i] = ldA(cur, 1, i);
#pragma unroll
        for (int j = 0; j < 4; j++) bb[j] = ldB(cur, 1, j);
        stageA(kb1, 1, nxt);
        SBAR();
        asm volatile("s_waitcnt lgkmcnt(0)" ::: "memory");
        SCHED0();
        __builtin_amdgcn_s_setprio(1);
        MFMA_GRP(0);
        __builtin_amdgcn_s_setprio(0);
        SCHED0(); SBAR(); SCHED0();
        // ---- P3 ----
#pragma unroll
        for (int i = 0; i < 4; i++) a[i] = ldA(cur, 1, 4 + i);
        stageB(kb1, 1, nxt);
        asm volatile("s_waitcnt vmcnt(4)" ::: "memory");   // t+1's klo landed
        SBAR();
        asm volatile("s_waitcnt lgkmcnt(0)" ::: "memory");
        SCHED0();
        __builtin_amdgcn_s_setprio(1);
        MFMA_GRP(4);
        __builtin_amdgcn_s_setprio(0);
        SCHED0(); SBAR(); SCHED0();
        cur = nxt;
    }
    // ---- last tile (no staging) ----
    {
        short8 a[4], bb[4];
#pragma unroll
        for (int i = 0; i < 4; i++) a[i] = ldA(cur, 0, i);
#pragma unroll
        for (int j = 0; j < 4; j++) bb[j] = ldB(cur, 0, j);
        SBAR();
        asm volatile("s_waitcnt lgkmcnt(0)" ::: "memory");
        SCHED0();
        MFMA_GRP(0);
        SCHED0(); SBAR(); SCHED0();
#pragma unroll
        for (int i = 0; i < 4; i++) a[i] = ldA(cur, 0, 4 + i);
        asm volatile("s_waitcnt vmcnt(0)" ::: "memory");   // its khi landed
        SBAR();
        asm volatile("s_waitcnt lgkmcnt(0)" ::: "memory");
        SCHED0();
        MFMA_GRP(4);
        SCHED0(); SBAR(); SCHED0();
#pragma unroll
        for (int i = 0; i < 4; i++) a[i] = ldA(cur, 1, i);
#pragma unroll
        for (int j = 0; j < 4; j++) bb[j] = ldB(cur, 1, j);
        asm volatile("s_waitcnt lgkmcnt(0)" ::: "memory");
        SCHED0();
        MFMA_GRP(0);
#pragma unroll
        for (int i = 0; i < 4; i++) a[i] = ldA(cur, 1, 4 + i);
        asm volatile("s_waitcnt lgkmcnt(0)" ::: "memory");
        SCHED0();
        MFMA_GRP(4);
    }
#undef MFMA_GRP

    // epilogue
    const int crow = (lane >> 4) * 4;
    const int ccol = lane & 15;
    float inv_[8][4];
#pragma unroll
    for (int i = 0; i < 8; i++)
#pragma unroll
        for (int r2 = 0; r2 < 4; r2++) {
            if constexpr (RS)
                inv_[i][r2] = 1.0f / rsc[(long)b * M + bm + wm2 + i * 16 + crow + r2];
            else
                inv_[i][r2] = 1.0f;
        }
#pragma unroll
    for (int i = 0; i < 8; i++) {
#pragma unroll
        for (int j = 0; j < 4; j++) {
#pragma unroll
            for (int r2 = 0; r2 < 4; r2++) {
                long rr = bm + wm2 + i * 16 + crow + r2;
                long cc = bn + wn2 + j * 16 + ccol;
                float v = acc[i][j][r2] * scale * inv_[i][r2];
                if constexpr (__is_same(OutT, float))
                    C[rr * (long)N + cc] = v;
                else
                    C[rr * (long)N + cc] = __float2bfloat16(v);
            }
        }
    }
}

// ---------------------------------------------------------------------------
// 256x128-tile GEMM, Round-6 rework: 2 DENSE phases per BK=64 K-tile.
// Round-5's 4-thin-phase version (8 MFMA/phase) was neutral vs 2-phase:
// phase overhead (2 barriers + waits + stage issue) was not amortized.
// v2 matches gemm256's per-phase density: 16 MFMA + 8 ds_read_b128/phase.
//
// 512 threads = 8 waves as 4(M) x 2(N); per-wave output 64x64 = acc[4][4].
// LDS: A[2][2][256][32] 64 KB + B[2][2][128][32] 32 KB = 96 KB, dbuf.
// Split-K: z = s*nbat + b; partial slot s at C + z*strideC.
// Same T2 chunk-XOR swizzle as gemm256 (both-sides).
//
// Per-thread vmcnt ledger (stage ops per k-half = 3: A=2, B=1, in-order):
//  prologue: stage klo(0)+khi(0) = 6 in flight; vmcnt(3) -> klo landed.
//  P0(t): ds_read klo(t); stage klo(t+1) [in flight khi(t)3+klo(t+1)3=6];
//         vmcnt(3) retires khi(t)  -> P1's reads safe;
//         SBAR; lgkm0; 16 MFMA (k0); SBAR.
//  P1(t): ds_read khi(t); stage khi(t+1) [in flight klo(t+1)3+khi(t+1)3=6];
//         vmcnt(3) retires klo(t+1) -> next P0's reads safe;
//         SBAR; lgkm0; 16 MFMA (k1); SBAR.
//  vmcnt never 0 in the main loop (T4). Buffer overwrite safe: stage(t+1)
//  issues after tile t-1's final lgkm0+SBAR (all reads of buf nxt done).
//  Last tile peeled: vmcnt(0) before its khi reads.
// ---------------------------------------------------------------------------
template <typename OutT, bool RS>
__global__ __launch_bounds__(512) void gemm256n128(
    const bf16* __restrict__ A, const bf16* __restrict__ B, OutT* __restrict__ C,
    int M, int N, int K, long strideA, long strideB, long strideC,
    float scale, int nbat, int splits, const float* __restrict__ rsc)
{
    const int z = blockIdx.z;
    const int b = z % nbat;
    const int s = z / nbat;
    const int klen = K / splits;
    const int k0 = s * klen;

    A += (long)b * strideA;
    B += (long)b * strideB;
    C += (long)z * strideC;

    // XCD-aware bijective swizzle of the (bx,by) plane (m204).
    const int nwg = gridDim.x * gridDim.y;
    const int orig = blockIdx.y * gridDim.x + blockIdx.x;
    const int q = nwg >> 3, r = nwg & 7;
    const int xcd = orig & 7, pos = orig >> 3;
    const int nid = (xcd < r ? xcd * (q + 1) : r * (q + 1) + (xcd - r) * q) + pos;
    const int bm = (nid / gridDim.x) * 256;
    const int bn = (nid % gridDim.x) * 128;

    const int tid = threadIdx.x;
    const int lane = tid & 63;
    const int wave = tid >> 6;                 // 0..7
    const int wm2 = (wave >> 1) * 64;          // wave's M offset (0/64/128/192)
    const int wn2 = (wave & 1) * 64;           // wave's N offset (0/64)
    const int mrow = lane & 15;
    const int g = lane >> 4;                   // k-chunk group 0..3

    __shared__ bf16 Asl[2][2][256][32];        // 64 KB
    __shared__ bf16 Bsl[2][2][128][32];        // 32 KB

    floatx4 acc[4][4];
#pragma unroll
    for (int i = 0; i < 4; i++)
#pragma unroll
        for (int j = 0; j < 4; j++) acc[i][j] = (floatx4)(0.0f);

    const int s0 = wave * 64 + lane;           // 0..511
    const int sr = s0 >> 2, sc = s0 & 3;       // row 0..127, chunk 0..3
    auto stageA = [&](int kb, int ks, int buf) {
        const int cg = (sc ^ (sr & 3)) * 8;    // (sr+128)&3 == sr&3
        const bf16* src0 = A + (long)(bm + sr) * K + kb + ks * 32 + cg;
        const bf16* src1 = A + (long)(bm + sr + 128) * K + kb + ks * 32 + cg;
        bf16* base = &Asl[buf][ks][0][0];
        async_copy16(src0, base + wave * 512);
        async_copy16(src1, base + 4096 + wave * 512);
    };
    auto stageB = [&](int kb, int ks, int buf) {
        const int cg = (sc ^ (sr & 3)) * 8;
        const bf16* src0 = B + (long)(bn + sr) * K + kb + ks * 32 + cg;
        bf16* base = &Bsl[buf][ks][0][0];
        async_copy16(src0, base + wave * 512);
    };
    auto ldA = [&](int buf, int ks, int mi) -> short8 {
        const int row = wm2 + mi * 16 + mrow;
        const int cc = (g ^ (row & 3)) * 8;
        return *(const short8*)(&Asl[buf][ks][row][cc]);
    };
    auto ldB = [&](int buf, int ks, int ni) -> short8 {
        const int row = wn2 + ni * 16 + mrow;
        const int cc = (g ^ (row & 3)) * 8;
        return *(const short8*)(&Bsl[buf][ks][row][cc]);
    };

#define MFMA_GRP16()                                                          \
    do {                                                                      \
        _Pragma("unroll") for (int i = 0; i < 4; i++)                         \
            _Pragma("unroll") for (int j = 0; j < 4; j++)                     \
                acc[i][j] = __builtin_amdgcn_mfma_f32_16x16x32_bf16(          \
                    a[i], bb[j], acc[i][j], 0, 0, 0);                         \
    } while (0)

    const int nt = klen / 64;
    stageA(k0, 0, 0); stageB(k0, 0, 0);
    stageA(k0, 1, 0); stageB(k0, 1, 0);
    asm volatile("s_waitcnt vmcnt(3)" ::: "memory");
    SBAR(); SCHED0();

    int cur = 0;
    for (int t = 0; t < nt - 1; ++t) {
        const int nxt = cur ^ 1;
        const int kb1 = k0 + (t + 1) * 64;
        short8 a[4], bb[4];
        // ---- P0: k-half 0, all 16 MFMA ----
#pragma unroll
        for (int i = 0; i < 4; i++) a[i] = ldA(cur, 0, i);
#pragma unroll
        for (int j = 0; j < 4; j++) bb[j] = ldB(cur, 0, j);
        stageA(kb1, 0, nxt);
        stageB(kb1, 0, nxt);
        asm volatile("s_waitcnt vmcnt(3)" ::: "memory");   // t's khi landed
        SBAR();
        asm volatile("s_waitcnt lgkmcnt(0)" ::: "memory");
        SCHED0();
        __builtin_amdgcn_s_setprio(1);
        MFMA_GRP16();
        __builtin_amdgcn_s_setprio(0);
        SCHED0(); SBAR(); SCHED0();
        // ---- P1: k-half 1, all 16 MFMA ----
#pragma unroll
        for (int i = 0; i < 4; i++) a[i] = ldA(cur, 1, i);
#pragma unroll
        for (int j = 0; j < 4; j++) bb[j] = ldB(cur, 1, j);
        stageA(kb1, 1, nxt);
        stageB(kb1, 1, nxt);
        asm volatile("s_waitcnt vmcnt(3)" ::: "memory");   // t+1's klo landed
        SBAR();
        asm volatile("s_waitcnt lgkmcnt(0)" ::: "memory");
        SCHED0();
        __builtin_amdgcn_s_setprio(1);
        MFMA_GRP16();
        __builtin_amdgcn_s_setprio(0);
        SCHED0(); SBAR(); SCHED0();
        cur = nxt;
    }
    // ---- last tile (no staging) ----
    {
        short8 a[4], bb[4];
        // P0
#pragma unroll
        for (int i = 0; i < 4; i++) a[i] = ldA(cur, 0, i);
#pragma unroll
        for (int j = 0; j < 4; j++) bb[j] = ldB(cur, 0, j);
        asm volatile("s_waitcnt vmcnt(0)" ::: "memory");   // its khi landed
        SBAR();
        asm volatile("s_waitcnt lgkmcnt(0)" ::: "memory");
        SCHED0();
        __builtin_amdgcn_s_setprio(1);
        MFMA_GRP16();
        __builtin_amdgcn_s_setprio(0);
        SCHED0(); SBAR(); SCHED0();
        // P1
#pragma unroll
        for (int i = 0; i < 4; i++) a[i] = ldA(cur, 1, i);
#pragma unroll
        for (int j = 0; j < 4; j++) bb[j] = ldB(cur, 1, j);
        asm volatile("s_waitcnt lgkmcnt(0)" ::: "memory");
        SCHED0();
        MFMA_GRP16();
    }
#undef MFMA_GRP16

    // epilogue
    const int crow = (lane >> 4) * 4;
    const int ccol = lane & 15;
    float inv_[4][4];
#pragma unroll
    for (int i = 0; i < 4; i++)
#pragma unroll
        for (int r2 = 0; r2 < 4; r2++) {
            if constexpr (RS)
                inv_[i][r2] = 1.0f / rsc[(long)b * M + bm + wm2 + i * 16 + crow + r2];
            else
                inv_[i][r2] = 1.0f;
        }
#pragma unroll
    for (int i = 0; i < 4; i++) {
#pragma unroll
        for (int j = 0; j < 4; j++) {
#pragma unroll
            for (int r2 = 0; r2 < 4; r2++) {
                long rr = bm + wm2 + i * 16 + crow + r2;
                long cc = bn + wn2 + j * 16 + ccol;
                float v = acc[i][j][r2] * scale * inv_[i][r2];
                if constexpr (__is_same(OutT, float))
                    C[rr * (long)N + cc] = v;
                else
                    C[rr * (long)N + cc] = __float2bfloat16(v);
            }
        }
    }
}

// ---------------------------------------------------------------------------
// One pass over S (bf16) producing BOTH row and col stat partials.
// ---------------------------------------------------------------------------
__global__ __launch_bounds__(256) void stats_both(
    const bf16* __restrict__ S, float4* __restrict__ rp, float4* __restrict__ cp)
{
    const int b = blockIdx.z, c0 = blockIdx.x * 64, p0 = blockIdx.y * 256;
    const int tid = threadIdx.x;
    const int rt = tid >> 3;          // 0..31 rows per pass
    const int ct = (tid & 7) * 8;     // 8 cols per thread

    float cs[8], cq[8], cm[8];
#pragma unroll
    for (int t = 0; t < 8; t++) { cs[t] = 0.f; cq[t] = 0.f; cm[t] = -3.4e38f; }

#pragma unroll
    for (int pass = 0; pass < 8; pass++) {
        const int p = p0 + pass * 32 + rt;
        const long sidx = ((long)(b * NPn + p)) * NCn + c0 + ct;
        short8 sv = *(const short8*)(S + sidx);
        float rs = 0.f, rq = 0.f, rm = -3.4e38f;
#pragma unroll
        for (int t = 0; t < 8; t++) {
            float x = b2f(sv[t]);
            rs += x; rq += x * x; rm = fmaxf(rm, x);
            cs[t] += x; cq[t] += x * x; cm[t] = fmaxf(cm[t], x);
        }
#pragma unroll
        for (int m = 1; m < 8; m <<= 1) {
            rs += __shfl_xor(rs, m);
            rq += __shfl_xor(rq, m);
            rm = fmaxf(rm, __shfl_xor(rm, m));
        }
        if ((tid & 7) == 0)
            rp[((long)(b * 16 + blockIdx.x)) * NPn + p] = make_float4(rs, rq, rm, 0.f);
    }

#pragma unroll
    for (int m = 8; m < 64; m <<= 1)
#pragma unroll
        for (int t = 0; t < 8; t++) {
            cs[t] += __shfl_xor(cs[t], m);
            cq[t] += __shfl_xor(cq[t], m);
            cm[t] = fmaxf(cm[t], __shfl_xor(cm[t], m));
        }
    __shared__ float LS[4][64], LQ[4][64], LM[4][64];
    const int lane = tid & 63, wave = tid >> 6;
    if (lane < 8)
#pragma unroll
        for (int t = 0; t < 8; t++) {
            LS[wave][lane * 8 + t] = cs[t];
            LQ[wave][lane * 8 + t] = cq[t];
            LM[wave][lane * 8 + t] = cm[t];
        }
    __syncthreads();
    if (tid < 64) {
        float s0 = LS[0][tid] + LS[1][tid] + LS[2][tid] + LS[3][tid];
        float q0 = LQ[0][tid] + LQ[1][tid] + LQ[2][tid] + LQ[3][tid];
        float m0 = fmaxf(fmaxf(LM[0][tid], LM[1][tid]), fmaxf(LM[2][tid], LM[3][tid]));
        cp[((long)(b * 16 + blockIdx.y)) * NCn + c0 + tid] = make_float4(s0, q0, m0, 0.f);
    }
}

// ---------------------------------------------------------------------------
// Finalize stats; thr = mean + std(ddof=1)/8. Also zeros d1/d2.
// ---------------------------------------------------------------------------
__global__ __launch_bounds__(256) void stats_final(
    const float4* __restrict__ rp, const float4* __restrict__ cp,
    float2* __restrict__ row_tm, float2* __restrict__ col_tm,
    float* __restrict__ d1, float* __restrict__ d2)
{
    int idx = blockIdx.x * 256 + threadIdx.x;
    if (idx < Bn * NPn) {
        int b = idx >> 12, p = idx & (NPn - 1);
        float s = 0.f, q = 0.f, m = -3.4e38f;
#pragma unroll
        for (int i = 0; i < 16; i++) {
            float4 v = rp[((long)(b * 16 + i)) * NPn + p];
            s += v.x; q += v.y; m = fmaxf(m, v.z);
        }
        float mean = s * (1.0f / NCn);
        float var = fmaxf((q - (float)NCn * mean * mean) * (1.0f / (NCn - 1)), 0.0f);
        row_tm[idx] = make_float2(mean + sqrtf(var) * 0.125f, m);
        d1[idx] = 0.f;
    } else {
        int cidx = idx - Bn * NPn;
        int b = cidx >> 10, c = cidx & (NCn - 1);
        float s = 0.f, q = 0.f, m = -3.4e38f;
#pragma unroll
        for (int i = 0; i < 16; i++) {
            float4 v = cp[((long)(b * 16 + i)) * NCn + c];
            s += v.x; q += v.y; m = fmaxf(m, v.z);
        }
        float mean = s * (1.0f / NPn);
        float var = fmaxf((q - (float)NPn * mean * mean) * (1.0f / (NPn - 1)), 0.0f);
        col_tm[cidx] = make_float2(mean + sqrtf(var) * 0.125f, m);
        d2[cidx] = 0.f;
    }
}

// ---------------------------------------------------------------------------
// Merged masked softmax: one read of S produces A1u (row-major) and A2u
// (transposed); d1/d2 denominators via atomics.
// ---------------------------------------------------------------------------
__global__ __launch_bounds__(256) void softmax_merged(
    const bf16* __restrict__ S, const float2* __restrict__ row_tm,
    const float2* __restrict__ col_tm, float* __restrict__ d1,
    float* __restrict__ d2, bf16* __restrict__ A1u, bf16* __restrict__ A2u)
{
    const int b = blockIdx.z, c0 = blockIdx.x * 64, p0 = blockIdx.y * 256;
    const int tid = threadIdx.x;
    const int rt = tid >> 3;
    const int ct = (tid & 7) * 8;

    __shared__ float T[64][265];
    __shared__ float dw2[4][64];

    float2 ctm[8];
#pragma unroll
    for (int t = 0; t < 8; t++) ctm[t] = col_tm[b * NCn + c0 + ct + t];

    float d2acc[8];
#pragma unroll
    for (int t = 0; t < 8; t++) d2acc[t] = 0.f;

#pragma unroll
    for (int pass = 0; pass < 8; pass++) {
        const int p = p0 + pass * 32 + rt;
        const float2 rtm = row_tm[b * NPn + p];
        const long sidx = ((long)(b * NPn + p)) * NCn + c0 + ct;
        short8 sv = *(const short8*)(S + sidx);
        bf16 o1[8] __attribute__((aligned(16)));
        float e1s = 0.f;
#pragma unroll
        for (int t = 0; t < 8; t++) {
            float x = b2f(sv[t]);
            float e1 = (x >= rtm.x) ? __expf(x - rtm.y) : 0.0f;
            o1[t] = __float2bfloat16(e1);
            e1s += e1;
            float e2 = (x >= ctm[t].x) ? __expf(x - ctm[t].y) : 0.0f;
            d2acc[t] += e2;
            T[ct + t][pass * 32 + rt] = e2;
        }
        *(short8*)(A1u + sidx) = *(const short8*)o1;
        e1s += __shfl_xor(e1s, 1);
        e1s += __shfl_xor(e1s, 2);
        e1s += __shfl_xor(e1s, 4);
        if ((tid & 7) == 0) atomicAdd(&d1[b * NPn + p], e1s);
    }

#pragma unroll
    for (int m = 8; m < 64; m <<= 1)
#pragma unroll
        for (int t = 0; t < 8; t++) d2acc[t] += __shfl_xor(d2acc[t], m);
    const int lane = tid & 63, wave = tid >> 6;
    if (lane < 8)
#pragma unroll
        for (int t = 0; t < 8; t++) dw2[wave][lane * 8 + t] = d2acc[t];
    __syncthreads();
    if (tid < 64)
        atomicAdd(&d2[b * NCn + c0 + tid],
                  dw2[0][tid] + dw2[1][tid] + dw2[2][tid] + dw2[3][tid]);

    const int c = tid >> 2, pb = (tid & 3) * 64;
    bf16* dst = A2u + ((long)(b * NCn + c0 + c)) * NPn + p0 + pb;
#pragma unroll
    for (int u = 0; u < 8; u++) {
        bf16 tmp[8] __attribute__((aligned(16)));
#pragma unroll
        for (int w = 0; w < 8; w++)
            tmp[w] = __float2bfloat16(T[c][pb + u * 8 + w]);
        *(short8*)(dst + u * 8) = *(const short8*)tmp;
    }
}

// ---------------------------------------------------------------------------
// Sum 4 split-K fp32 partials, scale row (b*NC+c) by 1/d2 -> bf16
// ---------------------------------------------------------------------------
__global__ __launch_bounds__(256) void reduce_scale_bf16(
    const float* __restrict__ Pp, const float* __restrict__ d2,
    bf16* __restrict__ out, long n4, long stride)
{
    long i = (long)blockIdx.x * 256 + threadIdx.x;
    if (i < n4) {
        float4 a = ((const float4*)Pp)[i];
#pragma unroll
        for (int s = 1; s < 4; s++) {
            float4 v = ((const float4*)(Pp + (long)s * stride))[i];
            a.x += v.x; a.y += v.y; a.z += v.z; a.w += v.w;
        }
        float inv = 1.0f / d2[i / (Dn / 4)];
        out[i * 4 + 0] = __float2bfloat16(a.x * inv);
        out[i * 4 + 1] = __float2bfloat16(a.y * inv);
        out[i * 4 + 2] = __float2bfloat16(a.z * inv);
        out[i * 4 + 3] = __float2bfloat16(a.w * inv);
    }
}

// ---------------------------------------------------------------------------
// fp32 [R x C] -> bf16 row-major copy AND bf16 [C x R] transpose, batched z.
// ---------------------------------------------------------------------------
__global__ __launch_bounds__(256) void cvt_both(
    const float* __restrict__ in, bf16* __restrict__ out_rm,
    bf16* __restrict__ out_t, int R, int C)
{
    __shared__ float tile[32][33];
    const long boff = (long)blockIdx.z * (long)R * C;
    in += boff; out_rm += boff; out_t += boff;
    const int c0 = blockIdx.x * 32, r0 = blockIdx.y * 32;
    const int tx = threadIdx.x, ty = threadIdx.y;
#pragma unroll
    for (int i = ty; i < 32; i += 8) {
        float x = in[(long)(r0 + i) * C + c0 + tx];
        tile[i][tx] = x;
        out_rm[(long)(r0 + i) * C + c0 + tx] = __float2bfloat16(x);
    }
    __syncthreads();
#pragma unroll
    for (int i = ty; i < 32; i += 8)
        out_t[(long)(c0 + i) * R + r0 + tx] = __float2bfloat16(tile[tx][i]);
}

// ---------------------------------------------------------------------------
extern "C" void kernel_launch(void* const* d_in, const int* in_sizes, int n_in,
                              void* d_out, int out_size, void* d_ws, size_t ws_size,
                              hipStream_t stream)
{
    const float* Xp = (const float*)d_in[0];  // [4,4096,512]
    const float* Xc = (const float*)d_in[1];  // [4,1024,512]
    float* out = (float*)d_out;               // [4,4096,1024]

    constexpr int B = Bn, NP = NPn, NC = NCn, D = Dn;
    constexpr float SCALE = 0.044194173824159216f;  // 1/sqrt(512)

    // workspace layout (bytes), ~164 MB
    char* ws = (char*)d_ws;
    bf16*   Qp     = (bf16*)(ws);                   // 16.78 MB [B,NP,D]
    bf16*   Kc     = (bf16*)(ws + 16777216);        //  4.19 MB [B,NC,D]
    bf16*   KcT    = (bf16*)(ws + 20971520);        //  4.19 MB [B,D,NC]
    bf16*   XpT    = (bf16*)(ws + 25165824);        // 16.78 MB [B,D,NP]
    bf16*   S      = (bf16*)(ws + 41943040);        // 33.55 MB [B,NP,NC]; later Hp overlays
    bf16*   A1u    = (bf16*)(ws + 75497472);        // 33.55 MB [B,NP,NC]
    bf16*   A2u    = (bf16*)(ws + 109051904);       // 33.55 MB [B,NC,NP]; rp/cp overlay pre-softmax
    bf16*   H1u    = (bf16*)(ws + 142606336);       // 16.78 MB [B,NP,D]
    bf16*   H2     = (bf16*)(ws + 159383552);       //  4.19 MB [B,NC,D]
    float2* row_tm = (float2*)(ws + 163577856);     // 128 KB  [B*NP]
    float2* col_tm = (float2*)(ws + 163708928);     //  32 KB  [B*NC]
    float*  d1     = (float*)(ws + 163741696);      //  64 KB  [B*NP]
    float*  d2     = (float*)(ws + 163807232);      //  16 KB  [B*NC]
    float4* rp     = (float4*)A2u;                  //  4.19 MB [B*16,NP]
    float4* cp     = (float4*)(ws + 109051904 + 4194304);  // 1.05 MB [B*16,NC]
    float*  Hp     = (float*)S;                     // split-K partials [4][B,NC,D] fp32 (S dead)

    // 1-2: convert + transpose inputs (one read of fp32 each)
    cvt_both<<<dim3(D / 32, NP / 32, B), dim3(32, 8), 0, stream>>>(Xp, Qp, XpT, NP, D);
    cvt_both<<<dim3(D / 32, NC / 32, B), dim3(32, 8), 0, stream>>>(Xc, Kc, KcT, NC, D);

    // 3: S = Qp*Kc^T*scale (bf16) -- 256x256 8-phase
    gemm256<bf16, false><<<dim3(NC / 256, NP / 256, B), dim3(512), 0, stream>>>(
        Qp, Kc, S, NP, NC, D, (long)NP * D, (long)NC * D, (long)NP * NC,
        SCALE, B, nullptr);
    // 4: one-pass row+col stat partials from S
    stats_both<<<dim3(NC / 64, NP / 256, B), dim3(256), 0, stream>>>(S, rp, cp);
    // 5: finalize thr/max; zero denoms
    stats_final<<<dim3((B * NP + B * NC) / 256), dim3(256), 0, stream>>>(
        rp, cp, row_tm, col_tm, d1, d2);
    // 6: merged softmax -> A1u + A2u (transposed), denoms via atomics
    softmax_merged<<<dim3(NC / 64, NP / 256, B), dim3(256), 0, stream>>>(
        S, row_tm, col_tm, d1, d2, A1u, A2u);
    // 7: H1u = A1u * Kc  [B,NP,D] bf16 -- 256x128 dense-2-phase (grid 4x16x4)
    gemm256n128<bf16, false><<<dim3(D / 128, NP / 256, B), dim3(512), 0, stream>>>(
        A1u, KcT, H1u, NP, D, NC, (long)NP * NC, (long)D * NC, (long)NP * D,
        1.0f, B, 1, nullptr);
    // 8: Hp = A2u * Xp partials [4][B,NC,D] fp32, 4-way split-K
    //    -- 256x128 dense-2-phase (grid 4x4x16)
    gemm256n128<float, false><<<dim3(D / 128, NC / 256, 4 * B), dim3(512), 0, stream>>>(
        A2u, XpT, Hp, NC, D, NP, (long)NC * NP, (long)D * NP, (long)NC * D,
        1.0f, B, 4, nullptr);
    // 9: H2 = sum(Hp) / d2 -> bf16
    {
        long n = (long)B * NC * D;
        reduce_scale_bf16<<<dim3((n / 4 + 255) / 256), dim3(256), 0, stream>>>(
            Hp, d2, H2, n / 4, n);
    }
    // 10: out = diag(1/d1) * H1u * H2^T   [B,NP,NC] fp32 -- 256x256 8-phase
    gemm256<float, true><<<dim3(NC / 256, NP / 256, B), dim3(512), 0, stream>>>(
        H1u, H2, out, NP, NC, D, (long)NP * D, (long)NC * D, (long)NP * NC,
        1.0f, B, d1);
}

// Round 7
// 257.462 us; speedup vs baseline: 1.1580x; 1.0247x over previous
//
#include <hip/hip_runtime.h>
#include <hip/hip_bf16.h>

using bf16 = __hip_bfloat16;
typedef __attribute__((ext_vector_type(8))) short short8;   // 8 bf16 (4 VGPRs)
typedef __attribute__((ext_vector_type(4))) float floatx4;  // MFMA C/D frag

#define NPn 4096
#define NCn 1024
#define Dn  512
#define Bn  4

__device__ __forceinline__ float b2f(short s) {
    union { unsigned u; float f; } cv;
    cv.u = ((unsigned)(unsigned short)s) << 16;
    return cv.f;
}

// ---------------------------------------------------------------------------
// async global->LDS, 16B per lane. LDS dest = (wave-uniform base) + lane*16B.
// ---------------------------------------------------------------------------
__device__ __forceinline__ void async_copy16(const bf16* g, bf16* l) {
    __builtin_amdgcn_global_load_lds(
        (const __attribute__((address_space(1))) unsigned int*)g,
        (__attribute__((address_space(3))) unsigned int*)l,
        16, 0, 0);
}

#define SBAR()  __builtin_amdgcn_s_barrier()
#define SCHED0() __builtin_amdgcn_sched_barrier(0)

// ---------------------------------------------------------------------------
// 256x256-tile 8-phase GEMM (T2+T3+T4+T5 port of the m201 template).
// C[M x N] = scale * A[M x K] * Bt[N x K]^T, row-major bf16 in, OutT out.
// 512 threads = 8 waves as 2(M) x 4(N); per-wave output 128x64 = acc[8][4].
// K consumed in BK=64 tiles, each as two k-32 halves (ks=0,1).
// LDS [buf][ks][256][32] bf16, 128 KB total, double buffered.
// Verified in Round 4 (passed, absmax unchanged).
//
// STATS (Round 7): fused row/col stat partials in the epilogue (replaces the
// stats_both kernel's full re-read of S). Per block:
//   rp[(b*4  + bn/256)*M + bm + r] = (sum,sq,max) over this block's 256 cols
//   cp[(b*16 + bm/256)*N + bn + c] = (sum,sq,max) over this block's 256 rows
// C/D frag layout (m89): col = lane&15, row = (lane>>4)*4 + r2.
// Row reduce: butterfly over lane&15 (xor 1,2,4,8) then cross-4-N-waves via
// reused Asl LDS. Col reduce: butterfly over lane>>4 (xor 16,32) then
// cross-2-M-waves via reused Bsl LDS. Stats use f32 v = acc*scale (closer to
// the f32 reference than the old bf16-S-read stats).
//
// Per-thread vmcnt ledger (stageA/stageB = 2 ops each, retire in order):
//  prologue stages 8 ops, vmcnt(4) -> klo landed, khi(4) in flight.
//  P0 +2 (A-klo t+1) =6; P1 +2 (B-klo t+1) =8, vmcnt(4) retires t's khi.
//  P2 +2 (A-khi t+1) =6; P3 +2 (B-khi t+1) =8, vmcnt(4) retires t+1's klo.
// vmcnt never 0 in the main loop (T4). Last tile peeled: vmcnt(0) at P1.
// ---------------------------------------------------------------------------
template <typename OutT, bool RS, bool STATS>
__global__ __launch_bounds__(512) void gemm256(
    const bf16* __restrict__ A, const bf16* __restrict__ B, OutT* __restrict__ C,
    int M, int N, int K, long strideA, long strideB, long strideC,
    float scale, int nbat, const float* __restrict__ rsc,
    float4* __restrict__ rp, float4* __restrict__ cp)
{
    const int z = blockIdx.z;
    const int b = z % nbat;
    A += (long)b * strideA;
    B += (long)b * strideB;
    C += (long)z * strideC;

    // XCD-aware bijective swizzle of the (bx,by) plane (m204).
    const int nwg = gridDim.x * gridDim.y;
    const int orig = blockIdx.y * gridDim.x + blockIdx.x;
    const int q = nwg >> 3, r = nwg & 7;
    const int xcd = orig & 7, pos = orig >> 3;
    const int nid = (xcd < r ? xcd * (q + 1) : r * (q + 1) + (xcd - r) * q) + pos;
    const int bm = (nid / gridDim.x) * 256;
    const int bn = (nid % gridDim.x) * 256;

    const int tid = threadIdx.x;
    const int lane = tid & 63;
    const int wave = tid >> 6;                 // 0..7
    const int wm2 = (wave >> 2) * 128;         // wave's M offset (0/128)
    const int wn2 = (wave & 3) * 64;           // wave's N offset (0/64/128/192)
    const int mrow = lane & 15;
    const int g = lane >> 4;                   // k-chunk group 0..3

    __shared__ bf16 Asl[2][2][256][32];        // [buf][ks][row][col] 64 KB
    __shared__ bf16 Bsl[2][2][256][32];        // 64 KB

    floatx4 acc[8][4];
#pragma unroll
    for (int i = 0; i < 8; i++)
#pragma unroll
        for (int j = 0; j < 4; j++) acc[i][j] = (floatx4)(0.0f);

    const int s0 = wave * 64 + lane;
    const int sr = s0 >> 2, sc = s0 & 3;
    auto stageA = [&](int kb, int ks, int buf) {
        const int cg = (sc ^ (sr & 3)) * 8;
        const bf16* src0 = A + (long)(bm + sr) * K + kb + ks * 32 + cg;
        const bf16* src1 = A + (long)(bm + sr + 128) * K + kb + ks * 32 + cg;
        bf16* base = &Asl[buf][ks][0][0];
        async_copy16(src0, base + wave * 512);
        async_copy16(src1, base + 4096 + wave * 512);
    };
    auto stageB = [&](int kb, int ks, int buf) {
        const int cg = (sc ^ (sr & 3)) * 8;
        const bf16* src0 = B + (long)(bn + sr) * K + kb + ks * 32 + cg;
        const bf16* src1 = B + (long)(bn + sr + 128) * K + kb + ks * 32 + cg;
        bf16* base = &Bsl[buf][ks][0][0];
        async_copy16(src0, base + wave * 512);
        async_copy16(src1, base + 4096 + wave * 512);
    };
    auto ldA = [&](int buf, int ks, int mi) -> short8 {
        const int row = wm2 + mi * 16 + mrow;
        const int cc = (g ^ (row & 3)) * 8;
        return *(const short8*)(&Asl[buf][ks][row][cc]);
    };
    auto ldB = [&](int buf, int ks, int ni) -> short8 {
        const int row = wn2 + ni * 16 + mrow;
        const int cc = (g ^ (row & 3)) * 8;
        return *(const short8*)(&Bsl[buf][ks][row][cc]);
    };

#define MFMA_GRP(MS)                                                          \
    do {                                                                      \
        _Pragma("unroll") for (int i = 0; i < 4; i++)                         \
            _Pragma("unroll") for (int j = 0; j < 4; j++)                     \
                acc[(MS) + i][j] = __builtin_amdgcn_mfma_f32_16x16x32_bf16(   \
                    a[i], bb[j], acc[(MS) + i][j], 0, 0, 0);                  \
    } while (0)

    const int nt = K / 64;
    stageA(0, 0, 0); stageB(0, 0, 0);
    stageA(0, 1, 0); stageB(0, 1, 0);
    asm volatile("s_waitcnt vmcnt(4)" ::: "memory");
    SBAR(); SCHED0();

    int cur = 0;
    for (int t = 0; t < nt - 1; ++t) {
        const int nxt = cur ^ 1;
        const int kb1 = (t + 1) * 64;
        short8 a[4], bb[4];
        // ---- P0 ----
#pragma unroll
        for (int i = 0; i < 4; i++) a[i] = ldA(cur, 0, i);
#pragma unroll
        for (int j = 0; j < 4; j++) bb[j] = ldB(cur, 0, j);
        stageA(kb1, 0, nxt);
        SBAR();
        asm volatile("s_waitcnt lgkmcnt(0)" ::: "memory");
        SCHED0();
        __builtin_amdgcn_s_setprio(1);
        MFMA_GRP(0);
        __builtin_amdgcn_s_setprio(0);
        SCHED0(); SBAR(); SCHED0();
        // ---- P1 ----
#pragma unroll
        for (int i = 0; i < 4; i++) a[i] = ldA(cur, 0, 4 + i);
        stageB(kb1, 0, nxt);
        asm volatile("s_waitcnt vmcnt(4)" ::: "memory");   // t's khi landed
        SBAR();
        asm volatile("s_waitcnt lgkmcnt(0)" ::: "memory");
        SCHED0();
        __builtin_amdgcn_s_setprio(1);
        MFMA_GRP(4);
        __builtin_amdgcn_s_setprio(0);
        SCHED0(); SBAR(); SCHED0();
        // ---- P2 ----
#pragma unroll
        for (int i = 0; i < 4; i++) a[i] = ldA(cur, 1, i);
#pragma unroll
        for (int j = 0; j < 4; j++) bb[j] = ldB(cur, 1, j);
        stageA(kb1, 1, nxt);
        SBAR();
        asm volatile("s_waitcnt lgkmcnt(0)" ::: "memory");
        SCHED0();
        __builtin_amdgcn_s_setprio(1);
        MFMA_GRP(0);
        __builtin_amdgcn_s_setprio(0);
        SCHED0(); SBAR(); SCHED0();
        // ---- P3 ----
#pragma unroll
        for (int i = 0; i < 4; i++) a[i] = ldA(cur, 1, 4 + i);
        stageB(kb1, 1, nxt);
        asm volatile("s_waitcnt vmcnt(4)" ::: "memory");   // t+1's klo landed
        SBAR();
        asm volatile("s_waitcnt lgkmcnt(0)" ::: "memory");
        SCHED0();
        __builtin_amdgcn_s_setprio(1);
        MFMA_GRP(4);
        __builtin_amdgcn_s_setprio(0);
        SCHED0(); SBAR(); SCHED0();
        cur = nxt;
    }
    // ---- last tile (no staging) ----
    {
        short8 a[4], bb[4];
#pragma unroll
        for (int i = 0; i < 4; i++) a[i] = ldA(cur, 0, i);
#pragma unroll
        for (int j = 0; j < 4; j++) bb[j] = ldB(cur, 0, j);
        SBAR();
        asm volatile("s_waitcnt lgkmcnt(0)" ::: "memory");
        SCHED0();
        MFMA_GRP(0);
        SCHED0(); SBAR(); SCHED0();
#pragma unroll
        for (int i = 0; i < 4; i++) a[i] = ldA(cur, 0, 4 + i);
        asm volatile("s_waitcnt vmcnt(0)" ::: "memory");   // its khi landed
        SBAR();
        asm volatile("s_waitcnt lgkmcnt(0)" ::: "memory");
        SCHED0();
        MFMA_GRP(4);
        SCHED0(); SBAR(); SCHED0();
#pragma unroll
        for (int i = 0; i < 4; i++) a[i] = ldA(cur, 1, i);
#pragma unroll
        for (int j = 0; j < 4; j++) bb[j] = ldB(cur, 1, j);
        asm volatile("s_waitcnt lgkmcnt(0)" ::: "memory");
        SCHED0();
        MFMA_GRP(0);
#pragma unroll
        for (int i = 0; i < 4; i++) a[i] = ldA(cur, 1, 4 + i);
        asm volatile("s_waitcnt lgkmcnt(0)" ::: "memory");
        SCHED0();
        MFMA_GRP(4);
    }
#undef MFMA_GRP

    const int crow = (lane >> 4) * 4;
    const int ccol = lane & 15;

    if constexpr (STATS) {
        // All waves' ds_reads are complete (per-wave lgkm0 before last MFMA);
        // barrier so Asl/Bsl can be reused as reduction scratch.
        __syncthreads();
        float* rst = (float*)&Asl[0][0][0][0];   // [nw(4)][plane(3)][256 rows]
        float* cst = (float*)&Bsl[0][0][0][0];   // [mw(2)][plane(3)][256 cols]
        const int nw = wave & 3, mw = wave >> 2;
        const int rg = lane >> 4, cl = lane & 15;

        float cs[4], cq[4], cm[4];
#pragma unroll
        for (int j = 0; j < 4; j++) { cs[j] = 0.f; cq[j] = 0.f; cm[j] = -3.4e38f; }

#pragma unroll
        for (int i = 0; i < 8; i++) {
            float rs[4], rq[4], rm[4];
#pragma unroll
            for (int r2 = 0; r2 < 4; r2++) { rs[r2] = 0.f; rq[r2] = 0.f; rm[r2] = -3.4e38f; }
#pragma unroll
            for (int j = 0; j < 4; j++)
#pragma unroll
                for (int r2 = 0; r2 < 4; r2++) {
                    float v = acc[i][j][r2] * scale;
                    rs[r2] += v; rq[r2] += v * v; rm[r2] = fmaxf(rm[r2], v);
                    cs[j] += v; cq[j] += v * v; cm[j] = fmaxf(cm[j], v);
                }
            // reduce across the 16 col-lanes (row fixed per (rg,r2))
#pragma unroll
            for (int m = 1; m < 16; m <<= 1)
#pragma unroll
                for (int r2 = 0; r2 < 4; r2++) {
                    rs[r2] += __shfl_xor(rs[r2], m);
                    rq[r2] += __shfl_xor(rq[r2], m);
                    rm[r2] = fmaxf(rm[r2], __shfl_xor(rm[r2], m));
                }
            if (cl == 0) {
#pragma unroll
                for (int r2 = 0; r2 < 4; r2++) {
                    int row = wm2 + i * 16 + rg * 4 + r2;
                    rst[nw * 768 + row] = rs[r2];
                    rst[nw * 768 + 256 + row] = rq[r2];
                    rst[nw * 768 + 512 + row] = rm[r2];
                }
            }
        }
        // reduce across the 4 row-groups (col fixed per (j,cl))
#pragma unroll
        for (int m = 16; m < 64; m <<= 1)
#pragma unroll
            for (int j = 0; j < 4; j++) {
                cs[j] += __shfl_xor(cs[j], m);
                cq[j] += __shfl_xor(cq[j], m);
                cm[j] = fmaxf(cm[j], __shfl_xor(cm[j], m));
            }
        if (rg == 0) {
#pragma unroll
            for (int j = 0; j < 4; j++) {
                int col = wn2 + j * 16 + cl;
                cst[mw * 768 + col] = cs[j];
                cst[mw * 768 + 256 + col] = cq[j];
                cst[mw * 768 + 512 + col] = cm[j];
            }
        }
        __syncthreads();
        if (tid < 256) {
            float s = 0.f, qq = 0.f, m = -3.4e38f;
#pragma unroll
            for (int w = 0; w < 4; w++) {
                s += rst[w * 768 + tid];
                qq += rst[w * 768 + 256 + tid];
                m = fmaxf(m, rst[w * 768 + 512 + tid]);
            }
            rp[((long)(b * 4 + (bn >> 8))) * M + bm + tid] = make_float4(s, qq, m, 0.f);
            float s2 = cst[tid] + cst[768 + tid];
            float q2 = cst[256 + tid] + cst[768 + 256 + tid];
            float m2 = fmaxf(cst[512 + tid], cst[768 + 512 + tid]);
            cp[((long)(b * 16 + (bm >> 8))) * N + bn + tid] = make_float4(s2, q2, m2, 0.f);
        }
    }

    // epilogue: C store
    float inv_[8][4];
#pragma unroll
    for (int i = 0; i < 8; i++)
#pragma unroll
        for (int r2 = 0; r2 < 4; r2++) {
            if constexpr (RS)
                inv_[i][r2] = 1.0f / rsc[(long)b * M + bm + wm2 + i * 16 + crow + r2];
            else
                inv_[i][r2] = 1.0f;
        }
#pragma unroll
    for (int i = 0; i < 8; i++) {
#pragma unroll
        for (int j = 0; j < 4; j++) {
#pragma unroll
            for (int r2 = 0; r2 < 4; r2++) {
                long rr = bm + wm2 + i * 16 + crow + r2;
                long cc = bn + wn2 + j * 16 + ccol;
                float v = acc[i][j][r2] * scale * inv_[i][r2];
                if constexpr (__is_same(OutT, float))
                    C[rr * (long)N + cc] = v;
                else
                    C[rr * (long)N + cc] = __float2bfloat16(v);
            }
        }
    }
}

// ---------------------------------------------------------------------------
// 256x128-tile GEMM, dense-2-phase (Round 6, verified). Used for the two
// N=512 GEMMs where a 256-wide tile would underfill the chip.
// 512 threads = 8 waves as 4(M) x 2(N); per-wave output 64x64 = acc[4][4].
// LDS: A[2][2][256][32] 64 KB + B[2][2][128][32] 32 KB = 96 KB, dbuf.
// Split-K: z = s*nbat + b; partial slot s at C + z*strideC.
// Per-thread vmcnt ledger in comments of Round 6 (vmcnt(3) steady, never 0).
// ---------------------------------------------------------------------------
template <typename OutT, bool RS>
__global__ __launch_bounds__(512) void gemm256n128(
    const bf16* __restrict__ A, const bf16* __restrict__ B, OutT* __restrict__ C,
    int M, int N, int K, long strideA, long strideB, long strideC,
    float scale, int nbat, int splits, const float* __restrict__ rsc)
{
    const int z = blockIdx.z;
    const int b = z % nbat;
    const int s = z / nbat;
    const int klen = K / splits;
    const int k0 = s * klen;

    A += (long)b * strideA;
    B += (long)b * strideB;
    C += (long)z * strideC;

    const int nwg = gridDim.x * gridDim.y;
    const int orig = blockIdx.y * gridDim.x + blockIdx.x;
    const int q = nwg >> 3, r = nwg & 7;
    const int xcd = orig & 7, pos = orig >> 3;
    const int nid = (xcd < r ? xcd * (q + 1) : r * (q + 1) + (xcd - r) * q) + pos;
    const int bm = (nid / gridDim.x) * 256;
    const int bn = (nid % gridDim.x) * 128;

    const int tid = threadIdx.x;
    const int lane = tid & 63;
    const int wave = tid >> 6;                 // 0..7
    const int wm2 = (wave >> 1) * 64;          // wave's M offset
    const int wn2 = (wave & 1) * 64;           // wave's N offset
    const int mrow = lane & 15;
    const int g = lane >> 4;

    __shared__ bf16 Asl[2][2][256][32];        // 64 KB
    __shared__ bf16 Bsl[2][2][128][32];        // 32 KB

    floatx4 acc[4][4];
#pragma unroll
    for (int i = 0; i < 4; i++)
#pragma unroll
        for (int j = 0; j < 4; j++) acc[i][j] = (floatx4)(0.0f);

    const int s0 = wave * 64 + lane;
    const int sr = s0 >> 2, sc = s0 & 3;
    auto stageA = [&](int kb, int ks, int buf) {
        const int cg = (sc ^ (sr & 3)) * 8;
        const bf16* src0 = A + (long)(bm + sr) * K + kb + ks * 32 + cg;
        const bf16* src1 = A + (long)(bm + sr + 128) * K + kb + ks * 32 + cg;
        bf16* base = &Asl[buf][ks][0][0];
        async_copy16(src0, base + wave * 512);
        async_copy16(src1, base + 4096 + wave * 512);
    };
    auto stageB = [&](int kb, int ks, int buf) {
        const int cg = (sc ^ (sr & 3)) * 8;
        const bf16* src0 = B + (long)(bn + sr) * K + kb + ks * 32 + cg;
        bf16* base = &Bsl[buf][ks][0][0];
        async_copy16(src0, base + wave * 512);
    };
    auto ldA = [&](int buf, int ks, int mi) -> short8 {
        const int row = wm2 + mi * 16 + mrow;
        const int cc = (g ^ (row & 3)) * 8;
        return *(const short8*)(&Asl[buf][ks][row][cc]);
    };
    auto ldB = [&](int buf, int ks, int ni) -> short8 {
        const int row = wn2 + ni * 16 + mrow;
        const int cc = (g ^ (row & 3)) * 8;
        return *(const short8*)(&Bsl[buf][ks][row][cc]);
    };

#define MFMA_GRP16()                                                          \
    do {                                                                      \
        _Pragma("unroll") for (int i = 0; i < 4; i++)                         \
            _Pragma("unroll") for (int j = 0; j < 4; j++)                     \
                acc[i][j] = __builtin_amdgcn_mfma_f32_16x16x32_bf16(          \
                    a[i], bb[j], acc[i][j], 0, 0, 0);                         \
    } while (0)

    const int nt = klen / 64;
    stageA(k0, 0, 0); stageB(k0, 0, 0);
    stageA(k0, 1, 0); stageB(k0, 1, 0);
    asm volatile("s_waitcnt vmcnt(3)" ::: "memory");
    SBAR(); SCHED0();

    int cur = 0;
    for (int t = 0; t < nt - 1; ++t) {
        const int nxt = cur ^ 1;
        const int kb1 = k0 + (t + 1) * 64;
        short8 a[4], bb[4];
        // ---- P0: k-half 0 ----
#pragma unroll
        for (int i = 0; i < 4; i++) a[i] = ldA(cur, 0, i);
#pragma unroll
        for (int j = 0; j < 4; j++) bb[j] = ldB(cur, 0, j);
        stageA(kb1, 0, nxt);
        stageB(kb1, 0, nxt);
        asm volatile("s_waitcnt vmcnt(3)" ::: "memory");   // t's khi landed
        SBAR();
        asm volatile("s_waitcnt lgkmcnt(0)" ::: "memory");
        SCHED0();
        __builtin_amdgcn_s_setprio(1);
        MFMA_GRP16();
        __builtin_amdgcn_s_setprio(0);
        SCHED0(); SBAR(); SCHED0();
        // ---- P1: k-half 1 ----
#pragma unroll
        for (int i = 0; i < 4; i++) a[i] = ldA(cur, 1, i);
#pragma unroll
        for (int j = 0; j < 4; j++) bb[j] = ldB(cur, 1, j);
        stageA(kb1, 1, nxt);
        stageB(kb1, 1, nxt);
        asm volatile("s_waitcnt vmcnt(3)" ::: "memory");   // t+1's klo landed
        SBAR();
        asm volatile("s_waitcnt lgkmcnt(0)" ::: "memory");
        SCHED0();
        __builtin_amdgcn_s_setprio(1);
        MFMA_GRP16();
        __builtin_amdgcn_s_setprio(0);
        SCHED0(); SBAR(); SCHED0();
        cur = nxt;
    }
    // ---- last tile (no staging) ----
    {
        short8 a[4], bb[4];
#pragma unroll
        for (int i = 0; i < 4; i++) a[i] = ldA(cur, 0, i);
#pragma unroll
        for (int j = 0; j < 4; j++) bb[j] = ldB(cur, 0, j);
        asm volatile("s_waitcnt vmcnt(0)" ::: "memory");
        SBAR();
        asm volatile("s_waitcnt lgkmcnt(0)" ::: "memory");
        SCHED0();
        __builtin_amdgcn_s_setprio(1);
        MFMA_GRP16();
        __builtin_amdgcn_s_setprio(0);
        SCHED0(); SBAR(); SCHED0();
#pragma unroll
        for (int i = 0; i < 4; i++) a[i] = ldA(cur, 1, i);
#pragma unroll
        for (int j = 0; j < 4; j++) bb[j] = ldB(cur, 1, j);
        asm volatile("s_waitcnt lgkmcnt(0)" ::: "memory");
        SCHED0();
        MFMA_GRP16();
    }
#undef MFMA_GRP16

    const int crow = (lane >> 4) * 4;
    const int ccol = lane & 15;
    float inv_[4][4];
#pragma unroll
    for (int i = 0; i < 4; i++)
#pragma unroll
        for (int r2 = 0; r2 < 4; r2++) {
            if constexpr (RS)
                inv_[i][r2] = 1.0f / rsc[(long)b * M + bm + wm2 + i * 16 + crow + r2];
            else
                inv_[i][r2] = 1.0f;
        }
#pragma unroll
    for (int i = 0; i < 4; i++) {
#pragma unroll
        for (int j = 0; j < 4; j++) {
#pragma unroll
            for (int r2 = 0; r2 < 4; r2++) {
                long rr = bm + wm2 + i * 16 + crow + r2;
                long cc = bn + wn2 + j * 16 + ccol;
                float v = acc[i][j][r2] * scale * inv_[i][r2];
                if constexpr (__is_same(OutT, float))
                    C[rr * (long)N + cc] = v;
                else
                    C[rr * (long)N + cc] = __float2bfloat16(v);
            }
        }
    }
}

// ---------------------------------------------------------------------------
// Finalize stats; thr = mean + std(ddof=1)/8. Also zeros d1/d2.
// Round 7: row partials now come from gemm256<STATS> -> 4 slots (256-col
// blocks); col partials 16 slots (256-row blocks).
// ---------------------------------------------------------------------------
__global__ __launch_bounds__(256) void stats_final(
    const float4* __restrict__ rp, const float4* __restrict__ cp,
    float2* __restrict__ row_tm, float2* __restrict__ col_tm,
    float* __restrict__ d1, float* __restrict__ d2)
{
    int idx = blockIdx.x * 256 + threadIdx.x;
    if (idx < Bn * NPn) {
        int b = idx >> 12, p = idx & (NPn - 1);
        float s = 0.f, q = 0.f, m = -3.4e38f;
#pragma unroll
        for (int i = 0; i < 4; i++) {
            float4 v = rp[((long)(b * 4 + i)) * NPn + p];
            s += v.x; q += v.y; m = fmaxf(m, v.z);
        }
        float mean = s * (1.0f / NCn);
        float var = fmaxf((q - (float)NCn * mean * mean) * (1.0f / (NCn - 1)), 0.0f);
        row_tm[idx] = make_float2(mean + sqrtf(var) * 0.125f, m);
        d1[idx] = 0.f;
    } else {
        int cidx = idx - Bn * NPn;
        int b = cidx >> 10, c = cidx & (NCn - 1);
        float s = 0.f, q = 0.f, m = -3.4e38f;
#pragma unroll
        for (int i = 0; i < 16; i++) {
            float4 v = cp[((long)(b * 16 + i)) * NCn + c];
            s += v.x; q += v.y; m = fmaxf(m, v.z);
        }
        float mean = s * (1.0f / NPn);
        float var = fmaxf((q - (float)NPn * mean * mean) * (1.0f / (NPn - 1)), 0.0f);
        col_tm[cidx] = make_float2(mean + sqrtf(var) * 0.125f, m);
        d2[cidx] = 0.f;
    }
}

// ---------------------------------------------------------------------------
// Merged masked softmax v2 (Round 7): one read of S produces A1u (row-major)
// and A2u (transposed); d1/d2 via atomics. The 256-row tile is processed as
// 2 x 128-row halves so the transpose staging LDS is halved:
// float T[64][133] = 34 KB (+1 KB dw2) -> 4 blocks/CU (was 69 KB -> 2).
// ---------------------------------------------------------------------------
__global__ __launch_bounds__(256) void softmax_merged(
    const bf16* __restrict__ S, const float2* __restrict__ row_tm,
    const float2* __restrict__ col_tm, float* __restrict__ d1,
    float* __restrict__ d2, bf16* __restrict__ A1u, bf16* __restrict__ A2u)
{
    const int b = blockIdx.z, c0 = blockIdx.x * 64, p0 = blockIdx.y * 256;
    const int tid = threadIdx.x;
    const int rt = tid >> 3;          // 0..31 row within pass
    const int ct = (tid & 7) * 8;     // col offset, 8 cols per thread

    __shared__ float T[64][133];      // transposed e2 staging (1 half-tile)
    __shared__ float dw2[4][64];      // per-wave col-denom partials

    float2 ctm[8];
#pragma unroll
    for (int t = 0; t < 8; t++) ctm[t] = col_tm[b * NCn + c0 + ct + t];

    float d2acc[8];
#pragma unroll
    for (int t = 0; t < 8; t++) d2acc[t] = 0.f;

    for (int half = 0; half < 2; ++half) {
#pragma unroll
        for (int pass = 0; pass < 4; pass++) {
            const int p = p0 + half * 128 + pass * 32 + rt;
            const float2 rtm = row_tm[b * NPn + p];
            const long sidx = ((long)(b * NPn + p)) * NCn + c0 + ct;
            short8 sv = *(const short8*)(S + sidx);
            bf16 o1[8] __attribute__((aligned(16)));
            float e1s = 0.f;
#pragma unroll
            for (int t = 0; t < 8; t++) {
                float x = b2f(sv[t]);
                float e1 = (x >= rtm.x) ? __expf(x - rtm.y) : 0.0f;
                o1[t] = __float2bfloat16(e1);
                e1s += e1;
                float e2 = (x >= ctm[t].x) ? __expf(x - ctm[t].y) : 0.0f;
                d2acc[t] += e2;
                T[ct + t][pass * 32 + rt] = e2;
            }
            *(short8*)(A1u + sidx) = *(const short8*)o1;
            e1s += __shfl_xor(e1s, 1);
            e1s += __shfl_xor(e1s, 2);
            e1s += __shfl_xor(e1s, 4);
            if ((tid & 7) == 0) atomicAdd(&d1[b * NPn + p], e1s);
        }
        __syncthreads();
        // flush this half's A2u rows (transposed) from LDS
        {
            const int c = tid >> 2, pb = (tid & 3) * 32;
            bf16* dst = A2u + ((long)(b * NCn + c0 + c)) * NPn + p0 + half * 128 + pb;
#pragma unroll
            for (int u = 0; u < 4; u++) {
                bf16 tmp[8] __attribute__((aligned(16)));
#pragma unroll
                for (int w = 0; w < 8; w++)
                    tmp[w] = __float2bfloat16(T[c][pb + u * 8 + w]);
                *(short8*)(dst + u * 8) = *(const short8*)tmp;
            }
        }
        __syncthreads();   // T reusable for next half
    }

    // col denominators: reduce d2acc across rt within wave, then LDS
#pragma unroll
    for (int m = 8; m < 64; m <<= 1)
#pragma unroll
        for (int t = 0; t < 8; t++) d2acc[t] += __shfl_xor(d2acc[t], m);
    const int lane = tid & 63, wave = tid >> 6;
    if (lane < 8)
#pragma unroll
        for (int t = 0; t < 8; t++) dw2[wave][lane * 8 + t] = d2acc[t];
    __syncthreads();
    if (tid < 64)
        atomicAdd(&d2[b * NCn + c0 + tid],
                  dw2[0][tid] + dw2[1][tid] + dw2[2][tid] + dw2[3][tid]);
}

// ---------------------------------------------------------------------------
// Sum 4 split-K fp32 partials, scale row (b*NC+c) by 1/d2 -> bf16
// ---------------------------------------------------------------------------
__global__ __launch_bounds__(256) void reduce_scale_bf16(
    const float* __restrict__ Pp, const float* __restrict__ d2,
    bf16* __restrict__ out, long n4, long stride)
{
    long i = (long)blockIdx.x * 256 + threadIdx.x;
    if (i < n4) {
        float4 a = ((const float4*)Pp)[i];
#pragma unroll
        for (int s = 1; s < 4; s++) {
            float4 v = ((const float4*)(Pp + (long)s * stride))[i];
            a.x += v.x; a.y += v.y; a.z += v.z; a.w += v.w;
        }
        float inv = 1.0f / d2[i / (Dn / 4)];
        out[i * 4 + 0] = __float2bfloat16(a.x * inv);
        out[i * 4 + 1] = __float2bfloat16(a.y * inv);
        out[i * 4 + 2] = __float2bfloat16(a.z * inv);
        out[i * 4 + 3] = __float2bfloat16(a.w * inv);
    }
}

// ---------------------------------------------------------------------------
// fp32 [R x C] -> bf16 row-major copy AND bf16 [C x R] transpose, batched z.
// ---------------------------------------------------------------------------
__global__ __launch_bounds__(256) void cvt_both(
    const float* __restrict__ in, bf16* __restrict__ out_rm,
    bf16* __restrict__ out_t, int R, int C)
{
    __shared__ float tile[32][33];
    const long boff = (long)blockIdx.z * (long)R * C;
    in += boff; out_rm += boff; out_t += boff;
    const int c0 = blockIdx.x * 32, r0 = blockIdx.y * 32;
    const int tx = threadIdx.x, ty = threadIdx.y;
#pragma unroll
    for (int i = ty; i < 32; i += 8) {
        float x = in[(long)(r0 + i) * C + c0 + tx];
        tile[i][tx] = x;
        out_rm[(long)(r0 + i) * C + c0 + tx] = __float2bfloat16(x);
    }
    __syncthreads();
#pragma unroll
    for (int i = ty; i < 32; i += 8)
        out_t[(long)(c0 + i) * R + r0 + tx] = __float2bfloat16(tile[tx][i]);
}

// ---------------------------------------------------------------------------
extern "C" void kernel_launch(void* const* d_in, const int* in_sizes, int n_in,
                              void* d_out, int out_size, void* d_ws, size_t ws_size,
                              hipStream_t stream)
{
    const float* Xp = (const float*)d_in[0];  // [4,4096,512]
    const float* Xc = (const float*)d_in[1];  // [4,1024,512]
    float* out = (float*)d_out;               // [4,4096,1024]

    constexpr int B = Bn, NP = NPn, NC = NCn, D = Dn;
    constexpr float SCALE = 0.044194173824159216f;  // 1/sqrt(512)

    // workspace layout (bytes), ~164 MB
    char* ws = (char*)d_ws;
    bf16*   Qp     = (bf16*)(ws);                   // 16.78 MB [B,NP,D]
    bf16*   Kc     = (bf16*)(ws + 16777216);        //  4.19 MB [B,NC,D]
    bf16*   KcT    = (bf16*)(ws + 20971520);        //  4.19 MB [B,D,NC]
    bf16*   XpT    = (bf16*)(ws + 25165824);        // 16.78 MB [B,D,NP]
    bf16*   S      = (bf16*)(ws + 41943040);        // 33.55 MB [B,NP,NC]; later Hp overlays
    bf16*   A1u    = (bf16*)(ws + 75497472);        // 33.55 MB [B,NP,NC]
    bf16*   A2u    = (bf16*)(ws + 109051904);       // 33.55 MB [B,NC,NP]; rp/cp overlay pre-softmax
    bf16*   H1u    = (bf16*)(ws + 142606336);       // 16.78 MB [B,NP,D]
    bf16*   H2     = (bf16*)(ws + 159383552);       //  4.19 MB [B,NC,D]
    float2* row_tm = (float2*)(ws + 163577856);     // 128 KB  [B*NP]
    float2* col_tm = (float2*)(ws + 163708928);     //  32 KB  [B*NC]
    float*  d1     = (float*)(ws + 163741696);      //  64 KB  [B*NP]
    float*  d2     = (float*)(ws + 163807232);      //  16 KB  [B*NC]
    float4* rp     = (float4*)A2u;                  //  1.05 MB [B*4,NP] (4 slots now)
    float4* cp     = (float4*)(ws + 109051904 + 4194304);  // 1.05 MB [B*16,NC]
    float*  Hp     = (float*)S;                     // split-K partials [4][B,NC,D] fp32 (S dead)

    // 1-2: convert + transpose inputs (one read of fp32 each)
    cvt_both<<<dim3(D / 32, NP / 32, B), dim3(32, 8), 0, stream>>>(Xp, Qp, XpT, NP, D);
    cvt_both<<<dim3(D / 32, NC / 32, B), dim3(32, 8), 0, stream>>>(Xc, Kc, KcT, NC, D);

    // 3: S = Qp*Kc^T*scale (bf16) -- 256x256 8-phase, fused row/col stats
    gemm256<bf16, false, true><<<dim3(NC / 256, NP / 256, B), dim3(512), 0, stream>>>(
        Qp, Kc, S, NP, NC, D, (long)NP * D, (long)NC * D, (long)NP * NC,
        SCALE, B, nullptr, rp, cp);
    // 4: finalize thr/max (rows: 4 partials, cols: 16); zero denoms
    stats_final<<<dim3((B * NP + B * NC) / 256), dim3(256), 0, stream>>>(
        rp, cp, row_tm, col_tm, d1, d2);
    // 5: merged softmax -> A1u + A2u (transposed), denoms via atomics
    softmax_merged<<<dim3(NC / 64, NP / 256, B), dim3(256), 0, stream>>>(
        S, row_tm, col_tm, d1, d2, A1u, A2u);
    // 6: H1u = A1u * Kc  [B,NP,D] bf16 -- 256x128 dense-2-phase
    gemm256n128<bf16, false><<<dim3(D / 128, NP / 256, B), dim3(512), 0, stream>>>(
        A1u, KcT, H1u, NP, D, NC, (long)NP * NC, (long)D * NC, (long)NP * D,
        1.0f, B, 1, nullptr);
    // 7: Hp = A2u * Xp partials [4][B,NC,D] fp32, 4-way split-K
    gemm256n128<float, false><<<dim3(D / 128, NC / 256, 4 * B), dim3(512), 0, stream>>>(
        A2u, XpT, Hp, NC, D, NP, (long)NC * NP, (long)D * NP, (long)NC * D,
        1.0f, B, 4, nullptr);
    // 8: H2 = sum(Hp) / d2 -> bf16
    {
        long n = (long)B * NC * D;
        reduce_scale_bf16<<<dim3((n / 4 + 255) / 256), dim3(256), 0, stream>>>(
            Hp, d2, H2, n / 4, n);
    }
    // 9: out = diag(1/d1) * H1u * H2^T   [B,NP,NC] fp32 -- 256x256 8-phase
    gemm256<float, true, false><<<dim3(NC / 256, NP / 256, B), dim3(512), 0, stream>>>(
        H1u, H2, out, NP, NC, D, (long)NP * D, (long)NC * D, (long)NP * NC,
        1.0f, B, d1, nullptr, nullptr);
}